// Round 9
// baseline (15123.932 us; speedup 1.0000x reference)
//
#include <hip/hip_runtime.h>
#include <stdint.h>
#include <stddef.h>
#include <math.h>

// ---- problem dims ----
#define NB   64
#define NP   8
#define ND   1024
#define NH   16
#define NBOS 16
#define NC   14
#define NS   30   // BOS + C
#define NL   4
#define NV   1024
#define NHID 2048
#define NDH  64

#define JAX_PARTITIONABLE 1

typedef _Float16 half_t;
typedef _Float16 h4_t __attribute__((ext_vector_type(4)));
typedef _Float16 h8_t __attribute__((ext_vector_type(8)));
typedef float f32x4 __attribute__((ext_vector_type(4)));

// ======================= threefry2x32 (JAX-exact) =======================
__device__ __forceinline__ uint32_t rotl32(uint32_t x, int d) {
  return (x << d) | (x >> (32 - d));
}

__device__ __forceinline__ void threefry2x32(uint32_t k0, uint32_t k1,
                                             uint32_t x0, uint32_t x1,
                                             uint32_t& o0, uint32_t& o1) {
  uint32_t ks2 = k0 ^ k1 ^ 0x1BD11BDAu;
  x0 += k0; x1 += k1;
#define TF_R4(a,b,c,d) \
  x0 += x1; x1 = rotl32(x1,(a)); x1 ^= x0; \
  x0 += x1; x1 = rotl32(x1,(b)); x1 ^= x0; \
  x0 += x1; x1 = rotl32(x1,(c)); x1 ^= x0; \
  x0 += x1; x1 = rotl32(x1,(d)); x1 ^= x0;
  TF_R4(13,15,26,6)  x0 += k1;  x1 += ks2 + 1u;
  TF_R4(17,29,16,24) x0 += ks2; x1 += k0 + 2u;
  TF_R4(13,15,26,6)  x0 += k0;  x1 += k1 + 3u;
  TF_R4(17,29,16,24) x0 += k1;  x1 += ks2 + 4u;
  TF_R4(13,15,26,6)  x0 += ks2; x1 += k0 + 5u;
#undef TF_R4
  o0 = x0; o1 = x1;
}

// ======================= generic fp32 GEMM (prologue + fallback) ========
__global__ __launch_bounds__(256) void k_gemm(
    const float* __restrict__ A, const float* __restrict__ Bm,
    float* __restrict__ Cm, const float* __restrict__ bias,
    int M, int N, int K, int epi) {
  __shared__ __align__(16) float As[16][64];
  __shared__ __align__(16) float Bs[16][64];
  const int tid = threadIdx.x;
  const int tx = tid & 15, ty = tid >> 4;
  const int m0 = blockIdx.y * 64, n0 = blockIdx.x * 64;
  const int lar = tid >> 2, lak = (tid & 3) << 2;
  const int lbk = tid >> 4, lbn = (tid & 15) << 2;
  float acc[4][4] = {};
  for (int kt = 0; kt < K; kt += 16) {
    float4 av = make_float4(0.f, 0.f, 0.f, 0.f);
    if (m0 + lar < M)
      av = *(const float4*)(A + (size_t)(m0 + lar) * K + kt + lak);
    float4 bv4 = make_float4(0.f, 0.f, 0.f, 0.f);
    if (n0 + lbn < N)
      bv4 = *(const float4*)(Bm + (size_t)(kt + lbk) * N + n0 + lbn);
    __syncthreads();
    As[lak + 0][lar] = av.x; As[lak + 1][lar] = av.y;
    As[lak + 2][lar] = av.z; As[lak + 3][lar] = av.w;
    *(float4*)(&Bs[lbk][lbn]) = bv4;
    __syncthreads();
#pragma unroll
    for (int kk = 0; kk < 16; ++kk) {
      float4 a4 = *(const float4*)(&As[kk][ty << 2]);
      float4 b4 = *(const float4*)(&Bs[kk][tx << 2]);
      float ar[4] = {a4.x, a4.y, a4.z, a4.w};
      float br[4] = {b4.x, b4.y, b4.z, b4.w};
#pragma unroll
      for (int i2 = 0; i2 < 4; ++i2)
#pragma unroll
        for (int j2 = 0; j2 < 4; ++j2)
          acc[i2][j2] = fmaf(ar[i2], br[j2], acc[i2][j2]);
    }
  }
#pragma unroll
  for (int i2 = 0; i2 < 4; ++i2) {
    int r = m0 + (ty << 2) + i2;
    if (r >= M) continue;
#pragma unroll
    for (int j2 = 0; j2 < 4; ++j2) {
      int c = n0 + (tx << 2) + j2;
      if (c >= N) continue;
      size_t off = (size_t)r * N + c;
      float val = acc[i2][j2];
      if (epi == 1) val += Cm[off];
      else if (epi == 2) val += bias[c];
      Cm[off] = val;
    }
  }
}

// ======================= fp16x3 MFMA GEMM (128x128, ring-4 prefetch) ====
__device__ __forceinline__ void gload16(const void* g, const void* l) {
  __builtin_amdgcn_global_load_lds((const __attribute__((address_space(1))) void*)g,
                                   (__attribute__((address_space(3))) void*)l, 16, 0, 0);
}

// XCD-aware chunked swizzle (per z-slice). gx*gy must be %8==0.
__device__ __forceinline__ void xcd_swz(int gx, int gy, int& bx, int& by) {
  const int flat = blockIdx.y * gx + blockIdx.x;
  const int chunk = (gx * gy) >> 3;
  const int myid = (flat & 7) * chunk + (flat >> 3);
  bx = myid / gy;
  by = myid % gy;
}

// EPI 0: store partial fp32*(1/1024) at Cout + z*M*N
// EPI 1: fused SwiGLU -> Mh/Ml (col-permuted W1 layout), full-K only
// EPI 2: store split fp16 planes (raw value) -> Mh/Ml, full-K only
// 512 threads = 8 waves (2 M x 4 N); wave tile 64x32; ring-4 LDS (128 KB),
// 3 stages in flight, counted vmcnt (T4): 4 loads/thread/stage.
template<int EPI>
__global__ __launch_bounds__(512) void k_g3(
    const half_t* __restrict__ Ah, const half_t* __restrict__ Al,
    const half_t* __restrict__ Bh, const half_t* __restrict__ Bl,
    float* __restrict__ Cout, half_t* __restrict__ Mh, half_t* __restrict__ Ml,
    int M, int N, int K, int CH) {
  __shared__ __align__(16) half_t sAh[4][4096];
  __shared__ __align__(16) half_t sAl[4][4096];
  __shared__ __align__(16) half_t sBh[4][4096];
  __shared__ __align__(16) half_t sBl[4][4096];
  int bx, by; xcd_swz(gridDim.x, gridDim.y, bx, by);
  const int tid = threadIdx.x;
  const int lane = tid & 63, w = tid >> 6;       // 8 waves
  const int wm = w >> 2, wn = w & 3;             // 2 x 4 wave grid
  const int m0 = by * 128, n0 = bx * 128;
  const int fr = lane & 15, fq = lane >> 4;
  const int kbeg = blockIdx.z * CH;
  const int kend = (kbeg + CH < K) ? (kbeg + CH) : K;
  const int nt = (kend - kbeg) >> 5;             // K-tiles (always >= 4 here)
  f32x4 acc[4][2] = {};
  // staging: thread t -> row t>>2 (0..127), k-halves (t&3)*8; dest byte t*16
  const int r0 = tid >> 2, ch = (tid & 3) * 8;
  const size_t aB = (size_t)(m0 + r0) * K + ch;
  const size_t bB = (size_t)(n0 + r0) * K + ch;
  const int wb = w * 1024;   // per-wave dest byte offset within 8KB plane

  auto STAGE = [&](int buf, int kt) {   // 4 loads/thread (one per plane)
    gload16(Ah + aB + kt, (char*)(&sAh[buf][0]) + wb);
    gload16(Al + aB + kt, (char*)(&sAl[buf][0]) + wb);
    gload16(Bh + bB + kt, (char*)(&sBh[buf][0]) + wb);
    gload16(Bl + bB + kt, (char*)(&sBl[buf][0]) + wb);
  };

  // prologue: issue up to 3 stages ahead
  STAGE(0, kbeg);
  if (nt > 1) STAGE(1, kbeg + 32);
  if (nt > 2) STAGE(2, kbeg + 64);
  for (int t = 0; t < nt; ++t) {
    const int cur = t & 3;
    if (t + 3 < nt) STAGE((t + 3) & 3, kbeg + (t + 3) * 32);
    // wait for tile t's 4 loads: outstanding = 4 * (stages issued beyond t)
    const int rem = nt - 1 - t;
    if (rem >= 3)      asm volatile("s_waitcnt vmcnt(12)" ::: "memory");
    else if (rem == 2) asm volatile("s_waitcnt vmcnt(8)"  ::: "memory");
    else if (rem == 1) asm volatile("s_waitcnt vmcnt(4)"  ::: "memory");
    else               asm volatile("s_waitcnt vmcnt(0)"  ::: "memory");
    asm volatile("s_barrier" ::: "memory");        // all waves' cur staged
    const half_t* bAh = &sAh[cur][0] + (wm * 64 + fr) * 32 + fq * 8;
    const half_t* bAl = &sAl[cur][0] + (wm * 64 + fr) * 32 + fq * 8;
    const half_t* bBh = &sBh[cur][0] + (wn * 32 + fr) * 32 + fq * 8;
    const half_t* bBl = &sBl[cur][0] + (wn * 32 + fr) * 32 + fq * 8;
    h8_t a[4], b[2], tt[2];
#pragma unroll
    for (int mi = 0; mi < 4; ++mi) a[mi] = *(const h8_t*)(bAh + mi * 512);
#pragma unroll
    for (int ni = 0; ni < 2; ++ni) b[ni] = *(const h8_t*)(bBh + ni * 512);
#pragma unroll
    for (int mi = 0; mi < 4; ++mi)
#pragma unroll
      for (int ni = 0; ni < 2; ++ni)
        acc[mi][ni] = __builtin_amdgcn_mfma_f32_16x16x32_f16(a[mi], b[ni], acc[mi][ni], 0, 0, 0);
#pragma unroll
    for (int ni = 0; ni < 2; ++ni) tt[ni] = *(const h8_t*)(bBl + ni * 512);
#pragma unroll
    for (int mi = 0; mi < 4; ++mi)
#pragma unroll
      for (int ni = 0; ni < 2; ++ni)
        acc[mi][ni] = __builtin_amdgcn_mfma_f32_16x16x32_f16(a[mi], tt[ni], acc[mi][ni], 0, 0, 0);
#pragma unroll
    for (int mi = 0; mi < 4; ++mi) a[mi] = *(const h8_t*)(bAl + mi * 512);
    // all ds_reads of cur issued; barrier before a later stage may overwrite.
    asm volatile("s_barrier" ::: "memory");
#pragma unroll
    for (int mi = 0; mi < 4; ++mi)
#pragma unroll
      for (int ni = 0; ni < 2; ++ni)
        acc[mi][ni] = __builtin_amdgcn_mfma_f32_16x16x32_f16(a[mi], b[ni], acc[mi][ni], 0, 0, 0);
  }
  const float sc = 1.0f / 1024.0f;
  if (EPI == 0) {
    float* Cz = Cout + (size_t)blockIdx.z * M * N;
#pragma unroll
    for (int mi = 0; mi < 4; ++mi) {
      const int row = m0 + wm * 64 + mi * 16 + fq * 4;
#pragma unroll
      for (int ni = 0; ni < 2; ++ni) {
        const int col = n0 + wn * 32 + ni * 16 + fr;
        float* cp = Cz + (size_t)row * N + col;
#pragma unroll
        for (int j = 0; j < 4; ++j) cp[(size_t)j * N] = acc[mi][ni][j] * sc;
      }
    }
  } else if (EPI == 1) {
    // SwiGLU: (acc[mi][0], acc[mi][1]) = (u1,u2) at hid = (n0+wn*32)/2 + fr
    const int hid = ((n0 + wn * 32) >> 1) + fr;
#pragma unroll
    for (int mi = 0; mi < 4; ++mi) {
      const int row = m0 + wm * 64 + mi * 16 + fq * 4;
#pragma unroll
      for (int j = 0; j < 4; ++j) {
        const float u1 = acc[mi][0][j] * sc;
        const float u2 = acc[mi][1][j] * sc;
        const float s = 1.0f / (1.0f + expf(-u1));
        const float y = (u1 * s) * u2 * 16.0f;
        const half_t hv = (half_t)y;
        const size_t off = (size_t)(row + j) * NHID + hid;
        Mh[off] = hv;
        Ml[off] = (half_t)(y - (float)hv);
      }
    }
  } else {
    // split fp16 planes of raw value (for qkv -> attn consumption)
#pragma unroll
    for (int mi = 0; mi < 4; ++mi) {
      const int row = m0 + wm * 64 + mi * 16 + fq * 4;
#pragma unroll
      for (int ni = 0; ni < 2; ++ni) {
        const int col = n0 + wn * 32 + ni * 16 + fr;
#pragma unroll
        for (int j = 0; j < 4; ++j) {
          const float v = acc[mi][ni][j] * sc;
          const half_t hv = (half_t)v;
          const size_t off = (size_t)(row + j) * N + col;
          Mh[off] = hv;
          Ml[off] = (half_t)(v - (float)hv);
        }
      }
    }
  }
}

// ---- weight split: W:(K,N) fp32 -> Th,Tl:(N,K) fp16 x64 ----
__global__ __launch_bounds__(256) void k_splitw(
    const float* __restrict__ W, half_t* __restrict__ Th, half_t* __restrict__ Tl,
    int K, int N) {
  __shared__ float t[32][33];
  const int kb = blockIdx.x * 32, nb = blockIdx.y * 32;
  const int tid = threadIdx.x;
  const int rr = tid >> 5, cc = tid & 31;
#pragma unroll
  for (int i = 0; i < 4; ++i)
    t[rr + i * 8][cc] = W[(size_t)(kb + rr + i * 8) * N + nb + cc];
  __syncthreads();
#pragma unroll
  for (int i = 0; i < 4; ++i) {
    const int nr = rr + i * 8;
    const float x = t[cc][nr] * 64.0f;
    const half_t h = (half_t)x;
    const float r = x - (float)h;
    const size_t off = (size_t)(nb + nr) * K + kb + cc;
    Th[off] = h;
    Tl[off] = (half_t)r;
  }
}

// variant for mlp_w1: logical col n -> physical row p for swiglu pairing
__global__ __launch_bounds__(256) void k_splitw_swz(
    const float* __restrict__ W, half_t* __restrict__ Th, half_t* __restrict__ Tl,
    int K, int N) {
  __shared__ float t[32][33];
  const int kb = blockIdx.x * 32, nb = blockIdx.y * 32;
  const int tid = threadIdx.x;
  const int rr = tid >> 5, cc = tid & 31;
#pragma unroll
  for (int i = 0; i < 4; ++i)
    t[rr + i * 8][cc] = W[(size_t)(kb + rr + i * 8) * N + nb + cc];
  __syncthreads();
#pragma unroll
  for (int i = 0; i < 4; ++i) {
    const int n = nb + rr + i * 8;
    const int hid = n & (NHID - 1), half = n >> 11;
    const int p = ((hid >> 4) << 5) + (half << 4) + (hid & 15);
    const float x = t[cc][rr + i * 8] * 64.0f;
    const half_t h = (half_t)x;
    const float r = x - (float)h;
    const size_t off = (size_t)p * K + kb + cc;
    Th[off] = h;
    Tl[off] = (half_t)r;
  }
}

// ======================= cross attention (builds BOS) ===================
__global__ __launch_bounds__(256) void k_ca_attn(
    const float* __restrict__ qh, const float* __restrict__ kh,
    const float* __restrict__ vh, float* __restrict__ bosw) {
  const int b = blockIdx.x >> 4, h = blockIdx.x & 15;
  __shared__ float q[NBOS][NDH], kk[NP][NDH], vv[NP][NDH], a[NBOS][NP];
  const int tid = threadIdx.x;
  for (int idx = tid; idx < NBOS * NDH; idx += 256) {
    int qi = idx >> 6, d = idx & 63;
    q[qi][d] = qh[(size_t)qi * ND + h * NDH + d];
  }
  for (int idx = tid; idx < NP * NDH; idx += 256) {
    int p = idx >> 6, d = idx & 63;
    kk[p][d] = kh[(size_t)(b * NP + p) * ND + h * NDH + d];
    vv[p][d] = vh[(size_t)(b * NP + p) * ND + h * NDH + d];
  }
  __syncthreads();
  if (tid < NBOS * NP) {
    int qi = tid >> 3, p = tid & 7;
    float dot = 0.f;
    for (int d = 0; d < NDH; ++d) dot = fmaf(q[qi][d], kk[p][d], dot);
    a[qi][p] = dot / 64.0f;
  }
  __syncthreads();
  if (tid < NBOS) {
    float mx = a[tid][0];
    for (int p = 1; p < NP; ++p) mx = fmaxf(mx, a[tid][p]);
    float sum = 0.f;
    for (int p = 0; p < NP; ++p) { float e = expf(a[tid][p] - mx); a[tid][p] = e; sum += e; }
    for (int p = 0; p < NP; ++p) a[tid][p] /= sum;
  }
  __syncthreads();
  for (int idx = tid; idx < NBOS * NDH; idx += 256) {
    int qi = idx >> 6, d = idx & 63;
    float o = 0.f;
    for (int p = 0; p < NP; ++p) o = fmaf(a[qi][p], vv[p][d], o);
    bosw[(size_t)(b * NBOS + qi) * ND + h * NDH + d] = o;
  }
}

// ======================= self attention (fallback fp32 qkv) =============
__global__ __launch_bounds__(256) void k_attn(
    const float* __restrict__ qkv, const float* __restrict__ relb,
    float* __restrict__ attout) {
  const int b = blockIdx.x >> 4, h = blockIdx.x & 15;
  __shared__ float q[NS][NDH], kk[NS][NDH], vv[NS][NDH];
  __shared__ float a[NS][NS];
  const int tid = threadIdx.x;
  for (int idx = tid; idx < NS * NDH; idx += 256) {
    int s = idx >> 6, d = idx & 63;
    size_t base = ((size_t)(b * NS + s) * 3) * ND + h * NDH + d;
    q[s][d]  = qkv[base];
    kk[s][d] = qkv[base + ND];
    vv[s][d] = qkv[base + 2 * ND];
  }
  __syncthreads();
  for (int idx = tid; idx < NS * NS; idx += 256) {
    int i = idx / NS, j = idx % NS;
    float sc = 0.f;
    if (j <= i) {
      float dot = 0.f;
      for (int d = 0; d < NDH; ++d) dot = fmaf(q[i][d], kk[j][d], dot);
      sc = dot * 0.125f + relb[(size_t)(i - j + NS - 1) * NH + h];
    }
    a[i][j] = sc;
  }
  __syncthreads();
  if (tid < NS) {
    const int i = tid;
    float mx = -INFINITY;
    for (int j = 0; j <= i; ++j) mx = fmaxf(mx, a[i][j]);
    float sum = 0.f;
    for (int j = 0; j <= i; ++j) { float e = expf(a[i][j] - mx); a[i][j] = e; sum += e; }
    for (int j = 0; j <= i; ++j) a[i][j] /= sum;
    for (int j = i + 1; j < NS; ++j) a[i][j] = 0.f;
  }
  __syncthreads();
  for (int idx = tid; idx < NS * NDH; idx += 256) {
    int i = idx >> 6, d = idx & 63;
    float o = 0.f;
    for (int j = 0; j < NS; ++j) o = fmaf(a[i][j], vv[j][d], o);
    attout[(size_t)(b * NS + i) * ND + h * NDH + d] = o;
  }
}

// self attention consuming split qkv planes, emitting split planes (x16)
__global__ __launch_bounds__(256) void k_attn16p(
    const half_t* __restrict__ Qh, const half_t* __restrict__ Ql,
    const float* __restrict__ relb,
    half_t* __restrict__ Oh, half_t* __restrict__ Ol) {
  const int b = blockIdx.x >> 4, h = blockIdx.x & 15;
  __shared__ float q[NS][NDH], kk[NS][NDH], vv[NS][NDH];
  __shared__ float a[NS][NS];
  const int tid = threadIdx.x;
  for (int idx = tid; idx < NS * NDH; idx += 256) {
    int s = idx >> 6, d = idx & 63;
    size_t base = (size_t)(b * NS + s) * 3072 + h * NDH + d;
    q[s][d]  = (float)Qh[base] + (float)Ql[base];
    kk[s][d] = (float)Qh[base + 1024] + (float)Ql[base + 1024];
    vv[s][d] = (float)Qh[base + 2048] + (float)Ql[base + 2048];
  }
  __syncthreads();
  for (int idx = tid; idx < NS * NS; idx += 256) {
    int i = idx / NS, j = idx % NS;
    float sc = 0.f;
    if (j <= i) {
      float dot = 0.f;
      for (int d = 0; d < NDH; ++d) dot = fmaf(q[i][d], kk[j][d], dot);
      sc = dot * 0.125f + relb[(size_t)(i - j + NS - 1) * NH + h];
    }
    a[i][j] = sc;
  }
  __syncthreads();
  if (tid < NS) {
    const int i = tid;
    float mx = -INFINITY;
    for (int j = 0; j <= i; ++j) mx = fmaxf(mx, a[i][j]);
    float sum = 0.f;
    for (int j = 0; j <= i; ++j) { float e = expf(a[i][j] - mx); a[i][j] = e; sum += e; }
    for (int j = 0; j <= i; ++j) a[i][j] /= sum;
    for (int j = i + 1; j < NS; ++j) a[i][j] = 0.f;
  }
  __syncthreads();
  for (int idx = tid; idx < NS * NDH; idx += 256) {
    int i = idx >> 6, d = idx & 63;
    float o = 0.f;
    for (int j = 0; j < NS; ++j) o = fmaf(a[i][j], vv[j][d], o);
    const float y = o * 16.0f;
    const half_t hv = (half_t)y;
    const size_t off = (size_t)(b * NS + i) * ND + h * NDH + d;
    Oh[off] = hv;
    Ol[off] = (half_t)(y - (float)hv);
  }
}

// ======================= layernorm cores ================================
__device__ __forceinline__ float block_sum(float val, float* sbuf) {
  for (int off = 32; off > 0; off >>= 1) val += __shfl_down(val, off, 64);
  const int wid = threadIdx.x >> 6;
  if ((threadIdx.x & 63) == 0) sbuf[wid] = val;
  __syncthreads();
  if (threadIdx.x == 0) sbuf[0] = sbuf[0] + sbuf[1] + sbuf[2] + sbuf[3];
  __syncthreads();
  float r = sbuf[0];
  __syncthreads();
  return r;
}

__device__ __forceinline__ void ln_core_emit16(
    float4 x4, const float* w, const float* bvec, float* sbuf,
    half_t* Oh, half_t* Ol, size_t rowoff, int d0) {
  float mean = block_sum(x4.x + x4.y + x4.z + x4.w, sbuf) * (1.0f / 1024.0f);
  float dx0 = x4.x - mean, dx1 = x4.y - mean, dx2 = x4.z - mean, dx3 = x4.w - mean;
  float var = block_sum(dx0*dx0 + dx1*dx1 + dx2*dx2 + dx3*dx3, sbuf) * (1.0f / 1024.0f);
  float rs = 1.0f / sqrtf(var + 1e-5f);
  float4 w4 = *(const float4*)(w + d0);
  float4 b4 = *(const float4*)(bvec + d0);
  float y0 = (dx0 * rs * w4.x + b4.x) * 16.0f;
  float y1 = (dx1 * rs * w4.y + b4.y) * 16.0f;
  float y2 = (dx2 * rs * w4.z + b4.z) * 16.0f;
  float y3 = (dx3 * rs * w4.w + b4.w) * 16.0f;
  h4_t vh, vl;
  vh.x = (half_t)y0; vl.x = (half_t)(y0 - (float)vh.x);
  vh.y = (half_t)y1; vl.y = (half_t)(y1 - (float)vh.y);
  vh.z = (half_t)y2; vl.z = (half_t)(y2 - (float)vh.z);
  vh.w = (half_t)y3; vl.w = (half_t)(y3 - (float)vh.w);
  *(h4_t*)(Oh + rowoff + d0) = vh;
  *(h4_t*)(Ol + rowoff + d0) = vl;
}

// fallback fp32 LN
__global__ __launch_bounds__(256) void k_ln(
    const float* __restrict__ in, const float* __restrict__ w,
    const float* __restrict__ bvec, float* __restrict__ out) {
  __shared__ float sbuf[4];
  const size_t row = blockIdx.x;
  const int d0 = threadIdx.x << 2;
  float4 x4 = *(const float4*)(in + row * ND + d0);
  float mean = block_sum(x4.x + x4.y + x4.z + x4.w, sbuf) * (1.0f / 1024.0f);
  float dx0 = x4.x - mean, dx1 = x4.y - mean, dx2 = x4.z - mean, dx3 = x4.w - mean;
  float var = block_sum(dx0*dx0 + dx1*dx1 + dx2*dx2 + dx3*dx3, sbuf) * (1.0f / 1024.0f);
  float rs = 1.0f / sqrtf(var + 1e-5f);
  float4 w4 = *(const float4*)(w + d0);
  float4 b4 = *(const float4*)(bvec + d0);
  float4 o;
  o.x = dx0 * rs * w4.x + b4.x;
  o.y = dx1 * rs * w4.y + b4.y;
  o.z = dx2 * rs * w4.z + b4.z;
  o.w = dx3 * rs * w4.w + b4.w;
  *(float4*)(out + row * ND + d0) = o;
}

// fused: X[row] += sum3(parts[row]); LN -> split planes. (1920 rows)
template<int WRITEX>
__global__ __launch_bounds__(256) void k_red_ln(
    const float* __restrict__ parts, float* __restrict__ X,
    const float* __restrict__ w, const float* __restrict__ bvec,
    half_t* __restrict__ Oh, half_t* __restrict__ Ol) {
  __shared__ float sbuf[4];
  const size_t row = blockIdx.x;
  const int d0 = threadIdx.x << 2;
  const size_t off = row * ND + d0;
  const size_t MN = (size_t)1920 * 1024;
  float4 x4 = *(const float4*)(X + off);
  float4 p0 = *(const float4*)(parts + off);
  float4 p1 = *(const float4*)(parts + MN + off);
  float4 p2 = *(const float4*)(parts + 2 * MN + off);
  x4.x += p0.x + p1.x + p2.x; x4.y += p0.y + p1.y + p2.y;
  x4.z += p0.z + p1.z + p2.z; x4.w += p0.w + p1.w + p2.w;
  if (WRITEX) *(float4*)(X + off) = x4;
  ln_core_emit16(x4, w, bvec, sbuf, Oh, Ol, row * ND, d0);
}

// fused: last-layer mlp2 reduce + lnf, packed to (896, ND) planes
__global__ __launch_bounds__(256) void k_red_lnf(
    const float* __restrict__ parts, const float* __restrict__ X,
    const float* __restrict__ w, const float* __restrict__ bvec,
    half_t* __restrict__ Oh, half_t* __restrict__ Ol) {
  __shared__ float sbuf[4];
  const int blk = blockIdx.x;
  const int b = blk / NC, c = blk % NC;
  const size_t row = (size_t)b * NS + NBOS + c;
  const int d0 = threadIdx.x << 2;
  const size_t off = row * ND + d0;
  const size_t MN = (size_t)1920 * 1024;
  float4 x4 = *(const float4*)(X + off);
  float4 p0 = *(const float4*)(parts + off);
  float4 p1 = *(const float4*)(parts + MN + off);
  float4 p2 = *(const float4*)(parts + 2 * MN + off);
  x4.x += p0.x + p1.x + p2.x; x4.y += p0.y + p1.y + p2.y;
  x4.z += p0.z + p1.z + p2.z; x4.w += p0.w + p1.w + p2.w;
  ln_core_emit16(x4, w, bvec, sbuf, Oh, Ol, (size_t)blk * ND, d0);
}

// fp32 lnf (fallback)
__global__ __launch_bounds__(256) void k_lnf(
    const float* __restrict__ x, const float* __restrict__ w,
    const float* __restrict__ bvec, float* __restrict__ out) {
  __shared__ float sbuf[4];
  const int blk = blockIdx.x;
  const int b = blk / NC, c = blk % NC;
  const size_t row = (size_t)b * NS + NBOS + c;
  const int d0 = threadIdx.x << 2;
  float4 x4 = *(const float4*)(x + row * ND + d0);
  float mean = block_sum(x4.x + x4.y + x4.z + x4.w, sbuf) * (1.0f / 1024.0f);
  float dx0 = x4.x - mean, dx1 = x4.y - mean, dx2 = x4.z - mean, dx3 = x4.w - mean;
  float var = block_sum(dx0*dx0 + dx1*dx1 + dx2*dx2 + dx3*dx3, sbuf) * (1.0f / 1024.0f);
  float rs = 1.0f / sqrtf(var + 1e-5f);
  float4 w4 = *(const float4*)(w + d0);
  float4 b4 = *(const float4*)(bvec + d0);
  float4 o;
  o.x = dx0 * rs * w4.x + b4.x;
  o.y = dx1 * rs * w4.y + b4.y;
  o.z = dx2 * rs * w4.z + b4.z;
  o.w = dx3 * rs * w4.w + b4.w;
  *(float4*)(out + (size_t)blk * ND + d0) = o;
}

// ======================= build x (+ fused layer-0 LN1) ==================
__device__ __forceinline__ float4 build_row(
    const float* bos, const float* pos_emb, const float* tok_emb,
    const int* tok, const float* stval, int b, int s, int d0, int step) {
  float4 o;
  if (s < NBOS) {
    o = *(const float4*)(bos + (size_t)(b * NBOS + s) * ND + d0);
  } else {
    int j = s - NBOS;
    if (j < step) {
      float sv = stval[b * NC + j];
      int t = tok[b * NC + j];
      float4 e = *(const float4*)(tok_emb + (size_t)t * ND + d0);
      o.x = sv * e.x; o.y = sv * e.y; o.z = sv * e.z; o.w = sv * e.w;
    } else {
      o = *(const float4*)(pos_emb + (size_t)j * ND + d0);
    }
  }
  return o;
}

__global__ __launch_bounds__(256) void k_build_x(
    const float* __restrict__ bos, const float* __restrict__ pos_emb,
    const float* __restrict__ tok_emb, const int* __restrict__ tok,
    const float* __restrict__ stval, float* __restrict__ x, int step) {
  const int row = blockIdx.x;
  const int b = row / NS, s = row % NS;
  const int d0 = threadIdx.x << 2;
  float4 o = build_row(bos, pos_emb, tok_emb, tok, stval, b, s, d0, step);
  *(float4*)(x + (size_t)row * ND + d0) = o;
}

__global__ __launch_bounds__(256) void k_build_ln(
    const float* __restrict__ bos, const float* __restrict__ pos_emb,
    const float* __restrict__ tok_emb, const int* __restrict__ tok,
    const float* __restrict__ stval, const float* __restrict__ w,
    const float* __restrict__ bvec, float* __restrict__ x,
    half_t* __restrict__ Oh, half_t* __restrict__ Ol, int step) {
  __shared__ float sbuf[4];
  const int row = blockIdx.x;
  const int b = row / NS, s = row % NS;
  const int d0 = threadIdx.x << 2;
  float4 o = build_row(bos, pos_emb, tok_emb, tok, stval, b, s, d0, step);
  *(float4*)(x + (size_t)row * ND + d0) = o;
  ln_core_emit16(o, w, bvec, sbuf, Oh, Ol, (size_t)row * ND, d0);
}

// ======================= SwiGLU (fallback) ==============================
__global__ __launch_bounds__(256) void k_swiglu(const float* __restrict__ u,
                                                float* __restrict__ m) {
  const size_t idx4 = (size_t)blockIdx.x * 256 + threadIdx.x;
  const size_t row = idx4 >> 9;
  const size_t c0 = (idx4 & 511) << 2;
  const float* ur = u + row * (2 * NHID);
  float4 a4 = *(const float4*)(ur + c0);
  float4 b4 = *(const float4*)(ur + NHID + c0);
  float4 o;
  { float s = 1.0f / (1.0f + expf(-a4.x)); o.x = (a4.x * s) * b4.x; }
  { float s = 1.0f / (1.0f + expf(-a4.y)); o.y = (a4.y * s) * b4.y; }
  { float s = 1.0f / (1.0f + expf(-a4.z)); o.z = (a4.z * s) * b4.z; }
  { float s = 1.0f / (1.0f + expf(-a4.w)); o.w = (a4.w * s) * b4.w; }
  *(float4*)(m + row * NHID + c0) = o;
}

// ======================= gumbel + argmax + st ===========================
// GRED=1: logits = sum of 3 partials (stride 896*1024) + bias
template<int GRED>
__global__ __launch_bounds__(256) void k_gumbel_t(
    const float* __restrict__ logits, const float* __restrict__ vb,
    int* __restrict__ tok, float* __restrict__ stval, float* __restrict__ out,
    int step, int finalstep) {
  const int blk = blockIdx.x;
  const int tid = threadIdx.x;
  uint32_t fk0, fk1;
  threefry2x32(0u, 42u, 0u, (uint32_t)step, fk0, fk1);
  const float* zrow = logits + (size_t)blk * NV;
  const size_t MN = (size_t)896 * 1024;
  float y[4];
  float bv = -INFINITY; int bi = 0;
#pragma unroll
  for (int j = 0; j < 4; ++j) {
    const int v = tid + (j << 8);
    const uint32_t idx = (uint32_t)blk * 1024u + (uint32_t)v;
    uint32_t o0, o1, bits;
#if JAX_PARTITIONABLE
    threefry2x32(fk0, fk1, 0u, idx, o0, o1);
    bits = o0 ^ o1;
#else
    const uint32_t half = (uint32_t)(NB * NC * NV / 2);
    uint32_t jj = (idx < half) ? idx : idx - half;
    threefry2x32(fk0, fk1, jj, jj + half, o0, o1);
    bits = (idx < half) ? o0 : o1;
#endif
    float f = __uint_as_float(0x3F800000u | (bits >> 9)) - 1.0f;
    float uu = (f == 0.0f) ? 1.17549435e-38f : f;
    float g = -logf(-logf(uu));
    float z;
    if (GRED) z = zrow[v] + zrow[MN + v] + zrow[2 * MN + v] + vb[v];
    else      z = zrow[v];
    float yv = z + g;
    y[j] = yv;
    if (yv > bv) { bv = yv; bi = v; }
  }
  __shared__ float swv[4]; __shared__ int swi[4];
  __shared__ float s_ymax; __shared__ int s_arg;
  for (int off = 32; off > 0; off >>= 1) {
    float ov = __shfl_down(bv, off, 64);
    int   oi = __shfl_down(bi, off, 64);
    if (ov > bv || (ov == bv && oi < bi)) { bv = ov; bi = oi; }
  }
  if ((tid & 63) == 0) { swv[tid >> 6] = bv; swi[tid >> 6] = bi; }
  __syncthreads();
  if (tid == 0) {
    float mv = swv[0]; int mi = swi[0];
    for (int w2 = 1; w2 < 4; ++w2)
      if (swv[w2] > mv || (swv[w2] == mv && swi[w2] < mi)) { mv = swv[w2]; mi = swi[w2]; }
    s_ymax = mv; s_arg = mi;
  }
  __syncthreads();
  const float ymax = s_ymax;
  float es = 0.f;
#pragma unroll
  for (int j = 0; j < 4; ++j) es += expf(y[j] - ymax);
  __shared__ float sbuf2[4]; __shared__ float s_es;
  for (int off = 32; off > 0; off >>= 1) es += __shfl_down(es, off, 64);
  if ((tid & 63) == 0) sbuf2[tid >> 6] = es;
  __syncthreads();
  if (tid == 0) s_es = sbuf2[0] + sbuf2[1] + sbuf2[2] + sbuf2[3];
  __syncthreads();
  const float esum = s_es;
  const float sprob = 0.9f * (1.0f / esum) + (0.1f / 1024.0f);
  const float stv = (1.0f - sprob) + sprob;
  if (tid == 0) { tok[blk] = s_arg; stval[blk] = stv; }
  if (finalstep) {
    const int b = blk / NC, c = blk % NC;
    float* orow = out + ((size_t)b * (NC + 2) + 1 + c) * NV;
#pragma unroll
    for (int j = 0; j < 4; ++j) {
      const int v = tid + (j << 8);
      orow[v] = (v == s_arg) ? stv : 0.0f;
    }
  }
}

__global__ __launch_bounds__(256) void k_out_init(float* __restrict__ out) {
  const int b = blockIdx.x;
  const int tid = threadIdx.x;
#pragma unroll
  for (int j = 0; j < 4; ++j) {
    const int v = tid + (j << 8);
    out[((size_t)b * (NC + 2) + 0) * NV + v]      = (v == 0) ? 1.0f : 0.0f;
    out[((size_t)b * (NC + 2) + NC + 1) * NV + v] = (v == 1) ? 1.0f : 0.0f;
  }
}

// ======================= host orchestration =============================
extern "C" void kernel_launch(void* const* d_in, const int* in_sizes, int n_in,
                              void* d_out, int out_size, void* d_ws, size_t ws_size,
                              hipStream_t stream) {
  (void)in_sizes; (void)n_in; (void)out_size;
  const float* prototypes = (const float*)d_in[0];
  const float* query      = (const float*)d_in[1];
  const float* ca_wq      = (const float*)d_in[2];
  const float* ca_wk      = (const float*)d_in[3];
  const float* ca_wv      = (const float*)d_in[4];
  const float* ca_wo      = (const float*)d_in[5];
  const float* ln1_w      = (const float*)d_in[6];
  const float* ln1_b      = (const float*)d_in[7];
  const float* qkv_w      = (const float*)d_in[8];
  const float* attn_out_w = (const float*)d_in[9];
  const float* rel_bias   = (const float*)d_in[10];
  const float* ln2_w      = (const float*)d_in[11];
  const float* ln2_b      = (const float*)d_in[12];
  const float* mlp_w1     = (const float*)d_in[13];
  const float* mlp_w2     = (const float*)d_in[14];
  const float* lnf_w      = (const float*)d_in[15];
  const float* lnf_b      = (const float*)d_in[16];
  const float* vocab_w    = (const float*)d_in[17];
  const float* vocab_b    = (const float*)d_in[18];
  const float* pos_emb    = (const float*)d_in[19];
  const float* tok_emb    = (const float*)d_in[20];
  float* out = (float*)d_out;

  dim3 thr(256);
  dim3 thr512(512);
  const size_t NEED = 234889216ull;

  if (ws_size >= NEED) {
    // ---------------- fast path: fp16x3 MFMA (ring-4 prefetch) ----------------
    char* p = (char*)d_ws;
    auto alloc = [&](size_t bytes) { char* r = p; p += (bytes + 255) & ~(size_t)255; return r; };
    half_t *WqH[NL], *WqL[NL], *WaH[NL], *WaL[NL], *W1H[NL], *W1L[NL], *W2H[NL], *W2L[NL];
    for (int l = 0; l < NL; ++l) {
      WqH[l] = (half_t*)alloc(3072 * 1024 * 2);
      WqL[l] = (half_t*)alloc(3072 * 1024 * 2);
      WaH[l] = (half_t*)alloc(1024 * 1024 * 2);
      WaL[l] = (half_t*)alloc(1024 * 1024 * 2);
      W1H[l] = (half_t*)alloc(4096 * 1024 * 2);
      W1L[l] = (half_t*)alloc(4096 * 1024 * 2);
      W2H[l] = (half_t*)alloc(1024 * 2048 * 2);
      W2L[l] = (half_t*)alloc(1024 * 2048 * 2);
    }
    half_t* WvH = (half_t*)alloc(1024 * 1024 * 2);
    half_t* WvL = (half_t*)alloc(1024 * 1024 * 2);
    half_t* Hh  = (half_t*)alloc(1920 * 1024 * 2);   // also hosts lnf rows (896x1024)
    half_t* Hl  = (half_t*)alloc(1920 * 1024 * 2);
    float* X    = (float*)alloc(1920 * 1024 * 4);
    float* QKV  = (float*)alloc(1920 * 3072 * 4);    // aliases qkv planes + PARTS + prologue
    half_t* Mh  = (half_t*)alloc(1920 * 2048 * 2);
    half_t* Ml  = (half_t*)alloc(1920 * 2048 * 2);
    float* LG   = (float*)alloc(896 * 1024 * 4);     // unused (kept for layout stability)
    float* BOSb = (float*)alloc(64 * 16 * 1024 * 4);
    float* STV  = (float*)alloc(4096);
    int*   TOK  = (int*)alloc(4096);
    (void)LG;
    float* PARTS = QKV;
    half_t* QKVh = (half_t*)QKV;                       // (1920,3072) planes
    half_t* QKVl = QKVh + (size_t)1920 * 3072;

    // ---- weight split (per launch; graph-captured) ----
    for (int l = 0; l < NL; ++l) {
      k_splitw<<<dim3(32, 96), thr, 0, stream>>>(qkv_w + (size_t)l * ND * 3 * ND, WqH[l], WqL[l], 1024, 3072);
      k_splitw<<<dim3(32, 32), thr, 0, stream>>>(attn_out_w + (size_t)l * ND * ND, WaH[l], WaL[l], 1024, 1024);
      k_splitw_swz<<<dim3(32, 128), thr, 0, stream>>>(mlp_w1 + (size_t)l * ND * 2 * NHID, W1H[l], W1L[l], 1024, 4096);
      k_splitw<<<dim3(64, 32), thr, 0, stream>>>(mlp_w2 + (size_t)l * NHID * ND, W2H[l], W2L[l], 2048, 1024);
    }
    k_splitw<<<dim3(32, 32), thr, 0, stream>>>(vocab_w, WvH, WvL, 1024, 1024);

    // ---- cross attention prologue (fp32, scratch inside QKV) ----
    float* QH = QKV;
    float* KH = QKV + 16384;
    float* VH = QKV + 540672;
    float* BOSW = QKV + 1064960;
    k_gemm<<<dim3(16, 1),  thr, 0, stream>>>(query,      ca_wq, QH,   nullptr, NBOS,    ND, ND, 0);
    k_gemm<<<dim3(16, 8),  thr, 0, stream>>>(prototypes, ca_wk, KH,   nullptr, NB * NP, ND, ND, 0);
    k_gemm<<<dim3(16, 8),  thr, 0, stream>>>(prototypes, ca_wv, VH,   nullptr, NB * NP, ND, ND, 0);
    k_ca_attn<<<dim3(NB * NH), thr, 0, stream>>>(QH, KH, VH, BOSW);
    k_gemm<<<dim3(16, 16), thr, 0, stream>>>(BOSW, ca_wo, BOSb, nullptr, NB * NBOS, ND, ND, 0);
    k_out_init<<<dim3(NB), thr, 0, stream>>>(out);

    // ---- 14 autoregressive steps ----
    for (int i = 0; i < NC; ++i) {
      k_build_ln<<<dim3(NB * NS), thr, 0, stream>>>(BOSb, pos_emb, tok_emb, TOK, STV,
                                                    ln1_w, ln1_b, X, Hh, Hl, i);
      for (int l = 0; l < NL; ++l) {
        k_g3<2><<<dim3(24, 15, 1), thr512, 0, stream>>>(Hh, Hl, WqH[l], WqL[l], nullptr, QKVh, QKVl,
                                                        1920, 3072, 1024, 1024);
        k_attn16p<<<dim3(NB * NH), thr, 0, stream>>>(QKVh, QKVl, rel_bias + (size_t)l * (2 * NS - 1) * NH, Hh, Hl);
        k_g3<0><<<dim3(8, 15, 3), thr512, 0, stream>>>(Hh, Hl, WaH[l], WaL[l], PARTS, nullptr, nullptr,
                                                       1920, 1024, 1024, 352);
        k_red_ln<1><<<dim3(1920), thr, 0, stream>>>(PARTS, X, ln2_w + l * ND, ln2_b + l * ND, Hh, Hl);
        k_g3<1><<<dim3(32, 15, 1), thr512, 0, stream>>>(Hh, Hl, W1H[l], W1L[l], nullptr, Mh, Ml,
                                                        1920, 4096, 1024, 1024);
        k_g3<0><<<dim3(8, 15, 3), thr512, 0, stream>>>(Mh, Ml, W2H[l], W2L[l], PARTS, nullptr, nullptr,
                                                       1920, 1024, 2048, 704);
        if (l < NL - 1)
          k_red_ln<1><<<dim3(1920), thr, 0, stream>>>(PARTS, X, ln1_w + (l + 1) * ND, ln1_b + (l + 1) * ND, Hh, Hl);
      }
      k_red_lnf<<<dim3(NB * NC), thr, 0, stream>>>(PARTS, X, lnf_w, lnf_b, Hh, Hl);
      k_g3<0><<<dim3(8, 7, 3), thr512, 0, stream>>>(Hh, Hl, WvH, WvL, PARTS, nullptr, nullptr,
                                                    896, 1024, 1024, 352);
      k_gumbel_t<1><<<dim3(NB * NC), thr, 0, stream>>>(PARTS, vocab_b, TOK, STV, out, i, (i == NC - 1) ? 1 : 0);
    }
    return;
  }

  // ---------------- fallback: round-1 fp32 path ----------------
  float* ws = (float*)d_ws;
  float* BOSW = ws + 0;
  float* BOSb = ws + 1048576;
  float* QH   = ws + 2097152;
  float* KH   = ws + 2113536;
  float* VH   = ws + 2637824;
  float* X    = ws + 3162112;
  float* Hb   = ws + 5128192;
  float* HL   = Hb;
  float* LG   = Hb + 917504;
  float* QKV  = ws + 7094272;
  float* U    = QKV;
  float* ATT  = ws + 14958592;
  float* Mb   = ATT;
  float* STV  = ws + 18890752;
  int*   TOK  = (int*)(ws + 18891648);

  k_gemm<<<dim3(16, 1),  thr, 0, stream>>>(query,      ca_wq, QH,   nullptr, NBOS,    ND, ND, 0);
  k_gemm<<<dim3(16, 8),  thr, 0, stream>>>(prototypes, ca_wk, KH,   nullptr, NB * NP, ND, ND, 0);
  k_gemm<<<dim3(16, 8),  thr, 0, stream>>>(prototypes, ca_wv, VH,   nullptr, NB * NP, ND, ND, 0);
  k_ca_attn<<<dim3(NB * NH), thr, 0, stream>>>(QH, KH, VH, BOSW);
  k_gemm<<<dim3(16, 16), thr, 0, stream>>>(BOSW, ca_wo, BOSb, nullptr, NB * NBOS, ND, ND, 0);
  k_out_init<<<dim3(NB), thr, 0, stream>>>(out);

  for (int i = 0; i < NC; ++i) {
    k_build_x<<<dim3(NB * NS), thr, 0, stream>>>(BOSb, pos_emb, tok_emb, TOK, STV, X, i);
    for (int l = 0; l < NL; ++l) {
      k_ln<<<dim3(NB * NS), thr, 0, stream>>>(X, ln1_w + l * ND, ln1_b + l * ND, Hb);
      k_gemm<<<dim3(48, 30), thr, 0, stream>>>(Hb, qkv_w + (size_t)l * ND * 3 * ND, QKV,
                                               nullptr, NB * NS, 3 * ND, ND, 0);
      k_attn<<<dim3(NB * NH), thr, 0, stream>>>(QKV, rel_bias + (size_t)l * (2 * NS - 1) * NH, ATT);
      k_gemm<<<dim3(16, 30), thr, 0, stream>>>(ATT, attn_out_w + (size_t)l * ND * ND, X,
                                               nullptr, NB * NS, ND, ND, 1);
      k_ln<<<dim3(NB * NS), thr, 0, stream>>>(X, ln2_w + l * ND, ln2_b + l * ND, Hb);
      k_gemm<<<dim3(64, 30), thr, 0, stream>>>(Hb, mlp_w1 + (size_t)l * ND * 2 * NHID, U,
                                               nullptr, NB * NS, 2 * NHID, ND, 0);
      k_swiglu<<<dim3(3840), thr, 0, stream>>>(U, Mb);
      k_gemm<<<dim3(16, 30), thr, 0, stream>>>(Mb, mlp_w2 + (size_t)l * NHID * ND, X,
                                               nullptr, NB * NS, ND, NHID, 1);
    }
    k_lnf<<<dim3(NB * NC), thr, 0, stream>>>(X, lnf_w, lnf_b, HL);
    k_gemm<<<dim3(16, 14), thr, 0, stream>>>(HL, vocab_w, LG, vocab_b, NB * NC, NV, ND, 2);
    k_gumbel_t<0><<<dim3(NB * NC), thr, 0, stream>>>(LG, nullptr, TOK, STV, out, i, (i == NC - 1) ? 1 : 0);
  }
}

// Round 10
// 10430.872 us; speedup vs baseline: 1.4499x; 1.4499x over previous
//
#include <hip/hip_runtime.h>
#include <stdint.h>
#include <stddef.h>
#include <math.h>

// ---- problem dims ----
#define NB   64
#define NP   8
#define ND   1024
#define NH   16
#define NBOS 16
#define NC   14
#define NS   30   // BOS + C
#define NL   4
#define NV   1024
#define NHID 2048
#define NDH  64

#define JAX_PARTITIONABLE 1

typedef _Float16 half_t;
typedef _Float16 h4_t __attribute__((ext_vector_type(4)));
typedef _Float16 h8_t __attribute__((ext_vector_type(8)));
typedef float f32x4 __attribute__((ext_vector_type(4)));

// ======================= threefry2x32 (JAX-exact) =======================
__device__ __forceinline__ uint32_t rotl32(uint32_t x, int d) {
  return (x << d) | (x >> (32 - d));
}

__device__ __forceinline__ void threefry2x32(uint32_t k0, uint32_t k1,
                                             uint32_t x0, uint32_t x1,
                                             uint32_t& o0, uint32_t& o1) {
  uint32_t ks2 = k0 ^ k1 ^ 0x1BD11BDAu;
  x0 += k0; x1 += k1;
#define TF_R4(a,b,c,d) \
  x0 += x1; x1 = rotl32(x1,(a)); x1 ^= x0; \
  x0 += x1; x1 = rotl32(x1,(b)); x1 ^= x0; \
  x0 += x1; x1 = rotl32(x1,(c)); x1 ^= x0; \
  x0 += x1; x1 = rotl32(x1,(d)); x1 ^= x0;
  TF_R4(13,15,26,6)  x0 += k1;  x1 += ks2 + 1u;
  TF_R4(17,29,16,24) x0 += ks2; x1 += k0 + 2u;
  TF_R4(13,15,26,6)  x0 += k0;  x1 += k1 + 3u;
  TF_R4(17,29,16,24) x0 += k1;  x1 += ks2 + 4u;
  TF_R4(13,15,26,6)  x0 += ks2; x1 += k0 + 5u;
#undef TF_R4
  o0 = x0; o1 = x1;
}

// ======================= generic fp32 GEMM (prologue + fallback) ========
__global__ __launch_bounds__(256) void k_gemm(
    const float* __restrict__ A, const float* __restrict__ Bm,
    float* __restrict__ Cm, const float* __restrict__ bias,
    int M, int N, int K, int epi) {
  __shared__ __align__(16) float As[16][64];
  __shared__ __align__(16) float Bs[16][64];
  const int tid = threadIdx.x;
  const int tx = tid & 15, ty = tid >> 4;
  const int m0 = blockIdx.y * 64, n0 = blockIdx.x * 64;
  const int lar = tid >> 2, lak = (tid & 3) << 2;
  const int lbk = tid >> 4, lbn = (tid & 15) << 2;
  float acc[4][4] = {};
  for (int kt = 0; kt < K; kt += 16) {
    float4 av = make_float4(0.f, 0.f, 0.f, 0.f);
    if (m0 + lar < M)
      av = *(const float4*)(A + (size_t)(m0 + lar) * K + kt + lak);
    float4 bv4 = make_float4(0.f, 0.f, 0.f, 0.f);
    if (n0 + lbn < N)
      bv4 = *(const float4*)(Bm + (size_t)(kt + lbk) * N + n0 + lbn);
    __syncthreads();
    As[lak + 0][lar] = av.x; As[lak + 1][lar] = av.y;
    As[lak + 2][lar] = av.z; As[lak + 3][lar] = av.w;
    *(float4*)(&Bs[lbk][lbn]) = bv4;
    __syncthreads();
#pragma unroll
    for (int kk = 0; kk < 16; ++kk) {
      float4 a4 = *(const float4*)(&As[kk][ty << 2]);
      float4 b4 = *(const float4*)(&Bs[kk][tx << 2]);
      float ar[4] = {a4.x, a4.y, a4.z, a4.w};
      float br[4] = {b4.x, b4.y, b4.z, b4.w};
#pragma unroll
      for (int i2 = 0; i2 < 4; ++i2)
#pragma unroll
        for (int j2 = 0; j2 < 4; ++j2)
          acc[i2][j2] = fmaf(ar[i2], br[j2], acc[i2][j2]);
    }
  }
#pragma unroll
  for (int i2 = 0; i2 < 4; ++i2) {
    int r = m0 + (ty << 2) + i2;
    if (r >= M) continue;
#pragma unroll
    for (int j2 = 0; j2 < 4; ++j2) {
      int c = n0 + (tx << 2) + j2;
      if (c >= N) continue;
      size_t off = (size_t)r * N + c;
      float val = acc[i2][j2];
      if (epi == 1) val += Cm[off];
      else if (epi == 2) val += bias[c];
      Cm[off] = val;
    }
  }
}

// ======================= fp16x3 MFMA GEMM (128x128, 8-wave, vmcnt) ======
// (R8 core: 2-buffer, counted vmcnt(4), 64 KB LDS -> 2 blocks/CU)
__device__ __forceinline__ void gload16(const void* g, const void* l) {
  __builtin_amdgcn_global_load_lds((const __attribute__((address_space(1))) void*)g,
                                   (__attribute__((address_space(3))) void*)l, 16, 0, 0);
}

// XCD-aware chunked swizzle (per z-slice). gx must be %8==0.
__device__ __forceinline__ void xcd_swz(int gx, int gy, int& bx, int& by) {
  const int flat = blockIdx.y * gx + blockIdx.x;
  const int chunk = (gx * gy) >> 3;
  const int myid = (flat & 7) * chunk + (flat >> 3);
  bx = myid / gy;
  by = myid % gy;
}

// EPI 0: store partial fp32*(1/1024) at Cout + z*M*N
// EPI 1: fused SwiGLU -> Mh/Ml (col-permuted W1 layout), full-K only
// EPI 2: store split fp16 planes (raw value) -> Mh/Ml, full-K only
template<int EPI>
__global__ __launch_bounds__(512) void k_g3(
    const half_t* __restrict__ Ah, const half_t* __restrict__ Al,
    const half_t* __restrict__ Bh, const half_t* __restrict__ Bl,
    float* __restrict__ Cout, half_t* __restrict__ Mh, half_t* __restrict__ Ml,
    int M, int N, int K, int CH) {
  __shared__ __align__(16) half_t sAh[2][4096];
  __shared__ __align__(16) half_t sAl[2][4096];
  __shared__ __align__(16) half_t sBh[2][4096];
  __shared__ __align__(16) half_t sBl[2][4096];
  int bx, by; xcd_swz(gridDim.x, gridDim.y, bx, by);
  const int tid = threadIdx.x;
  const int lane = tid & 63, w = tid >> 6;       // 8 waves
  const int wm = w >> 2, wn = w & 3;             // 2 x 4 wave grid
  const int m0 = by * 128, n0 = bx * 128;
  const int fr = lane & 15, fq = lane >> 4;
  const int kbeg = blockIdx.z * CH;
  const int kend = (kbeg + CH < K) ? (kbeg + CH) : K;
  f32x4 acc[4][2] = {};
  const int r0 = tid >> 2, ch = (tid & 3) * 8;
  const size_t aB = (size_t)(m0 + r0) * K + ch;
  const size_t bB = (size_t)(n0 + r0) * K + ch;
  const int wb = w * 1024;   // per-wave dest byte offset within 8KB plane

  auto STAGE = [&](int buf, int kt) {   // 4 loads/thread (one per plane)
    gload16(Ah + aB + kt, (char*)(&sAh[buf][0]) + wb);
    gload16(Al + aB + kt, (char*)(&sAl[buf][0]) + wb);
    gload16(Bh + bB + kt, (char*)(&sBh[buf][0]) + wb);
    gload16(Bl + bB + kt, (char*)(&sBl[buf][0]) + wb);
  };

  STAGE(0, kbeg);                                  // 4 outstanding
  int cur = 0;
  for (int kt = kbeg; kt < kend; kt += 32) {
    const bool has_next = (kt + 32 < kend);
    if (has_next) {
      STAGE(cur ^ 1, kt + 32);                     // +4 -> 8 outstanding
      asm volatile("s_waitcnt vmcnt(4)" ::: "memory");   // cur's 4 done
    } else {
      asm volatile("s_waitcnt vmcnt(0)" ::: "memory");
    }
    asm volatile("s_barrier" ::: "memory");        // all waves' cur staged
    const half_t* bAh = &sAh[cur][0] + (wm * 64 + fr) * 32 + fq * 8;
    const half_t* bAl = &sAl[cur][0] + (wm * 64 + fr) * 32 + fq * 8;
    const half_t* bBh = &sBh[cur][0] + (wn * 32 + fr) * 32 + fq * 8;
    const half_t* bBl = &sBl[cur][0] + (wn * 32 + fr) * 32 + fq * 8;
    h8_t a[4], b[2], t[2];
#pragma unroll
    for (int mi = 0; mi < 4; ++mi) a[mi] = *(const h8_t*)(bAh + mi * 512);
#pragma unroll
    for (int ni = 0; ni < 2; ++ni) b[ni] = *(const h8_t*)(bBh + ni * 512);
#pragma unroll
    for (int mi = 0; mi < 4; ++mi)
#pragma unroll
      for (int ni = 0; ni < 2; ++ni)
        acc[mi][ni] = __builtin_amdgcn_mfma_f32_16x16x32_f16(a[mi], b[ni], acc[mi][ni], 0, 0, 0);
#pragma unroll
    for (int ni = 0; ni < 2; ++ni) t[ni] = *(const h8_t*)(bBl + ni * 512);
#pragma unroll
    for (int mi = 0; mi < 4; ++mi)
#pragma unroll
      for (int ni = 0; ni < 2; ++ni)
        acc[mi][ni] = __builtin_amdgcn_mfma_f32_16x16x32_f16(a[mi], t[ni], acc[mi][ni], 0, 0, 0);
#pragma unroll
    for (int mi = 0; mi < 4; ++mi) a[mi] = *(const h8_t*)(bAl + mi * 512);
    asm volatile("s_barrier" ::: "memory");
#pragma unroll
    for (int mi = 0; mi < 4; ++mi)
#pragma unroll
      for (int ni = 0; ni < 2; ++ni)
        acc[mi][ni] = __builtin_amdgcn_mfma_f32_16x16x32_f16(a[mi], b[ni], acc[mi][ni], 0, 0, 0);
    cur ^= 1;
  }
  const float sc = 1.0f / 1024.0f;
  if (EPI == 0) {
    float* Cz = Cout + (size_t)blockIdx.z * M * N;
#pragma unroll
    for (int mi = 0; mi < 4; ++mi) {
      const int row = m0 + wm * 64 + mi * 16 + fq * 4;
#pragma unroll
      for (int ni = 0; ni < 2; ++ni) {
        const int col = n0 + wn * 32 + ni * 16 + fr;
        float* cp = Cz + (size_t)row * N + col;
#pragma unroll
        for (int j = 0; j < 4; ++j) cp[(size_t)j * N] = acc[mi][ni][j] * sc;
      }
    }
  } else if (EPI == 1) {
    const int hid = ((n0 + wn * 32) >> 1) + fr;
#pragma unroll
    for (int mi = 0; mi < 4; ++mi) {
      const int row = m0 + wm * 64 + mi * 16 + fq * 4;
#pragma unroll
      for (int j = 0; j < 4; ++j) {
        const float u1 = acc[mi][0][j] * sc;
        const float u2 = acc[mi][1][j] * sc;
        const float s = 1.0f / (1.0f + expf(-u1));
        const float y = (u1 * s) * u2 * 16.0f;
        const half_t hv = (half_t)y;
        const size_t off = (size_t)(row + j) * NHID + hid;
        Mh[off] = hv;
        Ml[off] = (half_t)(y - (float)hv);
      }
    }
  } else {
#pragma unroll
    for (int mi = 0; mi < 4; ++mi) {
      const int row = m0 + wm * 64 + mi * 16 + fq * 4;
#pragma unroll
      for (int ni = 0; ni < 2; ++ni) {
        const int col = n0 + wn * 32 + ni * 16 + fr;
#pragma unroll
        for (int j = 0; j < 4; ++j) {
          const float v = acc[mi][ni][j] * sc;
          const half_t hv = (half_t)v;
          const size_t off = (size_t)(row + j) * N + col;
          Mh[off] = hv;
          Ml[off] = (half_t)(v - (float)hv);
        }
      }
    }
  }
}

// ---- weight split: W:(K,N) fp32 -> Th,Tl:(N,K) fp16 x64 ----
__global__ __launch_bounds__(256) void k_splitw(
    const float* __restrict__ W, half_t* __restrict__ Th, half_t* __restrict__ Tl,
    int K, int N) {
  __shared__ float t[32][33];
  const int kb = blockIdx.x * 32, nb = blockIdx.y * 32;
  const int tid = threadIdx.x;
  const int rr = tid >> 5, cc = tid & 31;
#pragma unroll
  for (int i = 0; i < 4; ++i)
    t[rr + i * 8][cc] = W[(size_t)(kb + rr + i * 8) * N + nb + cc];
  __syncthreads();
#pragma unroll
  for (int i = 0; i < 4; ++i) {
    const int nr = rr + i * 8;
    const float x = t[cc][nr] * 64.0f;
    const half_t h = (half_t)x;
    const float r = x - (float)h;
    const size_t off = (size_t)(nb + nr) * K + kb + cc;
    Th[off] = h;
    Tl[off] = (half_t)r;
  }
}

// variant for mlp_w1: logical col n -> physical row p for swiglu pairing
__global__ __launch_bounds__(256) void k_splitw_swz(
    const float* __restrict__ W, half_t* __restrict__ Th, half_t* __restrict__ Tl,
    int K, int N) {
  __shared__ float t[32][33];
  const int kb = blockIdx.x * 32, nb = blockIdx.y * 32;
  const int tid = threadIdx.x;
  const int rr = tid >> 5, cc = tid & 31;
#pragma unroll
  for (int i = 0; i < 4; ++i)
    t[rr + i * 8][cc] = W[(size_t)(kb + rr + i * 8) * N + nb + cc];
  __syncthreads();
#pragma unroll
  for (int i = 0; i < 4; ++i) {
    const int n = nb + rr + i * 8;
    const int hid = n & (NHID - 1), half = n >> 11;
    const int p = ((hid >> 4) << 5) + (half << 4) + (hid & 15);
    const float x = t[cc][rr + i * 8] * 64.0f;
    const half_t h = (half_t)x;
    const float r = x - (float)h;
    const size_t off = (size_t)p * K + kb + cc;
    Th[off] = h;
    Tl[off] = (half_t)r;
  }
}

// ======================= cross attention (builds BOS) ===================
__global__ __launch_bounds__(256) void k_ca_attn(
    const float* __restrict__ qh, const float* __restrict__ kh,
    const float* __restrict__ vh, float* __restrict__ bosw) {
  const int b = blockIdx.x >> 4, h = blockIdx.x & 15;
  __shared__ float q[NBOS][NDH], kk[NP][NDH], vv[NP][NDH], a[NBOS][NP];
  const int tid = threadIdx.x;
  for (int idx = tid; idx < NBOS * NDH; idx += 256) {
    int qi = idx >> 6, d = idx & 63;
    q[qi][d] = qh[(size_t)qi * ND + h * NDH + d];
  }
  for (int idx = tid; idx < NP * NDH; idx += 256) {
    int p = idx >> 6, d = idx & 63;
    kk[p][d] = kh[(size_t)(b * NP + p) * ND + h * NDH + d];
    vv[p][d] = vh[(size_t)(b * NP + p) * ND + h * NDH + d];
  }
  __syncthreads();
  if (tid < NBOS * NP) {
    int qi = tid >> 3, p = tid & 7;
    float dot = 0.f;
    for (int d = 0; d < NDH; ++d) dot = fmaf(q[qi][d], kk[p][d], dot);
    a[qi][p] = dot / 64.0f;
  }
  __syncthreads();
  if (tid < NBOS) {
    float mx = a[tid][0];
    for (int p = 1; p < NP; ++p) mx = fmaxf(mx, a[tid][p]);
    float sum = 0.f;
    for (int p = 0; p < NP; ++p) { float e = expf(a[tid][p] - mx); a[tid][p] = e; sum += e; }
    for (int p = 0; p < NP; ++p) a[tid][p] /= sum;
  }
  __syncthreads();
  for (int idx = tid; idx < NBOS * NDH; idx += 256) {
    int qi = idx >> 6, d = idx & 63;
    float o = 0.f;
    for (int p = 0; p < NP; ++p) o = fmaf(a[qi][p], vv[p][d], o);
    bosw[(size_t)(b * NBOS + qi) * ND + h * NDH + d] = o;
  }
}

// ======================= self attention (fallback fp32 qkv) =============
__global__ __launch_bounds__(256) void k_attn(
    const float* __restrict__ qkv, const float* __restrict__ relb,
    float* __restrict__ attout) {
  const int b = blockIdx.x >> 4, h = blockIdx.x & 15;
  __shared__ float q[NS][NDH], kk[NS][NDH], vv[NS][NDH];
  __shared__ float a[NS][NS];
  const int tid = threadIdx.x;
  for (int idx = tid; idx < NS * NDH; idx += 256) {
    int s = idx >> 6, d = idx & 63;
    size_t base = ((size_t)(b * NS + s) * 3) * ND + h * NDH + d;
    q[s][d]  = qkv[base];
    kk[s][d] = qkv[base + ND];
    vv[s][d] = qkv[base + 2 * ND];
  }
  __syncthreads();
  for (int idx = tid; idx < NS * NS; idx += 256) {
    int i = idx / NS, j = idx % NS;
    float sc = 0.f;
    if (j <= i) {
      float dot = 0.f;
      for (int d = 0; d < NDH; ++d) dot = fmaf(q[i][d], kk[j][d], dot);
      sc = dot * 0.125f + relb[(size_t)(i - j + NS - 1) * NH + h];
    }
    a[i][j] = sc;
  }
  __syncthreads();
  if (tid < NS) {
    const int i = tid;
    float mx = -INFINITY;
    for (int j = 0; j <= i; ++j) mx = fmaxf(mx, a[i][j]);
    float sum = 0.f;
    for (int j = 0; j <= i; ++j) { float e = expf(a[i][j] - mx); a[i][j] = e; sum += e; }
    for (int j = 0; j <= i; ++j) a[i][j] /= sum;
    for (int j = i + 1; j < NS; ++j) a[i][j] = 0.f;
  }
  __syncthreads();
  for (int idx = tid; idx < NS * NDH; idx += 256) {
    int i = idx >> 6, d = idx & 63;
    float o = 0.f;
    for (int j = 0; j < NS; ++j) o = fmaf(a[i][j], vv[j][d], o);
    attout[(size_t)(b * NS + i) * ND + h * NDH + d] = o;
  }
}

// self attention on packed S rows, split qkv planes -> split out planes (x16)
__global__ __launch_bounds__(256) void k_attn16p(
    const half_t* __restrict__ Qh, const half_t* __restrict__ Ql,
    const float* __restrict__ relb,
    half_t* __restrict__ Oh, half_t* __restrict__ Ol, int S) {
  const int b = blockIdx.x >> 4, h = blockIdx.x & 15;
  __shared__ float q[NS][NDH], kk[NS][NDH], vv[NS][NDH];
  __shared__ float a[NS][NS];
  const int tid = threadIdx.x;
  for (int idx = tid; idx < S * NDH; idx += 256) {
    int s = idx >> 6, d = idx & 63;
    size_t base = (size_t)(b * S + s) * 3072 + h * NDH + d;
    q[s][d]  = (float)Qh[base] + (float)Ql[base];
    kk[s][d] = (float)Qh[base + 1024] + (float)Ql[base + 1024];
    vv[s][d] = (float)Qh[base + 2048] + (float)Ql[base + 2048];
  }
  __syncthreads();
  for (int idx = tid; idx < S * S; idx += 256) {
    int i = idx / S, j = idx % S;
    float sc = 0.f;
    if (j <= i) {
      float dot = 0.f;
      for (int d = 0; d < NDH; ++d) dot = fmaf(q[i][d], kk[j][d], dot);
      sc = dot * 0.125f + relb[(size_t)(i - j + NS - 1) * NH + h];
    }
    a[i][j] = sc;
  }
  __syncthreads();
  if (tid < S) {
    const int i = tid;
    float mx = -INFINITY;
    for (int j = 0; j <= i; ++j) mx = fmaxf(mx, a[i][j]);
    float sum = 0.f;
    for (int j = 0; j <= i; ++j) { float e = expf(a[i][j] - mx); a[i][j] = e; sum += e; }
    for (int j = 0; j <= i; ++j) a[i][j] /= sum;
    for (int j = i + 1; j < S; ++j) a[i][j] = 0.f;
  }
  __syncthreads();
  for (int idx = tid; idx < S * NDH; idx += 256) {
    int i = idx >> 6, d = idx & 63;
    float o = 0.f;
    for (int j = 0; j < S; ++j) o = fmaf(a[i][j], vv[j][d], o);
    const float y = o * 16.0f;
    const half_t hv = (half_t)y;
    const size_t off = (size_t)(b * S + i) * ND + h * NDH + d;
    Oh[off] = hv;
    Ol[off] = (half_t)(y - (float)hv);
  }
}

// ======================= layernorm cores ================================
__device__ __forceinline__ float block_sum(float val, float* sbuf) {
  for (int off = 32; off > 0; off >>= 1) val += __shfl_down(val, off, 64);
  const int wid = threadIdx.x >> 6;
  if ((threadIdx.x & 63) == 0) sbuf[wid] = val;
  __syncthreads();
  if (threadIdx.x == 0) sbuf[0] = sbuf[0] + sbuf[1] + sbuf[2] + sbuf[3];
  __syncthreads();
  float r = sbuf[0];
  __syncthreads();
  return r;
}

__device__ __forceinline__ void ln_core_emit16(
    float4 x4, const float* w, const float* bvec, float* sbuf,
    half_t* Oh, half_t* Ol, size_t rowoff, int d0) {
  float mean = block_sum(x4.x + x4.y + x4.z + x4.w, sbuf) * (1.0f / 1024.0f);
  float dx0 = x4.x - mean, dx1 = x4.y - mean, dx2 = x4.z - mean, dx3 = x4.w - mean;
  float var = block_sum(dx0*dx0 + dx1*dx1 + dx2*dx2 + dx3*dx3, sbuf) * (1.0f / 1024.0f);
  float rs = 1.0f / sqrtf(var + 1e-5f);
  float4 w4 = *(const float4*)(w + d0);
  float4 b4 = *(const float4*)(bvec + d0);
  float y0 = (dx0 * rs * w4.x + b4.x) * 16.0f;
  float y1 = (dx1 * rs * w4.y + b4.y) * 16.0f;
  float y2 = (dx2 * rs * w4.z + b4.z) * 16.0f;
  float y3 = (dx3 * rs * w4.w + b4.w) * 16.0f;
  h4_t vh, vl;
  vh.x = (half_t)y0; vl.x = (half_t)(y0 - (float)vh.x);
  vh.y = (half_t)y1; vl.y = (half_t)(y1 - (float)vh.y);
  vh.z = (half_t)y2; vl.z = (half_t)(y2 - (float)vh.z);
  vh.w = (half_t)y3; vl.w = (half_t)(y3 - (float)vh.w);
  *(h4_t*)(Oh + rowoff + d0) = vh;
  *(h4_t*)(Ol + rowoff + d0) = vl;
}

// fallback fp32 LN
__global__ __launch_bounds__(256) void k_ln(
    const float* __restrict__ in, const float* __restrict__ w,
    const float* __restrict__ bvec, float* __restrict__ out) {
  __shared__ float sbuf[4];
  const size_t row = blockIdx.x;
  const int d0 = threadIdx.x << 2;
  float4 x4 = *(const float4*)(in + row * ND + d0);
  float mean = block_sum(x4.x + x4.y + x4.z + x4.w, sbuf) * (1.0f / 1024.0f);
  float dx0 = x4.x - mean, dx1 = x4.y - mean, dx2 = x4.z - mean, dx3 = x4.w - mean;
  float var = block_sum(dx0*dx0 + dx1*dx1 + dx2*dx2 + dx3*dx3, sbuf) * (1.0f / 1024.0f);
  float rs = 1.0f / sqrtf(var + 1e-5f);
  float4 w4 = *(const float4*)(w + d0);
  float4 b4 = *(const float4*)(bvec + d0);
  float4 o;
  o.x = dx0 * rs * w4.x + b4.x;
  o.y = dx1 * rs * w4.y + b4.y;
  o.z = dx2 * rs * w4.z + b4.z;
  o.w = dx3 * rs * w4.w + b4.w;
  *(float4*)(out + row * ND + d0) = o;
}

// fused: X[row] += sum3(parts[row]); LN -> split planes. Packed rows; Mp =
// padded partial stride (rows).
template<int WRITEX>
__global__ __launch_bounds__(256) void k_red_ln(
    const float* __restrict__ parts, float* __restrict__ X,
    const float* __restrict__ w, const float* __restrict__ bvec,
    half_t* __restrict__ Oh, half_t* __restrict__ Ol, int Mp) {
  __shared__ float sbuf[4];
  const size_t row = blockIdx.x;
  const int d0 = threadIdx.x << 2;
  const size_t off = row * ND + d0;
  const size_t MN = (size_t)Mp * 1024;
  float4 x4 = *(const float4*)(X + off);
  float4 p0 = *(const float4*)(parts + off);
  float4 p1 = *(const float4*)(parts + MN + off);
  float4 p2 = *(const float4*)(parts + 2 * MN + off);
  x4.x += p0.x + p1.x + p2.x; x4.y += p0.y + p1.y + p2.y;
  x4.z += p0.z + p1.z + p2.z; x4.w += p0.w + p1.w + p2.w;
  if (WRITEX) *(float4*)(X + off) = x4;
  ln_core_emit16(x4, w, bvec, sbuf, Oh, Ol, row * ND, d0);
}

// fused: last-layer mlp2 reduce + lnf. Packed X (S rows/batch), output planes
// packed as blk = b*ncur + c.
__global__ __launch_bounds__(256) void k_red_lnf(
    const float* __restrict__ parts, const float* __restrict__ X,
    const float* __restrict__ w, const float* __restrict__ bvec,
    half_t* __restrict__ Oh, half_t* __restrict__ Ol, int ncur, int S, int Mp) {
  __shared__ float sbuf[4];
  const int blk = blockIdx.x;
  const int b = blk / ncur, c = blk % ncur;
  const size_t row = (size_t)b * S + NBOS + c;
  const int d0 = threadIdx.x << 2;
  const size_t off = row * ND + d0;
  const size_t MN = (size_t)Mp * 1024;
  float4 x4 = *(const float4*)(X + off);
  float4 p0 = *(const float4*)(parts + off);
  float4 p1 = *(const float4*)(parts + MN + off);
  float4 p2 = *(const float4*)(parts + 2 * MN + off);
  x4.x += p0.x + p1.x + p2.x; x4.y += p0.y + p1.y + p2.y;
  x4.z += p0.z + p1.z + p2.z; x4.w += p0.w + p1.w + p2.w;
  ln_core_emit16(x4, w, bvec, sbuf, Oh, Ol, (size_t)blk * ND, d0);
}

// fp32 lnf (fallback)
__global__ __launch_bounds__(256) void k_lnf(
    const float* __restrict__ x, const float* __restrict__ w,
    const float* __restrict__ bvec, float* __restrict__ out) {
  __shared__ float sbuf[4];
  const int blk = blockIdx.x;
  const int b = blk / NC, c = blk % NC;
  const size_t row = (size_t)b * NS + NBOS + c;
  const int d0 = threadIdx.x << 2;
  float4 x4 = *(const float4*)(x + row * ND + d0);
  float mean = block_sum(x4.x + x4.y + x4.z + x4.w, sbuf) * (1.0f / 1024.0f);
  float dx0 = x4.x - mean, dx1 = x4.y - mean, dx2 = x4.z - mean, dx3 = x4.w - mean;
  float var = block_sum(dx0*dx0 + dx1*dx1 + dx2*dx2 + dx3*dx3, sbuf) * (1.0f / 1024.0f);
  float rs = 1.0f / sqrtf(var + 1e-5f);
  float4 w4 = *(const float4*)(w + d0);
  float4 b4 = *(const float4*)(bvec + d0);
  float4 o;
  o.x = dx0 * rs * w4.x + b4.x;
  o.y = dx1 * rs * w4.y + b4.y;
  o.z = dx2 * rs * w4.z + b4.z;
  o.w = dx3 * rs * w4.w + b4.w;
  *(float4*)(out + (size_t)blk * ND + d0) = o;
}

// ======================= build x (+ fused layer-0 LN1) ==================
__device__ __forceinline__ float4 build_row(
    const float* bos, const float* pos_emb, const float* tok_emb,
    const int* tok, const float* stval, int b, int s, int d0, int step) {
  float4 o;
  if (s < NBOS) {
    o = *(const float4*)(bos + (size_t)(b * NBOS + s) * ND + d0);
  } else {
    int j = s - NBOS;
    if (j < step) {
      float sv = stval[b * NC + j];
      int t = tok[b * NC + j];
      float4 e = *(const float4*)(tok_emb + (size_t)t * ND + d0);
      o.x = sv * e.x; o.y = sv * e.y; o.z = sv * e.z; o.w = sv * e.w;
    } else {
      o = *(const float4*)(pos_emb + (size_t)j * ND + d0);
    }
  }
  return o;
}

__global__ __launch_bounds__(256) void k_build_x(
    const float* __restrict__ bos, const float* __restrict__ pos_emb,
    const float* __restrict__ tok_emb, const int* __restrict__ tok,
    const float* __restrict__ stval, float* __restrict__ x, int step) {
  const int row = blockIdx.x;
  const int b = row / NS, s = row % NS;
  const int d0 = threadIdx.x << 2;
  float4 o = build_row(bos, pos_emb, tok_emb, tok, stval, b, s, d0, step);
  *(float4*)(x + (size_t)row * ND + d0) = o;
}

// packed build + fused layer-0 LN1 (S rows per batch)
__global__ __launch_bounds__(256) void k_build_ln(
    const float* __restrict__ bos, const float* __restrict__ pos_emb,
    const float* __restrict__ tok_emb, const int* __restrict__ tok,
    const float* __restrict__ stval, const float* __restrict__ w,
    const float* __restrict__ bvec, float* __restrict__ x,
    half_t* __restrict__ Oh, half_t* __restrict__ Ol, int step, int S) {
  __shared__ float sbuf[4];
  const int row = blockIdx.x;
  const int b = row / S, s = row % S;
  const int d0 = threadIdx.x << 2;
  float4 o = build_row(bos, pos_emb, tok_emb, tok, stval, b, s, d0, step);
  *(float4*)(x + (size_t)row * ND + d0) = o;
  ln_core_emit16(o, w, bvec, sbuf, Oh, Ol, (size_t)row * ND, d0);
}

// ======================= SwiGLU (fallback) ==============================
__global__ __launch_bounds__(256) void k_swiglu(const float* __restrict__ u,
                                                float* __restrict__ m) {
  const size_t idx4 = (size_t)blockIdx.x * 256 + threadIdx.x;
  const size_t row = idx4 >> 9;
  const size_t c0 = (idx4 & 511) << 2;
  const float* ur = u + row * (2 * NHID);
  float4 a4 = *(const float4*)(ur + c0);
  float4 b4 = *(const float4*)(ur + NHID + c0);
  float4 o;
  { float s = 1.0f / (1.0f + expf(-a4.x)); o.x = (a4.x * s) * b4.x; }
  { float s = 1.0f / (1.0f + expf(-a4.y)); o.y = (a4.y * s) * b4.y; }
  { float s = 1.0f / (1.0f + expf(-a4.z)); o.z = (a4.z * s) * b4.z; }
  { float s = 1.0f / (1.0f + expf(-a4.w)); o.w = (a4.w * s) * b4.w; }
  *(float4*)(m + row * NHID + c0) = o;
}

// ======================= gumbel + argmax + st ===========================
// GRED=1: logits = sum of 3 partials (stride Mp*1024) + bias. Packed blocks
// blk = b*ncur + c; threefry/tok indices use logical (b, c) with NC stride.
template<int GRED>
__global__ __launch_bounds__(256) void k_gumbel_t(
    const float* __restrict__ logits, const float* __restrict__ vb,
    int* __restrict__ tok, float* __restrict__ stval, float* __restrict__ out,
    int step, int finalstep, int ncur, int Mp) {
  const int blk = blockIdx.x;
  const int b = blk / ncur, c = blk % ncur;
  const int tid = threadIdx.x;
  uint32_t fk0, fk1;
  threefry2x32(0u, 42u, 0u, (uint32_t)step, fk0, fk1);
  const float* zrow = logits + (size_t)blk * NV;
  const size_t MN = (size_t)Mp * 1024;
  float y[4];
  float bv = -INFINITY; int bi = 0;
#pragma unroll
  for (int j = 0; j < 4; ++j) {
    const int v = tid + (j << 8);
    const uint32_t idx = (uint32_t)(b * NC + c) * 1024u + (uint32_t)v;
    uint32_t o0, o1, bits;
#if JAX_PARTITIONABLE
    threefry2x32(fk0, fk1, 0u, idx, o0, o1);
    bits = o0 ^ o1;
#else
    const uint32_t half = (uint32_t)(NB * NC * NV / 2);
    uint32_t jj = (idx < half) ? idx : idx - half;
    threefry2x32(fk0, fk1, jj, jj + half, o0, o1);
    bits = (idx < half) ? o0 : o1;
#endif
    float f = __uint_as_float(0x3F800000u | (bits >> 9)) - 1.0f;
    float uu = (f == 0.0f) ? 1.17549435e-38f : f;
    float g = -logf(-logf(uu));
    float z;
    if (GRED) z = zrow[v] + zrow[MN + v] + zrow[2 * MN + v] + vb[v];
    else      z = zrow[v];
    float yv = z + g;
    y[j] = yv;
    if (yv > bv) { bv = yv; bi = v; }
  }
  __shared__ float swv[4]; __shared__ int swi[4];
  __shared__ float s_ymax; __shared__ int s_arg;
  for (int off = 32; off > 0; off >>= 1) {
    float ov = __shfl_down(bv, off, 64);
    int   oi = __shfl_down(bi, off, 64);
    if (ov > bv || (ov == bv && oi < bi)) { bv = ov; bi = oi; }
  }
  if ((tid & 63) == 0) { swv[tid >> 6] = bv; swi[tid >> 6] = bi; }
  __syncthreads();
  if (tid == 0) {
    float mv = swv[0]; int mi = swi[0];
    for (int w2 = 1; w2 < 4; ++w2)
      if (swv[w2] > mv || (swv[w2] == mv && swi[w2] < mi)) { mv = swv[w2]; mi = swi[w2]; }
    s_ymax = mv; s_arg = mi;
  }
  __syncthreads();
  const float ymax = s_ymax;
  float es = 0.f;
#pragma unroll
  for (int j = 0; j < 4; ++j) es += expf(y[j] - ymax);
  __shared__ float sbuf2[4]; __shared__ float s_es;
  for (int off = 32; off > 0; off >>= 1) es += __shfl_down(es, off, 64);
  if ((tid & 63) == 0) sbuf2[tid >> 6] = es;
  __syncthreads();
  if (tid == 0) s_es = sbuf2[0] + sbuf2[1] + sbuf2[2] + sbuf2[3];
  __syncthreads();
  const float esum = s_es;
  const float sprob = 0.9f * (1.0f / esum) + (0.1f / 1024.0f);
  const float stv = (1.0f - sprob) + sprob;
  if (tid == 0) { tok[b * NC + c] = s_arg; stval[b * NC + c] = stv; }
  if (finalstep) {
    float* orow = out + ((size_t)b * (NC + 2) + 1 + c) * NV;
#pragma unroll
    for (int j = 0; j < 4; ++j) {
      const int v = tid + (j << 8);
      orow[v] = (v == s_arg) ? stv : 0.0f;
    }
  }
}

__global__ __launch_bounds__(256) void k_out_init(float* __restrict__ out) {
  const int b = blockIdx.x;
  const int tid = threadIdx.x;
#pragma unroll
  for (int j = 0; j < 4; ++j) {
    const int v = tid + (j << 8);
    out[((size_t)b * (NC + 2) + 0) * NV + v]      = (v == 0) ? 1.0f : 0.0f;
    out[((size_t)b * (NC + 2) + NC + 1) * NV + v] = (v == 1) ? 1.0f : 0.0f;
  }
}

// ======================= host orchestration =============================
extern "C" void kernel_launch(void* const* d_in, const int* in_sizes, int n_in,
                              void* d_out, int out_size, void* d_ws, size_t ws_size,
                              hipStream_t stream) {
  (void)in_sizes; (void)n_in; (void)out_size;
  const float* prototypes = (const float*)d_in[0];
  const float* query      = (const float*)d_in[1];
  const float* ca_wq      = (const float*)d_in[2];
  const float* ca_wk      = (const float*)d_in[3];
  const float* ca_wv      = (const float*)d_in[4];
  const float* ca_wo      = (const float*)d_in[5];
  const float* ln1_w      = (const float*)d_in[6];
  const float* ln1_b      = (const float*)d_in[7];
  const float* qkv_w      = (const float*)d_in[8];
  const float* attn_out_w = (const float*)d_in[9];
  const float* rel_bias   = (const float*)d_in[10];
  const float* ln2_w      = (const float*)d_in[11];
  const float* ln2_b      = (const float*)d_in[12];
  const float* mlp_w1     = (const float*)d_in[13];
  const float* mlp_w2     = (const float*)d_in[14];
  const float* lnf_w      = (const float*)d_in[15];
  const float* lnf_b      = (const float*)d_in[16];
  const float* vocab_w    = (const float*)d_in[17];
  const float* vocab_b    = (const float*)d_in[18];
  const float* pos_emb    = (const float*)d_in[19];
  const float* tok_emb    = (const float*)d_in[20];
  float* out = (float*)d_out;

  dim3 thr(256);
  dim3 thr512(512);
  const size_t NEED = 234889216ull;

  if (ws_size >= NEED) {
    // -------- fast path: fp16x3 MFMA (R8 core) + causal triangular S --------
    char* p = (char*)d_ws;
    auto alloc = [&](size_t bytes) { char* r = p; p += (bytes + 255) & ~(size_t)255; return r; };
    half_t *WqH[NL], *WqL[NL], *WaH[NL], *WaL[NL], *W1H[NL], *W1L[NL], *W2H[NL], *W2L[NL];
    for (int l = 0; l < NL; ++l) {
      WqH[l] = (half_t*)alloc(3072 * 1024 * 2);
      WqL[l] = (half_t*)alloc(3072 * 1024 * 2);
      WaH[l] = (half_t*)alloc(1024 * 1024 * 2);
      WaL[l] = (half_t*)alloc(1024 * 1024 * 2);
      W1H[l] = (half_t*)alloc(4096 * 1024 * 2);
      W1L[l] = (half_t*)alloc(4096 * 1024 * 2);
      W2H[l] = (half_t*)alloc(1024 * 2048 * 2);
      W2L[l] = (half_t*)alloc(1024 * 2048 * 2);
    }
    half_t* WvH = (half_t*)alloc(1024 * 1024 * 2);
    half_t* WvL = (half_t*)alloc(1024 * 1024 * 2);
    half_t* Hh  = (half_t*)alloc(1920 * 1024 * 2);
    half_t* Hl  = (half_t*)alloc(1920 * 1024 * 2);
    float* X    = (float*)alloc(1920 * 1024 * 4);
    float* QKV  = (float*)alloc(1920 * 3072 * 4);    // aliases qkv planes + PARTS + prologue
    half_t* Mh  = (half_t*)alloc(1920 * 2048 * 2);
    half_t* Ml  = (half_t*)alloc(1920 * 2048 * 2);
    float* LG   = (float*)alloc(896 * 1024 * 4);     // unused (layout stability)
    float* BOSb = (float*)alloc(64 * 16 * 1024 * 4);
    float* STV  = (float*)alloc(4096);
    int*   TOK  = (int*)alloc(4096);
    (void)LG;
    float* PARTS = QKV;
    half_t* QKVh = (half_t*)QKV;                       // (1920,3072) planes
    half_t* QKVl = QKVh + (size_t)1920 * 3072;

    // ---- weight split (per launch; graph-captured) ----
    for (int l = 0; l < NL; ++l) {
      k_splitw<<<dim3(32, 96), thr, 0, stream>>>(qkv_w + (size_t)l * ND * 3 * ND, WqH[l], WqL[l], 1024, 3072);
      k_splitw<<<dim3(32, 32), thr, 0, stream>>>(attn_out_w + (size_t)l * ND * ND, WaH[l], WaL[l], 1024, 1024);
      k_splitw_swz<<<dim3(32, 128), thr, 0, stream>>>(mlp_w1 + (size_t)l * ND * 2 * NHID, W1H[l], W1L[l], 1024, 4096);
      k_splitw<<<dim3(64, 32), thr, 0, stream>>>(mlp_w2 + (size_t)l * NHID * ND, W2H[l], W2L[l], 2048, 1024);
    }
    k_splitw<<<dim3(32, 32), thr, 0, stream>>>(vocab_w, WvH, WvL, 1024, 1024);

    // ---- cross attention prologue (fp32, scratch inside QKV) ----
    float* QH = QKV;
    float* KH = QKV + 16384;
    float* VH = QKV + 540672;
    float* BOSW = QKV + 1064960;
    k_gemm<<<dim3(16, 1),  thr, 0, stream>>>(query,      ca_wq, QH,   nullptr, NBOS,    ND, ND, 0);
    k_gemm<<<dim3(16, 8),  thr, 0, stream>>>(prototypes, ca_wk, KH,   nullptr, NB * NP, ND, ND, 0);
    k_gemm<<<dim3(16, 8),  thr, 0, stream>>>(prototypes, ca_wv, VH,   nullptr, NB * NP, ND, ND, 0);
    k_ca_attn<<<dim3(NB * NH), thr, 0, stream>>>(QH, KH, VH, BOSW);
    k_gemm<<<dim3(16, 16), thr, 0, stream>>>(BOSW, ca_wo, BOSb, nullptr, NB * NBOS, ND, ND, 0);
    k_out_init<<<dim3(NB), thr, 0, stream>>>(out);

    // ---- 14 autoregressive steps (triangular: S = 17+i rows/batch) ----
    for (int i = 0; i < NC; ++i) {
      const int S   = NBOS + i + 1;              // 17..30
      const int Mt  = NB * S;                    // 1088..1920
      const int MtP = (Mt + 127) & ~127;         // padded to x128
      const int gy  = MtP / 128;                 // 9..15
      const int ncur = i + 1;
      const int Mv  = NB * ncur;                 // 64..896
      const int MvP = (Mv + 127) & ~127;
      const int gvy = MvP / 128;

      k_build_ln<<<dim3(Mt), thr, 0, stream>>>(BOSb, pos_emb, tok_emb, TOK, STV,
                                               ln1_w, ln1_b, X, Hh, Hl, i, S);
      for (int l = 0; l < NL; ++l) {
        k_g3<2><<<dim3(24, gy, 1), thr512, 0, stream>>>(Hh, Hl, WqH[l], WqL[l], nullptr, QKVh, QKVl,
                                                        MtP, 3072, 1024, 1024);
        k_attn16p<<<dim3(NB * NH), thr, 0, stream>>>(QKVh, QKVl, rel_bias + (size_t)l * (2 * NS - 1) * NH,
                                                     Hh, Hl, S);
        k_g3<0><<<dim3(8, gy, 3), thr512, 0, stream>>>(Hh, Hl, WaH[l], WaL[l], PARTS, nullptr, nullptr,
                                                       MtP, 1024, 1024, 352);
        k_red_ln<1><<<dim3(Mt), thr, 0, stream>>>(PARTS, X, ln2_w + l * ND, ln2_b + l * ND, Hh, Hl, MtP);
        k_g3<1><<<dim3(32, gy, 1), thr512, 0, stream>>>(Hh, Hl, W1H[l], W1L[l], nullptr, Mh, Ml,
                                                        MtP, 4096, 1024, 1024);
        k_g3<0><<<dim3(8, gy, 3), thr512, 0, stream>>>(Mh, Ml, W2H[l], W2L[l], PARTS, nullptr, nullptr,
                                                       MtP, 1024, 2048, 704);
        if (l < NL - 1)
          k_red_ln<1><<<dim3(Mt), thr, 0, stream>>>(PARTS, X, ln1_w + (l + 1) * ND, ln1_b + (l + 1) * ND,
                                                    Hh, Hl, MtP);
      }
      k_red_lnf<<<dim3(NB * ncur), thr, 0, stream>>>(PARTS, X, lnf_w, lnf_b, Hh, Hl, ncur, S, MtP);
      k_g3<0><<<dim3(8, gvy, 3), thr512, 0, stream>>>(Hh, Hl, WvH, WvL, PARTS, nullptr, nullptr,
                                                      MvP, 1024, 1024, 352);
      k_gumbel_t<1><<<dim3(NB * ncur), thr, 0, stream>>>(PARTS, vocab_b, TOK, STV, out, i,
                                                         (i == NC - 1) ? 1 : 0, ncur, MvP);
    }
    return;
  }

  // ---------------- fallback: round-1 fp32 path ----------------
  float* ws = (float*)d_ws;
  float* BOSW = ws + 0;
  float* BOSb = ws + 1048576;
  float* QH   = ws + 2097152;
  float* KH   = ws + 2113536;
  float* VH   = ws + 2637824;
  float* X    = ws + 3162112;
  float* Hb   = ws + 5128192;
  float* HL   = Hb;
  float* LG   = Hb + 917504;
  float* QKV  = ws + 7094272;
  float* U    = QKV;
  float* ATT  = ws + 14958592;
  float* Mb   = ATT;
  float* STV  = ws + 18890752;
  int*   TOK  = (int*)(ws + 18891648);

  k_gemm<<<dim3(16, 1),  thr, 0, stream>>>(query,      ca_wq, QH,   nullptr, NBOS,    ND, ND, 0);
  k_gemm<<<dim3(16, 8),  thr, 0, stream>>>(prototypes, ca_wk, KH,   nullptr, NB * NP, ND, ND, 0);
  k_gemm<<<dim3(16, 8),  thr, 0, stream>>>(prototypes, ca_wv, VH,   nullptr, NB * NP, ND, ND, 0);
  k_ca_attn<<<dim3(NB * NH), thr, 0, stream>>>(QH, KH, VH, BOSW);
  k_gemm<<<dim3(16, 16), thr, 0, stream>>>(BOSW, ca_wo, BOSb, nullptr, NB * NBOS, ND, ND, 0);
  k_out_init<<<dim3(NB), thr, 0, stream>>>(out);

  for (int i = 0; i < NC; ++i) {
    k_build_x<<<dim3(NB * NS), thr, 0, stream>>>(BOSb, pos_emb, tok_emb, TOK, STV, X, i);
    for (int l = 0; l < NL; ++l) {
      k_ln<<<dim3(NB * NS), thr, 0, stream>>>(X, ln1_w + l * ND, ln1_b + l * ND, Hb);
      k_gemm<<<dim3(48, 30), thr, 0, stream>>>(Hb, qkv_w + (size_t)l * ND * 3 * ND, QKV,
                                               nullptr, NB * NS, 3 * ND, ND, 0);
      k_attn<<<dim3(NB * NH), thr, 0, stream>>>(QKV, rel_bias + (size_t)l * (2 * NS - 1) * NH, ATT);
      k_gemm<<<dim3(16, 30), thr, 0, stream>>>(ATT, attn_out_w + (size_t)l * ND * ND, X,
                                               nullptr, NB * NS, ND, ND, 1);
      k_ln<<<dim3(NB * NS), thr, 0, stream>>>(X, ln2_w + l * ND, ln2_b + l * ND, Hb);
      k_gemm<<<dim3(64, 30), thr, 0, stream>>>(Hb, mlp_w1 + (size_t)l * ND * 2 * NHID, U,
                                               nullptr, NB * NS, 2 * NHID, ND, 0);
      k_swiglu<<<dim3(3840), thr, 0, stream>>>(U, Mb);
      k_gemm<<<dim3(16, 30), thr, 0, stream>>>(Mb, mlp_w2 + (size_t)l * NHID * ND, X,
                                               nullptr, NB * NS, ND, NHID, 1);
    }
    k_lnf<<<dim3(NB * NC), thr, 0, stream>>>(X, lnf_w, lnf_b, HL);
    k_gemm<<<dim3(16, 14), thr, 0, stream>>>(HL, vocab_w, LG, vocab_b, NB * NC, NV, ND, 2);
    k_gumbel_t<0><<<dim3(NB * NC), thr, 0, stream>>>(LG, nullptr, TOK, STV, out, i,
                                                     (i == NC - 1) ? 1 : 0, NC, 896);
  }
}

// Round 11
// 8853.305 us; speedup vs baseline: 1.7083x; 1.1782x over previous
//
#include <hip/hip_runtime.h>
#include <stdint.h>
#include <stddef.h>
#include <math.h>

// ---- problem dims ----
#define NB   64
#define NP   8
#define ND   1024
#define NH   16
#define NBOS 16
#define NC   14
#define NS   30   // BOS + C
#define NL   4
#define NV   1024
#define NHID 2048
#define NDH  64

#define JAX_PARTITIONABLE 1

typedef _Float16 half_t;
typedef _Float16 h4_t __attribute__((ext_vector_type(4)));
typedef _Float16 h8_t __attribute__((ext_vector_type(8)));
typedef float f32x4 __attribute__((ext_vector_type(4)));

// ======================= threefry2x32 (JAX-exact) =======================
__device__ __forceinline__ uint32_t rotl32(uint32_t x, int d) {
  return (x << d) | (x >> (32 - d));
}

__device__ __forceinline__ void threefry2x32(uint32_t k0, uint32_t k1,
                                             uint32_t x0, uint32_t x1,
                                             uint32_t& o0, uint32_t& o1) {
  uint32_t ks2 = k0 ^ k1 ^ 0x1BD11BDAu;
  x0 += k0; x1 += k1;
#define TF_R4(a,b,c,d) \
  x0 += x1; x1 = rotl32(x1,(a)); x1 ^= x0; \
  x0 += x1; x1 = rotl32(x1,(b)); x1 ^= x0; \
  x0 += x1; x1 = rotl32(x1,(c)); x1 ^= x0; \
  x0 += x1; x1 = rotl32(x1,(d)); x1 ^= x0;
  TF_R4(13,15,26,6)  x0 += k1;  x1 += ks2 + 1u;
  TF_R4(17,29,16,24) x0 += ks2; x1 += k0 + 2u;
  TF_R4(13,15,26,6)  x0 += k0;  x1 += k1 + 3u;
  TF_R4(17,29,16,24) x0 += k1;  x1 += ks2 + 4u;
  TF_R4(13,15,26,6)  x0 += ks2; x1 += k0 + 5u;
#undef TF_R4
  o0 = x0; o1 = x1;
}

// ======================= generic fp32 GEMM (prologue + fallback) ========
__global__ __launch_bounds__(256) void k_gemm(
    const float* __restrict__ A, const float* __restrict__ Bm,
    float* __restrict__ Cm, const float* __restrict__ bias,
    int M, int N, int K, int epi) {
  __shared__ __align__(16) float As[16][64];
  __shared__ __align__(16) float Bs[16][64];
  const int tid = threadIdx.x;
  const int tx = tid & 15, ty = tid >> 4;
  const int m0 = blockIdx.y * 64, n0 = blockIdx.x * 64;
  const int lar = tid >> 2, lak = (tid & 3) << 2;
  const int lbk = tid >> 4, lbn = (tid & 15) << 2;
  float acc[4][4] = {};
  for (int kt = 0; kt < K; kt += 16) {
    float4 av = make_float4(0.f, 0.f, 0.f, 0.f);
    if (m0 + lar < M)
      av = *(const float4*)(A + (size_t)(m0 + lar) * K + kt + lak);
    float4 bv4 = make_float4(0.f, 0.f, 0.f, 0.f);
    if (n0 + lbn < N)
      bv4 = *(const float4*)(Bm + (size_t)(kt + lbk) * N + n0 + lbn);
    __syncthreads();
    As[lak + 0][lar] = av.x; As[lak + 1][lar] = av.y;
    As[lak + 2][lar] = av.z; As[lak + 3][lar] = av.w;
    *(float4*)(&Bs[lbk][lbn]) = bv4;
    __syncthreads();
#pragma unroll
    for (int kk = 0; kk < 16; ++kk) {
      float4 a4 = *(const float4*)(&As[kk][ty << 2]);
      float4 b4 = *(const float4*)(&Bs[kk][tx << 2]);
      float ar[4] = {a4.x, a4.y, a4.z, a4.w};
      float br[4] = {b4.x, b4.y, b4.z, b4.w};
#pragma unroll
      for (int i2 = 0; i2 < 4; ++i2)
#pragma unroll
        for (int j2 = 0; j2 < 4; ++j2)
          acc[i2][j2] = fmaf(ar[i2], br[j2], acc[i2][j2]);
    }
  }
#pragma unroll
  for (int i2 = 0; i2 < 4; ++i2) {
    int r = m0 + (ty << 2) + i2;
    if (r >= M) continue;
#pragma unroll
    for (int j2 = 0; j2 < 4; ++j2) {
      int c = n0 + (tx << 2) + j2;
      if (c >= N) continue;
      size_t off = (size_t)r * N + c;
      float val = acc[i2][j2];
      if (epi == 1) val += Cm[off];
      else if (epi == 2) val += bias[c];
      Cm[off] = val;
    }
  }
}

// ======================= fp16x3 MFMA GEMM (R8 core) =====================
__device__ __forceinline__ void gload16(const void* g, const void* l) {
  __builtin_amdgcn_global_load_lds((const __attribute__((address_space(1))) void*)g,
                                   (__attribute__((address_space(3))) void*)l, 16, 0, 0);
}

// XCD-aware chunked swizzle (per z-slice). gx must be %8==0.
__device__ __forceinline__ void xcd_swz(int gx, int gy, int& bx, int& by) {
  const int flat = blockIdx.y * gx + blockIdx.x;
  const int chunk = (gx * gy) >> 3;
  const int myid = (flat & 7) * chunk + (flat >> 3);
  bx = myid / gy;
  by = myid % gy;
}

// EPI 0: store partial fp32*(1/1024) at Cout + z*M*N
// EPI 1: fused SwiGLU -> Mh/Ml (col-permuted W1 layout), full-K only
// EPI 2: store split fp16 planes (raw value) -> Mh/Ml, full-K only
template<int EPI>
__global__ __launch_bounds__(512) void k_g3(
    const half_t* __restrict__ Ah, const half_t* __restrict__ Al,
    const half_t* __restrict__ Bh, const half_t* __restrict__ Bl,
    float* __restrict__ Cout, half_t* __restrict__ Mh, half_t* __restrict__ Ml,
    int M, int N, int K, int CH) {
  __shared__ __align__(16) half_t sAh[2][4096];
  __shared__ __align__(16) half_t sAl[2][4096];
  __shared__ __align__(16) half_t sBh[2][4096];
  __shared__ __align__(16) half_t sBl[2][4096];
  int bx, by; xcd_swz(gridDim.x, gridDim.y, bx, by);
  const int tid = threadIdx.x;
  const int lane = tid & 63, w = tid >> 6;       // 8 waves
  const int wm = w >> 2, wn = w & 3;             // 2 x 4 wave grid
  const int m0 = by * 128, n0 = bx * 128;
  const int fr = lane & 15, fq = lane >> 4;
  const int kbeg = blockIdx.z * CH;
  const int kend = (kbeg + CH < K) ? (kbeg + CH) : K;
  f32x4 acc[4][2] = {};
  const int r0 = tid >> 2, ch = (tid & 3) * 8;
  const size_t aB = (size_t)(m0 + r0) * K + ch;
  const size_t bB = (size_t)(n0 + r0) * K + ch;
  const int wb = w * 1024;   // per-wave dest byte offset within 8KB plane

  auto STAGE = [&](int buf, int kt) {   // 4 loads/thread (one per plane)
    gload16(Ah + aB + kt, (char*)(&sAh[buf][0]) + wb);
    gload16(Al + aB + kt, (char*)(&sAl[buf][0]) + wb);
    gload16(Bh + bB + kt, (char*)(&sBh[buf][0]) + wb);
    gload16(Bl + bB + kt, (char*)(&sBl[buf][0]) + wb);
  };

  STAGE(0, kbeg);                                  // 4 outstanding
  int cur = 0;
  for (int kt = kbeg; kt < kend; kt += 32) {
    const bool has_next = (kt + 32 < kend);
    if (has_next) {
      STAGE(cur ^ 1, kt + 32);                     // +4 -> 8 outstanding
      asm volatile("s_waitcnt vmcnt(4)" ::: "memory");   // cur's 4 done
    } else {
      asm volatile("s_waitcnt vmcnt(0)" ::: "memory");
    }
    asm volatile("s_barrier" ::: "memory");        // all waves' cur staged
    const half_t* bAh = &sAh[cur][0] + (wm * 64 + fr) * 32 + fq * 8;
    const half_t* bAl = &sAl[cur][0] + (wm * 64 + fr) * 32 + fq * 8;
    const half_t* bBh = &sBh[cur][0] + (wn * 32 + fr) * 32 + fq * 8;
    const half_t* bBl = &sBl[cur][0] + (wn * 32 + fr) * 32 + fq * 8;
    h8_t a[4], b[2], t[2];
#pragma unroll
    for (int mi = 0; mi < 4; ++mi) a[mi] = *(const h8_t*)(bAh + mi * 512);
#pragma unroll
    for (int ni = 0; ni < 2; ++ni) b[ni] = *(const h8_t*)(bBh + ni * 512);
#pragma unroll
    for (int mi = 0; mi < 4; ++mi)
#pragma unroll
      for (int ni = 0; ni < 2; ++ni)
        acc[mi][ni] = __builtin_amdgcn_mfma_f32_16x16x32_f16(a[mi], b[ni], acc[mi][ni], 0, 0, 0);
#pragma unroll
    for (int ni = 0; ni < 2; ++ni) t[ni] = *(const h8_t*)(bBl + ni * 512);
#pragma unroll
    for (int mi = 0; mi < 4; ++mi)
#pragma unroll
      for (int ni = 0; ni < 2; ++ni)
        acc[mi][ni] = __builtin_amdgcn_mfma_f32_16x16x32_f16(a[mi], t[ni], acc[mi][ni], 0, 0, 0);
#pragma unroll
    for (int mi = 0; mi < 4; ++mi) a[mi] = *(const h8_t*)(bAl + mi * 512);
    asm volatile("s_barrier" ::: "memory");
#pragma unroll
    for (int mi = 0; mi < 4; ++mi)
#pragma unroll
      for (int ni = 0; ni < 2; ++ni)
        acc[mi][ni] = __builtin_amdgcn_mfma_f32_16x16x32_f16(a[mi], b[ni], acc[mi][ni], 0, 0, 0);
    cur ^= 1;
  }
  const float sc = 1.0f / 1024.0f;
  if (EPI == 0) {
    float* Cz = Cout + (size_t)blockIdx.z * M * N;
#pragma unroll
    for (int mi = 0; mi < 4; ++mi) {
      const int row = m0 + wm * 64 + mi * 16 + fq * 4;
#pragma unroll
      for (int ni = 0; ni < 2; ++ni) {
        const int col = n0 + wn * 32 + ni * 16 + fr;
        float* cp = Cz + (size_t)row * N + col;
#pragma unroll
        for (int j = 0; j < 4; ++j) cp[(size_t)j * N] = acc[mi][ni][j] * sc;
      }
    }
  } else if (EPI == 1) {
    const int hid = ((n0 + wn * 32) >> 1) + fr;
#pragma unroll
    for (int mi = 0; mi < 4; ++mi) {
      const int row = m0 + wm * 64 + mi * 16 + fq * 4;
#pragma unroll
      for (int j = 0; j < 4; ++j) {
        const float u1 = acc[mi][0][j] * sc;
        const float u2 = acc[mi][1][j] * sc;
        const float s = 1.0f / (1.0f + expf(-u1));
        const float y = (u1 * s) * u2 * 16.0f;
        const half_t hv = (half_t)y;
        const size_t off = (size_t)(row + j) * NHID + hid;
        Mh[off] = hv;
        Ml[off] = (half_t)(y - (float)hv);
      }
    }
  } else {
#pragma unroll
    for (int mi = 0; mi < 4; ++mi) {
      const int row = m0 + wm * 64 + mi * 16 + fq * 4;
#pragma unroll
      for (int ni = 0; ni < 2; ++ni) {
        const int col = n0 + wn * 32 + ni * 16 + fr;
#pragma unroll
        for (int j = 0; j < 4; ++j) {
          const float v = acc[mi][ni][j] * sc;
          const half_t hv = (half_t)v;
          const size_t off = (size_t)(row + j) * N + col;
          Mh[off] = hv;
          Ml[off] = (half_t)(v - (float)hv);
        }
      }
    }
  }
}

// ---- weight split: W:(K,N) fp32 -> Th,Tl:(N,K) fp16 x64 ----
__global__ __launch_bounds__(256) void k_splitw(
    const float* __restrict__ W, half_t* __restrict__ Th, half_t* __restrict__ Tl,
    int K, int N) {
  __shared__ float t[32][33];
  const int kb = blockIdx.x * 32, nb = blockIdx.y * 32;
  const int tid = threadIdx.x;
  const int rr = tid >> 5, cc = tid & 31;
#pragma unroll
  for (int i = 0; i < 4; ++i)
    t[rr + i * 8][cc] = W[(size_t)(kb + rr + i * 8) * N + nb + cc];
  __syncthreads();
#pragma unroll
  for (int i = 0; i < 4; ++i) {
    const int nr = rr + i * 8;
    const float x = t[cc][nr] * 64.0f;
    const half_t h = (half_t)x;
    const float r = x - (float)h;
    const size_t off = (size_t)(nb + nr) * K + kb + cc;
    Th[off] = h;
    Tl[off] = (half_t)r;
  }
}

// variant for mlp_w1: logical col n -> physical row p for swiglu pairing
__global__ __launch_bounds__(256) void k_splitw_swz(
    const float* __restrict__ W, half_t* __restrict__ Th, half_t* __restrict__ Tl,
    int K, int N) {
  __shared__ float t[32][33];
  const int kb = blockIdx.x * 32, nb = blockIdx.y * 32;
  const int tid = threadIdx.x;
  const int rr = tid >> 5, cc = tid & 31;
#pragma unroll
  for (int i = 0; i < 4; ++i)
    t[rr + i * 8][cc] = W[(size_t)(kb + rr + i * 8) * N + nb + cc];
  __syncthreads();
#pragma unroll
  for (int i = 0; i < 4; ++i) {
    const int n = nb + rr + i * 8;
    const int hid = n & (NHID - 1), half = n >> 11;
    const int p = ((hid >> 4) << 5) + (half << 4) + (hid & 15);
    const float x = t[cc][rr + i * 8] * 64.0f;
    const half_t h = (half_t)x;
    const float r = x - (float)h;
    const size_t off = (size_t)p * K + kb + cc;
    Th[off] = h;
    Tl[off] = (half_t)r;
  }
}

// ======================= cross attention (builds BOS) ===================
__global__ __launch_bounds__(256) void k_ca_attn(
    const float* __restrict__ qh, const float* __restrict__ kh,
    const float* __restrict__ vh, float* __restrict__ bosw) {
  const int b = blockIdx.x >> 4, h = blockIdx.x & 15;
  __shared__ float q[NBOS][NDH], kk[NP][NDH], vv[NP][NDH], a[NBOS][NP];
  const int tid = threadIdx.x;
  for (int idx = tid; idx < NBOS * NDH; idx += 256) {
    int qi = idx >> 6, d = idx & 63;
    q[qi][d] = qh[(size_t)qi * ND + h * NDH + d];
  }
  for (int idx = tid; idx < NP * NDH; idx += 256) {
    int p = idx >> 6, d = idx & 63;
    kk[p][d] = kh[(size_t)(b * NP + p) * ND + h * NDH + d];
    vv[p][d] = vh[(size_t)(b * NP + p) * ND + h * NDH + d];
  }
  __syncthreads();
  if (tid < NBOS * NP) {
    int qi = tid >> 3, p = tid & 7;
    float dot = 0.f;
    for (int d = 0; d < NDH; ++d) dot = fmaf(q[qi][d], kk[p][d], dot);
    a[qi][p] = dot / 64.0f;
  }
  __syncthreads();
  if (tid < NBOS) {
    float mx = a[tid][0];
    for (int p = 1; p < NP; ++p) mx = fmaxf(mx, a[tid][p]);
    float sum = 0.f;
    for (int p = 0; p < NP; ++p) { float e = expf(a[tid][p] - mx); a[tid][p] = e; sum += e; }
    for (int p = 0; p < NP; ++p) a[tid][p] /= sum;
  }
  __syncthreads();
  for (int idx = tid; idx < NBOS * NDH; idx += 256) {
    int qi = idx >> 6, d = idx & 63;
    float o = 0.f;
    for (int p = 0; p < NP; ++p) o = fmaf(a[qi][p], vv[p][d], o);
    bosw[(size_t)(b * NBOS + qi) * ND + h * NDH + d] = o;
  }
}

// ======================= self attention (fallback fp32 qkv) =============
__global__ __launch_bounds__(256) void k_attn(
    const float* __restrict__ qkv, const float* __restrict__ relb,
    float* __restrict__ attout) {
  const int b = blockIdx.x >> 4, h = blockIdx.x & 15;
  __shared__ float q[NS][NDH], kk[NS][NDH], vv[NS][NDH];
  __shared__ float a[NS][NS];
  const int tid = threadIdx.x;
  for (int idx = tid; idx < NS * NDH; idx += 256) {
    int s = idx >> 6, d = idx & 63;
    size_t base = ((size_t)(b * NS + s) * 3) * ND + h * NDH + d;
    q[s][d]  = qkv[base];
    kk[s][d] = qkv[base + ND];
    vv[s][d] = qkv[base + 2 * ND];
  }
  __syncthreads();
  for (int idx = tid; idx < NS * NS; idx += 256) {
    int i = idx / NS, j = idx % NS;
    float sc = 0.f;
    if (j <= i) {
      float dot = 0.f;
      for (int d = 0; d < NDH; ++d) dot = fmaf(q[i][d], kk[j][d], dot);
      sc = dot * 0.125f + relb[(size_t)(i - j + NS - 1) * NH + h];
    }
    a[i][j] = sc;
  }
  __syncthreads();
  if (tid < NS) {
    const int i = tid;
    float mx = -INFINITY;
    for (int j = 0; j <= i; ++j) mx = fmaxf(mx, a[i][j]);
    float sum = 0.f;
    for (int j = 0; j <= i; ++j) { float e = expf(a[i][j] - mx); a[i][j] = e; sum += e; }
    for (int j = 0; j <= i; ++j) a[i][j] /= sum;
    for (int j = i + 1; j < NS; ++j) a[i][j] = 0.f;
  }
  __syncthreads();
  for (int idx = tid; idx < NS * NDH; idx += 256) {
    int i = idx >> 6, d = idx & 63;
    float o = 0.f;
    for (int j = 0; j < NS; ++j) o = fmaf(a[i][j], vv[j][d], o);
    attout[(size_t)(b * NS + i) * ND + h * NDH + d] = o;
  }
}

// self attention on packed S rows, split qkv planes -> split out planes (x16)
// used for the one-time BOS precompute pass (S = 16).
__global__ __launch_bounds__(256) void k_attn16p(
    const half_t* __restrict__ Qh, const half_t* __restrict__ Ql,
    const float* __restrict__ relb,
    half_t* __restrict__ Oh, half_t* __restrict__ Ol, int S) {
  const int b = blockIdx.x >> 4, h = blockIdx.x & 15;
  __shared__ float q[NS][NDH], kk[NS][NDH], vv[NS][NDH];
  __shared__ float a[NS][NS];
  const int tid = threadIdx.x;
  for (int idx = tid; idx < S * NDH; idx += 256) {
    int s = idx >> 6, d = idx & 63;
    size_t base = (size_t)(b * S + s) * 3072 + h * NDH + d;
    q[s][d]  = (float)Qh[base] + (float)Ql[base];
    kk[s][d] = (float)Qh[base + 1024] + (float)Ql[base + 1024];
    vv[s][d] = (float)Qh[base + 2048] + (float)Ql[base + 2048];
  }
  __syncthreads();
  for (int idx = tid; idx < S * S; idx += 256) {
    int i = idx / S, j = idx % S;
    float sc = 0.f;
    if (j <= i) {
      float dot = 0.f;
      for (int d = 0; d < NDH; ++d) dot = fmaf(q[i][d], kk[j][d], dot);
      sc = dot * 0.125f + relb[(size_t)(i - j + NS - 1) * NH + h];
    }
    a[i][j] = sc;
  }
  __syncthreads();
  if (tid < S) {
    const int i = tid;
    float mx = -INFINITY;
    for (int j = 0; j <= i; ++j) mx = fmaxf(mx, a[i][j]);
    float sum = 0.f;
    for (int j = 0; j <= i; ++j) { float e = expf(a[i][j] - mx); a[i][j] = e; sum += e; }
    for (int j = 0; j <= i; ++j) a[i][j] /= sum;
    for (int j = i + 1; j < S; ++j) a[i][j] = 0.f;
  }
  __syncthreads();
  for (int idx = tid; idx < S * NDH; idx += 256) {
    int i = idx >> 6, d = idx & 63;
    float o = 0.f;
    for (int j = 0; j < S; ++j) o = fmaf(a[i][j], vv[j][d], o);
    const float y = o * 16.0f;
    const half_t hv = (half_t)y;
    const size_t off = (size_t)(b * S + i) * ND + h * NDH + d;
    Oh[off] = hv;
    Ol[off] = (half_t)(y - (float)hv);
  }
}

// copy K/V cols (1024..3071) of BOS QKV planes -> per-layer cache (stride 2048)
__global__ __launch_bounds__(256) void k_copy_kv(
    const half_t* __restrict__ Qh, const half_t* __restrict__ Ql,
    half_t* __restrict__ Ch, half_t* __restrict__ Cl) {
  const int row = blockIdx.x;           // 0..1023 = b*16+s
  const int c0 = threadIdx.x * 8;       // 0..2040
  const size_t src = (size_t)row * 3072 + 1024 + c0;
  const size_t dst = (size_t)row * 2048 + c0;
  *(h8_t*)(Ch + dst) = *(const h8_t*)(Qh + src);
  *(h8_t*)(Cl + dst) = *(const h8_t*)(Ql + src);
}

// content attention: queries = content rows c=0..ncur-1 (global pos 16+c),
// keys/values = cached BOS (16) + fresh content (ncur). Split planes in/out.
__global__ __launch_bounds__(256) void k_attn16c(
    const half_t* __restrict__ Qh, const half_t* __restrict__ Ql,
    const half_t* __restrict__ Ch, const half_t* __restrict__ Cl,
    const float* __restrict__ relb,
    half_t* __restrict__ Oh, half_t* __restrict__ Ol, int ncur) {
  const int b = blockIdx.x >> 4, h = blockIdx.x & 15;
  const int S = NBOS + ncur;            // keys: 17..30
  __shared__ float q[NC][NDH], kk[NS][NDH], vv[NS][NDH];
  __shared__ float a[NC][NS];
  const int tid = threadIdx.x;
  for (int idx = tid; idx < ncur * NDH; idx += 256) {
    int c = idx >> 6, d = idx & 63;
    size_t base = (size_t)(b * ncur + c) * 3072 + h * NDH + d;
    q[c][d] = (float)Qh[base] + (float)Ql[base];
  }
  for (int idx = tid; idx < S * NDH; idx += 256) {
    int j = idx >> 6, d = idx & 63;
    if (j < NBOS) {
      size_t r = (size_t)(b * NBOS + j) * 2048 + h * NDH + d;
      kk[j][d] = (float)Ch[r] + (float)Cl[r];
      vv[j][d] = (float)Ch[r + 1024] + (float)Cl[r + 1024];
    } else {
      size_t base = (size_t)(b * ncur + (j - NBOS)) * 3072 + h * NDH + d;
      kk[j][d] = (float)Qh[base + 1024] + (float)Ql[base + 1024];
      vv[j][d] = (float)Qh[base + 2048] + (float)Ql[base + 2048];
    }
  }
  __syncthreads();
  for (int idx = tid; idx < ncur * S; idx += 256) {
    int c = idx / S, j = idx % S;
    const int s = NBOS + c;
    float sc = 0.f;
    if (j <= s) {
      float dot = 0.f;
      for (int d = 0; d < NDH; ++d) dot = fmaf(q[c][d], kk[j][d], dot);
      sc = dot * 0.125f + relb[(size_t)(s - j + NS - 1) * NH + h];
    }
    a[c][j] = sc;
  }
  __syncthreads();
  if (tid < ncur) {
    const int c = tid, s = NBOS + c;
    float mx = -INFINITY;
    for (int j = 0; j <= s; ++j) mx = fmaxf(mx, a[c][j]);
    float sum = 0.f;
    for (int j = 0; j <= s; ++j) { float e = expf(a[c][j] - mx); a[c][j] = e; sum += e; }
    for (int j = 0; j <= s; ++j) a[c][j] /= sum;
    for (int j = s + 1; j < S; ++j) a[c][j] = 0.f;
  }
  __syncthreads();
  for (int idx = tid; idx < ncur * NDH; idx += 256) {
    int c = idx >> 6, d = idx & 63;
    float o = 0.f;
    for (int j = 0; j < S; ++j) o = fmaf(a[c][j], vv[j][d], o);
    const float y = o * 16.0f;
    const half_t hv = (half_t)y;
    const size_t off = (size_t)(b * ncur + c) * ND + h * NDH + d;
    Oh[off] = hv;
    Ol[off] = (half_t)(y - (float)hv);
  }
}

// ======================= layernorm cores ================================
__device__ __forceinline__ float block_sum(float val, float* sbuf) {
  for (int off = 32; off > 0; off >>= 1) val += __shfl_down(val, off, 64);
  const int wid = threadIdx.x >> 6;
  if ((threadIdx.x & 63) == 0) sbuf[wid] = val;
  __syncthreads();
  if (threadIdx.x == 0) sbuf[0] = sbuf[0] + sbuf[1] + sbuf[2] + sbuf[3];
  __syncthreads();
  float r = sbuf[0];
  __syncthreads();
  return r;
}

__device__ __forceinline__ void ln_core_emit16(
    float4 x4, const float* w, const float* bvec, float* sbuf,
    half_t* Oh, half_t* Ol, size_t rowoff, int d0) {
  float mean = block_sum(x4.x + x4.y + x4.z + x4.w, sbuf) * (1.0f / 1024.0f);
  float dx0 = x4.x - mean, dx1 = x4.y - mean, dx2 = x4.z - mean, dx3 = x4.w - mean;
  float var = block_sum(dx0*dx0 + dx1*dx1 + dx2*dx2 + dx3*dx3, sbuf) * (1.0f / 1024.0f);
  float rs = 1.0f / sqrtf(var + 1e-5f);
  float4 w4 = *(const float4*)(w + d0);
  float4 b4 = *(const float4*)(bvec + d0);
  float y0 = (dx0 * rs * w4.x + b4.x) * 16.0f;
  float y1 = (dx1 * rs * w4.y + b4.y) * 16.0f;
  float y2 = (dx2 * rs * w4.z + b4.z) * 16.0f;
  float y3 = (dx3 * rs * w4.w + b4.w) * 16.0f;
  h4_t vh, vl;
  vh.x = (half_t)y0; vl.x = (half_t)(y0 - (float)vh.x);
  vh.y = (half_t)y1; vl.y = (half_t)(y1 - (float)vh.y);
  vh.z = (half_t)y2; vl.z = (half_t)(y2 - (float)vh.z);
  vh.w = (half_t)y3; vl.w = (half_t)(y3 - (float)vh.w);
  *(h4_t*)(Oh + rowoff + d0) = vh;
  *(h4_t*)(Ol + rowoff + d0) = vl;
}

// fallback fp32 LN
__global__ __launch_bounds__(256) void k_ln(
    const float* __restrict__ in, const float* __restrict__ w,
    const float* __restrict__ bvec, float* __restrict__ out) {
  __shared__ float sbuf[4];
  const size_t row = blockIdx.x;
  const int d0 = threadIdx.x << 2;
  float4 x4 = *(const float4*)(in + row * ND + d0);
  float mean = block_sum(x4.x + x4.y + x4.z + x4.w, sbuf) * (1.0f / 1024.0f);
  float dx0 = x4.x - mean, dx1 = x4.y - mean, dx2 = x4.z - mean, dx3 = x4.w - mean;
  float var = block_sum(dx0*dx0 + dx1*dx1 + dx2*dx2 + dx3*dx3, sbuf) * (1.0f / 1024.0f);
  float rs = 1.0f / sqrtf(var + 1e-5f);
  float4 w4 = *(const float4*)(w + d0);
  float4 b4 = *(const float4*)(bvec + d0);
  float4 o;
  o.x = dx0 * rs * w4.x + b4.x;
  o.y = dx1 * rs * w4.y + b4.y;
  o.z = dx2 * rs * w4.z + b4.z;
  o.w = dx3 * rs * w4.w + b4.w;
  *(float4*)(out + row * ND + d0) = o;
}

// fused: X[row] += sum3(parts[row]); LN -> split planes. Packed rows; Mp =
// padded partial stride (rows). WRITEX=0 doubles as the lnf epilogue.
template<int WRITEX>
__global__ __launch_bounds__(256) void k_red_ln(
    const float* __restrict__ parts, float* __restrict__ X,
    const float* __restrict__ w, const float* __restrict__ bvec,
    half_t* __restrict__ Oh, half_t* __restrict__ Ol, int Mp) {
  __shared__ float sbuf[4];
  const size_t row = blockIdx.x;
  const int d0 = threadIdx.x << 2;
  const size_t off = row * ND + d0;
  const size_t MN = (size_t)Mp * 1024;
  float4 x4 = *(const float4*)(X + off);
  float4 p0 = *(const float4*)(parts + off);
  float4 p1 = *(const float4*)(parts + MN + off);
  float4 p2 = *(const float4*)(parts + 2 * MN + off);
  x4.x += p0.x + p1.x + p2.x; x4.y += p0.y + p1.y + p2.y;
  x4.z += p0.z + p1.z + p2.z; x4.w += p0.w + p1.w + p2.w;
  if (WRITEX) *(float4*)(X + off) = x4;
  ln_core_emit16(x4, w, bvec, sbuf, Oh, Ol, row * ND, d0);
}

// fp32 lnf (fallback)
__global__ __launch_bounds__(256) void k_lnf(
    const float* __restrict__ x, const float* __restrict__ w,
    const float* __restrict__ bvec, float* __restrict__ out) {
  __shared__ float sbuf[4];
  const int blk = blockIdx.x;
  const int b = blk / NC, c = blk % NC;
  const size_t row = (size_t)b * NS + NBOS + c;
  const int d0 = threadIdx.x << 2;
  float4 x4 = *(const float4*)(x + row * ND + d0);
  float mean = block_sum(x4.x + x4.y + x4.z + x4.w, sbuf) * (1.0f / 1024.0f);
  float dx0 = x4.x - mean, dx1 = x4.y - mean, dx2 = x4.z - mean, dx3 = x4.w - mean;
  float var = block_sum(dx0*dx0 + dx1*dx1 + dx2*dx2 + dx3*dx3, sbuf) * (1.0f / 1024.0f);
  float rs = 1.0f / sqrtf(var + 1e-5f);
  float4 w4 = *(const float4*)(w + d0);
  float4 b4 = *(const float4*)(bvec + d0);
  float4 o;
  o.x = dx0 * rs * w4.x + b4.x;
  o.y = dx1 * rs * w4.y + b4.y;
  o.z = dx2 * rs * w4.z + b4.z;
  o.w = dx3 * rs * w4.w + b4.w;
  *(float4*)(out + (size_t)blk * ND + d0) = o;
}

// ======================= build x (+ fused LN1) ==========================
__device__ __forceinline__ float4 build_row(
    const float* bos, const float* pos_emb, const float* tok_emb,
    const int* tok, const float* stval, int b, int s, int d0, int step) {
  float4 o;
  if (s < NBOS) {
    o = *(const float4*)(bos + (size_t)(b * NBOS + s) * ND + d0);
  } else {
    int j = s - NBOS;
    if (j < step) {
      float sv = stval[b * NC + j];
      int t = tok[b * NC + j];
      float4 e = *(const float4*)(tok_emb + (size_t)t * ND + d0);
      o.x = sv * e.x; o.y = sv * e.y; o.z = sv * e.z; o.w = sv * e.w;
    } else {
      o = *(const float4*)(pos_emb + (size_t)j * ND + d0);
    }
  }
  return o;
}

__global__ __launch_bounds__(256) void k_build_x(
    const float* __restrict__ bos, const float* __restrict__ pos_emb,
    const float* __restrict__ tok_emb, const int* __restrict__ tok,
    const float* __restrict__ stval, float* __restrict__ x, int step) {
  const int row = blockIdx.x;
  const int b = row / NS, s = row % NS;
  const int d0 = threadIdx.x << 2;
  float4 o = build_row(bos, pos_emb, tok_emb, tok, stval, b, s, d0, step);
  *(float4*)(x + (size_t)row * ND + d0) = o;
}

// packed build + fused LN1 (S rows per batch; used once for BOS with S=16)
__global__ __launch_bounds__(256) void k_build_ln(
    const float* __restrict__ bos, const float* __restrict__ pos_emb,
    const float* __restrict__ tok_emb, const int* __restrict__ tok,
    const float* __restrict__ stval, const float* __restrict__ w,
    const float* __restrict__ bvec, float* __restrict__ x,
    half_t* __restrict__ Oh, half_t* __restrict__ Ol, int step, int S) {
  __shared__ float sbuf[4];
  const int row = blockIdx.x;
  const int b = row / S, s = row % S;
  const int d0 = threadIdx.x << 2;
  float4 o = build_row(bos, pos_emb, tok_emb, tok, stval, b, s, d0, step);
  *(float4*)(x + (size_t)row * ND + d0) = o;
  ln_core_emit16(o, w, bvec, sbuf, Oh, Ol, (size_t)row * ND, d0);
}

// content-only build + LN1: row = b*ncur + c, logical position s = NBOS+c
__global__ __launch_bounds__(256) void k_build_ln_c(
    const float* __restrict__ pos_emb, const float* __restrict__ tok_emb,
    const int* __restrict__ tok, const float* __restrict__ stval,
    const float* __restrict__ w, const float* __restrict__ bvec,
    float* __restrict__ x, half_t* __restrict__ Oh, half_t* __restrict__ Ol,
    int step, int ncur) {
  __shared__ float sbuf[4];
  const int row = blockIdx.x;
  const int b = row / ncur, c = row % ncur;
  const int d0 = threadIdx.x << 2;
  float4 o;
  if (c < step) {
    float sv = stval[b * NC + c];
    int t = tok[b * NC + c];
    float4 e = *(const float4*)(tok_emb + (size_t)t * ND + d0);
    o.x = sv * e.x; o.y = sv * e.y; o.z = sv * e.z; o.w = sv * e.w;
  } else {
    o = *(const float4*)(pos_emb + (size_t)c * ND + d0);
  }
  *(float4*)(x + (size_t)row * ND + d0) = o;
  ln_core_emit16(o, w, bvec, sbuf, Oh, Ol, (size_t)row * ND, d0);
}

// ======================= SwiGLU (fallback) ==============================
__global__ __launch_bounds__(256) void k_swiglu(const float* __restrict__ u,
                                                float* __restrict__ m) {
  const size_t idx4 = (size_t)blockIdx.x * 256 + threadIdx.x;
  const size_t row = idx4 >> 9;
  const size_t c0 = (idx4 & 511) << 2;
  const float* ur = u + row * (2 * NHID);
  float4 a4 = *(const float4*)(ur + c0);
  float4 b4 = *(const float4*)(ur + NHID + c0);
  float4 o;
  { float s = 1.0f / (1.0f + expf(-a4.x)); o.x = (a4.x * s) * b4.x; }
  { float s = 1.0f / (1.0f + expf(-a4.y)); o.y = (a4.y * s) * b4.y; }
  { float s = 1.0f / (1.0f + expf(-a4.z)); o.z = (a4.z * s) * b4.z; }
  { float s = 1.0f / (1.0f + expf(-a4.w)); o.w = (a4.w * s) * b4.w; }
  *(float4*)(m + row * NHID + c0) = o;
}

// ======================= gumbel + argmax + st ===========================
// GRED=1: logits = sum of 3 partials (stride Mp*1024) + bias. Packed blocks
// blk = b*ncur + c; threefry/tok indices use logical (b, c) with NC stride.
template<int GRED>
__global__ __launch_bounds__(256) void k_gumbel_t(
    const float* __restrict__ logits, const float* __restrict__ vb,
    int* __restrict__ tok, float* __restrict__ stval, float* __restrict__ out,
    int step, int finalstep, int ncur, int Mp) {
  const int blk = blockIdx.x;
  const int b = blk / ncur, c = blk % ncur;
  const int tid = threadIdx.x;
  uint32_t fk0, fk1;
  threefry2x32(0u, 42u, 0u, (uint32_t)step, fk0, fk1);
  const float* zrow = logits + (size_t)blk * NV;
  const size_t MN = (size_t)Mp * 1024;
  float y[4];
  float bv = -INFINITY; int bi = 0;
#pragma unroll
  for (int j = 0; j < 4; ++j) {
    const int v = tid + (j << 8);
    const uint32_t idx = (uint32_t)(b * NC + c) * 1024u + (uint32_t)v;
    uint32_t o0, o1, bits;
#if JAX_PARTITIONABLE
    threefry2x32(fk0, fk1, 0u, idx, o0, o1);
    bits = o0 ^ o1;
#else
    const uint32_t half = (uint32_t)(NB * NC * NV / 2);
    uint32_t jj = (idx < half) ? idx : idx - half;
    threefry2x32(fk0, fk1, jj, jj + half, o0, o1);
    bits = (idx < half) ? o0 : o1;
#endif
    float f = __uint_as_float(0x3F800000u | (bits >> 9)) - 1.0f;
    float uu = (f == 0.0f) ? 1.17549435e-38f : f;
    float g = -logf(-logf(uu));
    float z;
    if (GRED) z = zrow[v] + zrow[MN + v] + zrow[2 * MN + v] + vb[v];
    else      z = zrow[v];
    float yv = z + g;
    y[j] = yv;
    if (yv > bv) { bv = yv; bi = v; }
  }
  __shared__ float swv[4]; __shared__ int swi[4];
  __shared__ float s_ymax; __shared__ int s_arg;
  for (int off = 32; off > 0; off >>= 1) {
    float ov = __shfl_down(bv, off, 64);
    int   oi = __shfl_down(bi, off, 64);
    if (ov > bv || (ov == bv && oi < bi)) { bv = ov; bi = oi; }
  }
  if ((tid & 63) == 0) { swv[tid >> 6] = bv; swi[tid >> 6] = bi; }
  __syncthreads();
  if (tid == 0) {
    float mv = swv[0]; int mi = swi[0];
    for (int w2 = 1; w2 < 4; ++w2)
      if (swv[w2] > mv || (swv[w2] == mv && swi[w2] < mi)) { mv = swv[w2]; mi = swi[w2]; }
    s_ymax = mv; s_arg = mi;
  }
  __syncthreads();
  const float ymax = s_ymax;
  float es = 0.f;
#pragma unroll
  for (int j = 0; j < 4; ++j) es += expf(y[j] - ymax);
  __shared__ float sbuf2[4]; __shared__ float s_es;
  for (int off = 32; off > 0; off >>= 1) es += __shfl_down(es, off, 64);
  if ((tid & 63) == 0) sbuf2[tid >> 6] = es;
  __syncthreads();
  if (tid == 0) s_es = sbuf2[0] + sbuf2[1] + sbuf2[2] + sbuf2[3];
  __syncthreads();
  const float esum = s_es;
  const float sprob = 0.9f * (1.0f / esum) + (0.1f / 1024.0f);
  const float stv = (1.0f - sprob) + sprob;
  if (tid == 0) { tok[b * NC + c] = s_arg; stval[b * NC + c] = stv; }
  if (finalstep) {
    float* orow = out + ((size_t)b * (NC + 2) + 1 + c) * NV;
#pragma unroll
    for (int j = 0; j < 4; ++j) {
      const int v = tid + (j << 8);
      orow[v] = (v == s_arg) ? stv : 0.0f;
    }
  }
}

__global__ __launch_bounds__(256) void k_out_init(float* __restrict__ out) {
  const int b = blockIdx.x;
  const int tid = threadIdx.x;
#pragma unroll
  for (int j = 0; j < 4; ++j) {
    const int v = tid + (j << 8);
    out[((size_t)b * (NC + 2) + 0) * NV + v]      = (v == 0) ? 1.0f : 0.0f;
    out[((size_t)b * (NC + 2) + NC + 1) * NV + v] = (v == 1) ? 1.0f : 0.0f;
  }
}

// ======================= host orchestration =============================
extern "C" void kernel_launch(void* const* d_in, const int* in_sizes, int n_in,
                              void* d_out, int out_size, void* d_ws, size_t ws_size,
                              hipStream_t stream) {
  (void)in_sizes; (void)n_in; (void)out_size;
  const float* prototypes = (const float*)d_in[0];
  const float* query      = (const float*)d_in[1];
  const float* ca_wq      = (const float*)d_in[2];
  const float* ca_wk      = (const float*)d_in[3];
  const float* ca_wv      = (const float*)d_in[4];
  const float* ca_wo      = (const float*)d_in[5];
  const float* ln1_w      = (const float*)d_in[6];
  const float* ln1_b      = (const float*)d_in[7];
  const float* qkv_w      = (const float*)d_in[8];
  const float* attn_out_w = (const float*)d_in[9];
  const float* rel_bias   = (const float*)d_in[10];
  const float* ln2_w      = (const float*)d_in[11];
  const float* ln2_b      = (const float*)d_in[12];
  const float* mlp_w1     = (const float*)d_in[13];
  const float* mlp_w2     = (const float*)d_in[14];
  const float* lnf_w      = (const float*)d_in[15];
  const float* lnf_b      = (const float*)d_in[16];
  const float* vocab_w    = (const float*)d_in[17];
  const float* vocab_b    = (const float*)d_in[18];
  const float* pos_emb    = (const float*)d_in[19];
  const float* tok_emb    = (const float*)d_in[20];
  float* out = (float*)d_out;

  dim3 thr(256);
  dim3 thr512(512);
  const size_t NEED = 234889216ull;

  if (ws_size >= NEED) {
    // ---- fast path: fp16x3 MFMA + BOS K/V cache + content-only steps ----
    char* p = (char*)d_ws;
    auto alloc = [&](size_t bytes) { char* r = p; p += (bytes + 255) & ~(size_t)255; return r; };
    half_t *WqH[NL], *WqL[NL], *WaH[NL], *WaL[NL], *W1H[NL], *W1L[NL], *W2H[NL], *W2L[NL];
    for (int l = 0; l < NL; ++l) {
      WqH[l] = (half_t*)alloc(3072 * 1024 * 2);
      WqL[l] = (half_t*)alloc(3072 * 1024 * 2);
      WaH[l] = (half_t*)alloc(1024 * 1024 * 2);
      WaL[l] = (half_t*)alloc(1024 * 1024 * 2);
      W1H[l] = (half_t*)alloc(4096 * 1024 * 2);
      W1L[l] = (half_t*)alloc(4096 * 1024 * 2);
      W2H[l] = (half_t*)alloc(1024 * 2048 * 2);
      W2L[l] = (half_t*)alloc(1024 * 2048 * 2);
    }
    half_t* WvH = (half_t*)alloc(1024 * 1024 * 2);
    half_t* WvL = (half_t*)alloc(1024 * 1024 * 2);
    half_t *KVh[NL], *KVl[NL];
    for (int l = 0; l < NL; ++l) {
      KVh[l] = (half_t*)alloc(1024 * 2048 * 2);    // (b*16+s, 2048) hi
      KVl[l] = (half_t*)alloc(1024 * 2048 * 2);    // lo
    }
    half_t* Hh  = (half_t*)alloc(1024 * 1024 * 2); // LN/attn-out/lnf planes
    half_t* Hl  = (half_t*)alloc(1024 * 1024 * 2);
    float*  X   = (float*)alloc(1024 * 1024 * 4);  // residual (BOS pre / content)
    char*  QKVr = alloc(12582912);                 // qkv planes + PARTS + prologue
    half_t* Mh  = (half_t*)alloc(1024 * 2048 * 2); // swiglu planes (hosts BOSb)
    half_t* Ml  = (half_t*)alloc(1024 * 2048 * 2);
    float* STV  = (float*)alloc(4096);
    int*   TOK  = (int*)alloc(4096);
    float* PARTS = (float*)QKVr;
    half_t* QKVh = (half_t*)QKVr;                  // (rows,3072) hi plane
    half_t* QKVl = QKVh + (size_t)1024 * 3072;     // lo plane
    float* BOSb  = (float*)Mh;                     // (NB*16, ND) — dead after build

    // ---- weight split ----
    for (int l = 0; l < NL; ++l) {
      k_splitw<<<dim3(32, 96), thr, 0, stream>>>(qkv_w + (size_t)l * ND * 3 * ND, WqH[l], WqL[l], 1024, 3072);
      k_splitw<<<dim3(32, 32), thr, 0, stream>>>(attn_out_w + (size_t)l * ND * ND, WaH[l], WaL[l], 1024, 1024);
      k_splitw_swz<<<dim3(32, 128), thr, 0, stream>>>(mlp_w1 + (size_t)l * ND * 2 * NHID, W1H[l], W1L[l], 1024, 4096);
      k_splitw<<<dim3(64, 32), thr, 0, stream>>>(mlp_w2 + (size_t)l * NHID * ND, W2H[l], W2L[l], 2048, 1024);
    }
    k_splitw<<<dim3(32, 32), thr, 0, stream>>>(vocab_w, WvH, WvL, 1024, 1024);

    // ---- cross attention prologue (fp32, scratch inside QKVr) ----
    float* QH = (float*)QKVr;
    float* KH = (float*)QKVr + 16384;
    float* VH = (float*)QKVr + 540672;
    float* BOSW = (float*)QKVr + 1064960;
    k_gemm<<<dim3(16, 1),  thr, 0, stream>>>(query,      ca_wq, QH,   nullptr, NBOS,    ND, ND, 0);
    k_gemm<<<dim3(16, 8),  thr, 0, stream>>>(prototypes, ca_wk, KH,   nullptr, NB * NP, ND, ND, 0);
    k_gemm<<<dim3(16, 8),  thr, 0, stream>>>(prototypes, ca_wv, VH,   nullptr, NB * NP, ND, ND, 0);
    k_ca_attn<<<dim3(NB * NH), thr, 0, stream>>>(QH, KH, VH, BOSW);
    k_gemm<<<dim3(16, 16), thr, 0, stream>>>(BOSW, ca_wo, BOSb, nullptr, NB * NBOS, ND, ND, 0);
    k_out_init<<<dim3(NB), thr, 0, stream>>>(out);

    // ---- one-time BOS pass: 1024 rows (b*16+s); cache per-layer K/V ----
    k_build_ln<<<dim3(1024), thr, 0, stream>>>(BOSb, pos_emb, tok_emb, TOK, STV,
                                               ln1_w, ln1_b, X, Hh, Hl, 0, NBOS);
    for (int l = 0; l < NL; ++l) {
      k_g3<2><<<dim3(24, 8, 1), thr512, 0, stream>>>(Hh, Hl, WqH[l], WqL[l], nullptr, QKVh, QKVl,
                                                     1024, 3072, 1024, 1024);
      k_copy_kv<<<dim3(1024), thr, 0, stream>>>(QKVh, QKVl, KVh[l], KVl[l]);
      k_attn16p<<<dim3(NB * NH), thr, 0, stream>>>(QKVh, QKVl, rel_bias + (size_t)l * (2 * NS - 1) * NH,
                                                   Hh, Hl, NBOS);
      k_g3<0><<<dim3(8, 8, 3), thr512, 0, stream>>>(Hh, Hl, WaH[l], WaL[l], PARTS, nullptr, nullptr,
                                                    1024, 1024, 1024, 352);
      k_red_ln<1><<<dim3(1024), thr, 0, stream>>>(PARTS, X, ln2_w + l * ND, ln2_b + l * ND, Hh, Hl, 1024);
      k_g3<1><<<dim3(32, 8, 1), thr512, 0, stream>>>(Hh, Hl, W1H[l], W1L[l], nullptr, Mh, Ml,
                                                     1024, 4096, 1024, 1024);
      k_g3<0><<<dim3(8, 8, 3), thr512, 0, stream>>>(Mh, Ml, W2H[l], W2L[l], PARTS, nullptr, nullptr,
                                                    1024, 1024, 2048, 704);
      if (l < NL - 1)
        k_red_ln<1><<<dim3(1024), thr, 0, stream>>>(PARTS, X, ln1_w + (l + 1) * ND, ln1_b + (l + 1) * ND,
                                                    Hh, Hl, 1024);
    }

    // ---- 14 autoregressive steps: content rows only (c <= i) ----
    for (int i = 0; i < NC; ++i) {
      const int ncur = i + 1;
      const int Mv = NB * ncur;                  // 64..896
      const int MP = (Mv + 127) & ~127;          // x128
      const int gy = MP / 128;

      k_build_ln_c<<<dim3(Mv), thr, 0, stream>>>(pos_emb, tok_emb, TOK, STV,
                                                 ln1_w, ln1_b, X, Hh, Hl, i, ncur);
      for (int l = 0; l < NL; ++l) {
        k_g3<2><<<dim3(24, gy, 1), thr512, 0, stream>>>(Hh, Hl, WqH[l], WqL[l], nullptr, QKVh, QKVl,
                                                        MP, 3072, 1024, 1024);
        k_attn16c<<<dim3(NB * NH), thr, 0, stream>>>(QKVh, QKVl, KVh[l], KVl[l],
                                                     rel_bias + (size_t)l * (2 * NS - 1) * NH,
                                                     Hh, Hl, ncur);
        k_g3<0><<<dim3(8, gy, 3), thr512, 0, stream>>>(Hh, Hl, WaH[l], WaL[l], PARTS, nullptr, nullptr,
                                                       MP, 1024, 1024, 352);
        k_red_ln<1><<<dim3(Mv), thr, 0, stream>>>(PARTS, X, ln2_w + l * ND, ln2_b + l * ND, Hh, Hl, MP);
        k_g3<1><<<dim3(32, gy, 1), thr512, 0, stream>>>(Hh, Hl, W1H[l], W1L[l], nullptr, Mh, Ml,
                                                        MP, 4096, 1024, 1024);
        k_g3<0><<<dim3(8, gy, 3), thr512, 0, stream>>>(Mh, Ml, W2H[l], W2L[l], PARTS, nullptr, nullptr,
                                                       MP, 1024, 2048, 704);
        if (l < NL - 1)
          k_red_ln<1><<<dim3(Mv), thr, 0, stream>>>(PARTS, X, ln1_w + (l + 1) * ND, ln1_b + (l + 1) * ND,
                                                    Hh, Hl, MP);
        else
          k_red_ln<0><<<dim3(Mv), thr, 0, stream>>>(PARTS, X, lnf_w, lnf_b, Hh, Hl, MP);
      }
      k_g3<0><<<dim3(8, gy, 3), thr512, 0, stream>>>(Hh, Hl, WvH, WvL, PARTS, nullptr, nullptr,
                                                     MP, 1024, 1024, 352);
      k_gumbel_t<1><<<dim3(Mv), thr, 0, stream>>>(PARTS, vocab_b, TOK, STV, out, i,
                                                  (i == NC - 1) ? 1 : 0, ncur, MP);
    }
    return;
  }

  // ---------------- fallback: round-1 fp32 path ----------------
  float* ws = (float*)d_ws;
  float* BOSW = ws + 0;
  float* BOSb = ws + 1048576;
  float* QH   = ws + 2097152;
  float* KH   = ws + 2113536;
  float* VH   = ws + 2637824;
  float* X    = ws + 3162112;
  float* Hb   = ws + 5128192;
  float* HL   = Hb;
  float* LG   = Hb + 917504;
  float* QKV  = ws + 7094272;
  float* U    = QKV;
  float* ATT  = ws + 14958592;
  float* Mb   = ATT;
  float* STV  = ws + 18890752;
  int*   TOK  = (int*)(ws + 18891648);

  k_gemm<<<dim3(16, 1),  thr, 0, stream>>>(query,      ca_wq, QH,   nullptr, NBOS,    ND, ND, 0);
  k_gemm<<<dim3(16, 8),  thr, 0, stream>>>(prototypes, ca_wk, KH,   nullptr, NB * NP, ND, ND, 0);
  k_gemm<<<dim3(16, 8),  thr, 0, stream>>>(prototypes, ca_wv, VH,   nullptr, NB * NP, ND, ND, 0);
  k_ca_attn<<<dim3(NB * NH), thr, 0, stream>>>(QH, KH, VH, BOSW);
  k_gemm<<<dim3(16, 16), thr, 0, stream>>>(BOSW, ca_wo, BOSb, nullptr, NB * NBOS, ND, ND, 0);
  k_out_init<<<dim3(NB), thr, 0, stream>>>(out);

  for (int i = 0; i < NC; ++i) {
    k_build_x<<<dim3(NB * NS), thr, 0, stream>>>(BOSb, pos_emb, tok_emb, TOK, STV, X, i);
    for (int l = 0; l < NL; ++l) {
      k_ln<<<dim3(NB * NS), thr, 0, stream>>>(X, ln1_w + l * ND, ln1_b + l * ND, Hb);
      k_gemm<<<dim3(48, 30), thr, 0, stream>>>(Hb, qkv_w + (size_t)l * ND * 3 * ND, QKV,
                                               nullptr, NB * NS, 3 * ND, ND, 0);
      k_attn<<<dim3(NB * NH), thr, 0, stream>>>(QKV, rel_bias + (size_t)l * (2 * NS - 1) * NH, ATT);
      k_gemm<<<dim3(16, 30), thr, 0, stream>>>(ATT, attn_out_w + (size_t)l * ND * ND, X,
                                               nullptr, NB * NS, ND, ND, 1);
      k_ln<<<dim3(NB * NS), thr, 0, stream>>>(X, ln2_w + l * ND, ln2_b + l * ND, Hb);
      k_gemm<<<dim3(64, 30), thr, 0, stream>>>(Hb, mlp_w1 + (size_t)l * ND * 2 * NHID, U,
                                               nullptr, NB * NS, 2 * NHID, ND, 0);
      k_swiglu<<<dim3(3840), thr, 0, stream>>>(U, Mb);
      k_gemm<<<dim3(16, 30), thr, 0, stream>>>(Mb, mlp_w2 + (size_t)l * NHID * ND, X,
                                               nullptr, NB * NS, ND, NHID, 1);
    }
    k_lnf<<<dim3(NB * NC), thr, 0, stream>>>(X, lnf_w, lnf_b, HL);
    k_gemm<<<dim3(16, 14), thr, 0, stream>>>(HL, vocab_w, LG, vocab_b, NB * NC, NV, ND, 2);
    k_gumbel_t<0><<<dim3(NB * NC), thr, 0, stream>>>(LG, nullptr, TOK, STV, out, i,
                                                     (i == NC - 1) ? 1 : 0, NC, 896);
  }
}

// Round 12
// 8815.175 us; speedup vs baseline: 1.7157x; 1.0043x over previous
//
#include <hip/hip_runtime.h>
#include <stdint.h>
#include <stddef.h>
#include <math.h>

// ---- problem dims ----
#define NB   64
#define NP   8
#define ND   1024
#define NH   16
#define NBOS 16
#define NC   14
#define NS   30   // BOS + C
#define NL   4
#define NV   1024
#define NHID 2048
#define NDH  64

#define JAX_PARTITIONABLE 1

typedef _Float16 half_t;
typedef _Float16 h4_t __attribute__((ext_vector_type(4)));
typedef _Float16 h8_t __attribute__((ext_vector_type(8)));
typedef float f32x4 __attribute__((ext_vector_type(4)));

// ======================= threefry2x32 (JAX-exact) =======================
__device__ __forceinline__ uint32_t rotl32(uint32_t x, int d) {
  return (x << d) | (x >> (32 - d));
}

__device__ __forceinline__ void threefry2x32(uint32_t k0, uint32_t k1,
                                             uint32_t x0, uint32_t x1,
                                             uint32_t& o0, uint32_t& o1) {
  uint32_t ks2 = k0 ^ k1 ^ 0x1BD11BDAu;
  x0 += k0; x1 += k1;
#define TF_R4(a,b,c,d) \
  x0 += x1; x1 = rotl32(x1,(a)); x1 ^= x0; \
  x0 += x1; x1 = rotl32(x1,(b)); x1 ^= x0; \
  x0 += x1; x1 = rotl32(x1,(c)); x1 ^= x0; \
  x0 += x1; x1 = rotl32(x1,(d)); x1 ^= x0;
  TF_R4(13,15,26,6)  x0 += k1;  x1 += ks2 + 1u;
  TF_R4(17,29,16,24) x0 += ks2; x1 += k0 + 2u;
  TF_R4(13,15,26,6)  x0 += k0;  x1 += k1 + 3u;
  TF_R4(17,29,16,24) x0 += k1;  x1 += ks2 + 4u;
  TF_R4(13,15,26,6)  x0 += ks2; x1 += k0 + 5u;
#undef TF_R4
  o0 = x0; o1 = x1;
}

// ======================= generic fp32 GEMM (prologue + fallback) ========
__global__ __launch_bounds__(256) void k_gemm(
    const float* __restrict__ A, const float* __restrict__ Bm,
    float* __restrict__ Cm, const float* __restrict__ bias,
    int M, int N, int K, int epi) {
  __shared__ __align__(16) float As[16][64];
  __shared__ __align__(16) float Bs[16][64];
  const int tid = threadIdx.x;
  const int tx = tid & 15, ty = tid >> 4;
  const int m0 = blockIdx.y * 64, n0 = blockIdx.x * 64;
  const int lar = tid >> 2, lak = (tid & 3) << 2;
  const int lbk = tid >> 4, lbn = (tid & 15) << 2;
  float acc[4][4] = {};
  for (int kt = 0; kt < K; kt += 16) {
    float4 av = make_float4(0.f, 0.f, 0.f, 0.f);
    if (m0 + lar < M)
      av = *(const float4*)(A + (size_t)(m0 + lar) * K + kt + lak);
    float4 bv4 = make_float4(0.f, 0.f, 0.f, 0.f);
    if (n0 + lbn < N)
      bv4 = *(const float4*)(Bm + (size_t)(kt + lbk) * N + n0 + lbn);
    __syncthreads();
    As[lak + 0][lar] = av.x; As[lak + 1][lar] = av.y;
    As[lak + 2][lar] = av.z; As[lak + 3][lar] = av.w;
    *(float4*)(&Bs[lbk][lbn]) = bv4;
    __syncthreads();
#pragma unroll
    for (int kk = 0; kk < 16; ++kk) {
      float4 a4 = *(const float4*)(&As[kk][ty << 2]);
      float4 b4 = *(const float4*)(&Bs[kk][tx << 2]);
      float ar[4] = {a4.x, a4.y, a4.z, a4.w};
      float br[4] = {b4.x, b4.y, b4.z, b4.w};
#pragma unroll
      for (int i2 = 0; i2 < 4; ++i2)
#pragma unroll
        for (int j2 = 0; j2 < 4; ++j2)
          acc[i2][j2] = fmaf(ar[i2], br[j2], acc[i2][j2]);
    }
  }
#pragma unroll
  for (int i2 = 0; i2 < 4; ++i2) {
    int r = m0 + (ty << 2) + i2;
    if (r >= M) continue;
#pragma unroll
    for (int j2 = 0; j2 < 4; ++j2) {
      int c = n0 + (tx << 2) + j2;
      if (c >= N) continue;
      size_t off = (size_t)r * N + c;
      float val = acc[i2][j2];
      if (epi == 1) val += Cm[off];
      else if (epi == 2) val += bias[c];
      Cm[off] = val;
    }
  }
}

// ===== fp16x3 MFMA GEMM (128x128, 8-wave, ring-4 counted-vmcnt) =========
// All fast-path grids are <= 256 blocks (<=1 block/CU), so the 128 KB LDS
// ring-4 costs no occupancy and buys 3-deep prefetch (R9-verified body).
__device__ __forceinline__ void gload16(const void* g, const void* l) {
  __builtin_amdgcn_global_load_lds((const __attribute__((address_space(1))) void*)g,
                                   (__attribute__((address_space(3))) void*)l, 16, 0, 0);
}

// XCD-aware chunked swizzle (per z-slice). gx must be %8==0.
__device__ __forceinline__ void xcd_swz(int gx, int gy, int& bx, int& by) {
  const int flat = blockIdx.y * gx + blockIdx.x;
  const int chunk = (gx * gy) >> 3;
  const int myid = (flat & 7) * chunk + (flat >> 3);
  bx = myid / gy;
  by = myid % gy;
}

// EPI 0: store partial fp32*(1/1024) at Cout + z*M*N
// EPI 1: fused SwiGLU -> Mh/Ml (col-permuted W1 layout), full-K only
// EPI 2: store split fp16 planes (raw value) -> Mh/Ml, full-K only
template<int EPI>
__global__ __launch_bounds__(512) void k_g3(
    const half_t* __restrict__ Ah, const half_t* __restrict__ Al,
    const half_t* __restrict__ Bh, const half_t* __restrict__ Bl,
    float* __restrict__ Cout, half_t* __restrict__ Mh, half_t* __restrict__ Ml,
    int M, int N, int K, int CH) {
  __shared__ __align__(16) half_t sAh[4][4096];
  __shared__ __align__(16) half_t sAl[4][4096];
  __shared__ __align__(16) half_t sBh[4][4096];
  __shared__ __align__(16) half_t sBl[4][4096];
  int bx, by; xcd_swz(gridDim.x, gridDim.y, bx, by);
  const int tid = threadIdx.x;
  const int lane = tid & 63, w = tid >> 6;       // 8 waves
  const int wm = w >> 2, wn = w & 3;             // 2 x 4 wave grid
  const int m0 = by * 128, n0 = bx * 128;
  const int fr = lane & 15, fq = lane >> 4;
  const int kbeg = blockIdx.z * CH;
  const int kend = (kbeg + CH < K) ? (kbeg + CH) : K;
  const int nt = (kend - kbeg) >> 5;             // K-tiles
  f32x4 acc[4][2] = {};
  const int r0 = tid >> 2, ch = (tid & 3) * 8;
  const size_t aB = (size_t)(m0 + r0) * K + ch;
  const size_t bB = (size_t)(n0 + r0) * K + ch;
  const int wb = w * 1024;   // per-wave dest byte offset within 8KB plane

  auto STAGE = [&](int buf, int kt) {   // 4 loads/thread (one per plane)
    gload16(Ah + aB + kt, (char*)(&sAh[buf][0]) + wb);
    gload16(Al + aB + kt, (char*)(&sAl[buf][0]) + wb);
    gload16(Bh + bB + kt, (char*)(&sBh[buf][0]) + wb);
    gload16(Bl + bB + kt, (char*)(&sBl[buf][0]) + wb);
  };

  // prologue: issue up to 3 stages ahead
  STAGE(0, kbeg);
  if (nt > 1) STAGE(1, kbeg + 32);
  if (nt > 2) STAGE(2, kbeg + 64);
  for (int t = 0; t < nt; ++t) {
    const int cur = t & 3;
    if (t + 3 < nt) STAGE((t + 3) & 3, kbeg + (t + 3) * 32);
    // wait for tile t's 4 loads: outstanding = 4 * (stages issued beyond t)
    const int rem = nt - 1 - t;
    if (rem >= 3)      asm volatile("s_waitcnt vmcnt(12)" ::: "memory");
    else if (rem == 2) asm volatile("s_waitcnt vmcnt(8)"  ::: "memory");
    else if (rem == 1) asm volatile("s_waitcnt vmcnt(4)"  ::: "memory");
    else               asm volatile("s_waitcnt vmcnt(0)"  ::: "memory");
    asm volatile("s_barrier" ::: "memory");        // all waves' cur staged
    const half_t* bAh = &sAh[cur][0] + (wm * 64 + fr) * 32 + fq * 8;
    const half_t* bAl = &sAl[cur][0] + (wm * 64 + fr) * 32 + fq * 8;
    const half_t* bBh = &sBh[cur][0] + (wn * 32 + fr) * 32 + fq * 8;
    const half_t* bBl = &sBl[cur][0] + (wn * 32 + fr) * 32 + fq * 8;
    h8_t a[4], b[2], tt[2];
#pragma unroll
    for (int mi = 0; mi < 4; ++mi) a[mi] = *(const h8_t*)(bAh + mi * 512);
#pragma unroll
    for (int ni = 0; ni < 2; ++ni) b[ni] = *(const h8_t*)(bBh + ni * 512);
#pragma unroll
    for (int mi = 0; mi < 4; ++mi)
#pragma unroll
      for (int ni = 0; ni < 2; ++ni)
        acc[mi][ni] = __builtin_amdgcn_mfma_f32_16x16x32_f16(a[mi], b[ni], acc[mi][ni], 0, 0, 0);
#pragma unroll
    for (int ni = 0; ni < 2; ++ni) tt[ni] = *(const h8_t*)(bBl + ni * 512);
#pragma unroll
    for (int mi = 0; mi < 4; ++mi)
#pragma unroll
      for (int ni = 0; ni < 2; ++ni)
        acc[mi][ni] = __builtin_amdgcn_mfma_f32_16x16x32_f16(a[mi], tt[ni], acc[mi][ni], 0, 0, 0);
#pragma unroll
    for (int mi = 0; mi < 4; ++mi) a[mi] = *(const h8_t*)(bAl + mi * 512);
    // all ds_reads of cur issued; barrier before a later stage may overwrite.
    asm volatile("s_barrier" ::: "memory");
#pragma unroll
    for (int mi = 0; mi < 4; ++mi)
#pragma unroll
      for (int ni = 0; ni < 2; ++ni)
        acc[mi][ni] = __builtin_amdgcn_mfma_f32_16x16x32_f16(a[mi], b[ni], acc[mi][ni], 0, 0, 0);
  }
  const float sc = 1.0f / 1024.0f;
  if (EPI == 0) {
    float* Cz = Cout + (size_t)blockIdx.z * M * N;
#pragma unroll
    for (int mi = 0; mi < 4; ++mi) {
      const int row = m0 + wm * 64 + mi * 16 + fq * 4;
#pragma unroll
      for (int ni = 0; ni < 2; ++ni) {
        const int col = n0 + wn * 32 + ni * 16 + fr;
        float* cp = Cz + (size_t)row * N + col;
#pragma unroll
        for (int j = 0; j < 4; ++j) cp[(size_t)j * N] = acc[mi][ni][j] * sc;
      }
    }
  } else if (EPI == 1) {
    const int hid = ((n0 + wn * 32) >> 1) + fr;
#pragma unroll
    for (int mi = 0; mi < 4; ++mi) {
      const int row = m0 + wm * 64 + mi * 16 + fq * 4;
#pragma unroll
      for (int j = 0; j < 4; ++j) {
        const float u1 = acc[mi][0][j] * sc;
        const float u2 = acc[mi][1][j] * sc;
        const float s = 1.0f / (1.0f + expf(-u1));
        const float y = (u1 * s) * u2 * 16.0f;
        const half_t hv = (half_t)y;
        const size_t off = (size_t)(row + j) * NHID + hid;
        Mh[off] = hv;
        Ml[off] = (half_t)(y - (float)hv);
      }
    }
  } else {
#pragma unroll
    for (int mi = 0; mi < 4; ++mi) {
      const int row = m0 + wm * 64 + mi * 16 + fq * 4;
#pragma unroll
      for (int ni = 0; ni < 2; ++ni) {
        const int col = n0 + wn * 32 + ni * 16 + fr;
#pragma unroll
        for (int j = 0; j < 4; ++j) {
          const float v = acc[mi][ni][j] * sc;
          const half_t hv = (half_t)v;
          const size_t off = (size_t)(row + j) * N + col;
          Mh[off] = hv;
          Ml[off] = (half_t)(v - (float)hv);
        }
      }
    }
  }
}

// ---- weight split: W:(K,N) fp32 -> Th,Tl:(N,K) fp16 x64 ----
__global__ __launch_bounds__(256) void k_splitw(
    const float* __restrict__ W, half_t* __restrict__ Th, half_t* __restrict__ Tl,
    int K, int N) {
  __shared__ float t[32][33];
  const int kb = blockIdx.x * 32, nb = blockIdx.y * 32;
  const int tid = threadIdx.x;
  const int rr = tid >> 5, cc = tid & 31;
#pragma unroll
  for (int i = 0; i < 4; ++i)
    t[rr + i * 8][cc] = W[(size_t)(kb + rr + i * 8) * N + nb + cc];
  __syncthreads();
#pragma unroll
  for (int i = 0; i < 4; ++i) {
    const int nr = rr + i * 8;
    const float x = t[cc][nr] * 64.0f;
    const half_t h = (half_t)x;
    const float r = x - (float)h;
    const size_t off = (size_t)(nb + nr) * K + kb + cc;
    Th[off] = h;
    Tl[off] = (half_t)r;
  }
}

// variant for mlp_w1: logical col n -> physical row p for swiglu pairing
__global__ __launch_bounds__(256) void k_splitw_swz(
    const float* __restrict__ W, half_t* __restrict__ Th, half_t* __restrict__ Tl,
    int K, int N) {
  __shared__ float t[32][33];
  const int kb = blockIdx.x * 32, nb = blockIdx.y * 32;
  const int tid = threadIdx.x;
  const int rr = tid >> 5, cc = tid & 31;
#pragma unroll
  for (int i = 0; i < 4; ++i)
    t[rr + i * 8][cc] = W[(size_t)(kb + rr + i * 8) * N + nb + cc];
  __syncthreads();
#pragma unroll
  for (int i = 0; i < 4; ++i) {
    const int n = nb + rr + i * 8;
    const int hid = n & (NHID - 1), half = n >> 11;
    const int p = ((hid >> 4) << 5) + (half << 4) + (hid & 15);
    const float x = t[cc][rr + i * 8] * 64.0f;
    const half_t h = (half_t)x;
    const float r = x - (float)h;
    const size_t off = (size_t)p * K + kb + cc;
    Th[off] = h;
    Tl[off] = (half_t)r;
  }
}

// ======================= cross attention (builds BOS) ===================
__global__ __launch_bounds__(256) void k_ca_attn(
    const float* __restrict__ qh, const float* __restrict__ kh,
    const float* __restrict__ vh, float* __restrict__ bosw) {
  const int b = blockIdx.x >> 4, h = blockIdx.x & 15;
  __shared__ float q[NBOS][NDH], kk[NP][NDH], vv[NP][NDH], a[NBOS][NP];
  const int tid = threadIdx.x;
  for (int idx = tid; idx < NBOS * NDH; idx += 256) {
    int qi = idx >> 6, d = idx & 63;
    q[qi][d] = qh[(size_t)qi * ND + h * NDH + d];
  }
  for (int idx = tid; idx < NP * NDH; idx += 256) {
    int p = idx >> 6, d = idx & 63;
    kk[p][d] = kh[(size_t)(b * NP + p) * ND + h * NDH + d];
    vv[p][d] = vh[(size_t)(b * NP + p) * ND + h * NDH + d];
  }
  __syncthreads();
  if (tid < NBOS * NP) {
    int qi = tid >> 3, p = tid & 7;
    float dot = 0.f;
    for (int d = 0; d < NDH; ++d) dot = fmaf(q[qi][d], kk[p][d], dot);
    a[qi][p] = dot / 64.0f;
  }
  __syncthreads();
  if (tid < NBOS) {
    float mx = a[tid][0];
    for (int p = 1; p < NP; ++p) mx = fmaxf(mx, a[tid][p]);
    float sum = 0.f;
    for (int p = 0; p < NP; ++p) { float e = expf(a[tid][p] - mx); a[tid][p] = e; sum += e; }
    for (int p = 0; p < NP; ++p) a[tid][p] /= sum;
  }
  __syncthreads();
  for (int idx = tid; idx < NBOS * NDH; idx += 256) {
    int qi = idx >> 6, d = idx & 63;
    float o = 0.f;
    for (int p = 0; p < NP; ++p) o = fmaf(a[qi][p], vv[p][d], o);
    bosw[(size_t)(b * NBOS + qi) * ND + h * NDH + d] = o;
  }
}

// ======================= self attention (fallback fp32 qkv) =============
__global__ __launch_bounds__(256) void k_attn(
    const float* __restrict__ qkv, const float* __restrict__ relb,
    float* __restrict__ attout) {
  const int b = blockIdx.x >> 4, h = blockIdx.x & 15;
  __shared__ float q[NS][NDH], kk[NS][NDH], vv[NS][NDH];
  __shared__ float a[NS][NS];
  const int tid = threadIdx.x;
  for (int idx = tid; idx < NS * NDH; idx += 256) {
    int s = idx >> 6, d = idx & 63;
    size_t base = ((size_t)(b * NS + s) * 3) * ND + h * NDH + d;
    q[s][d]  = qkv[base];
    kk[s][d] = qkv[base + ND];
    vv[s][d] = qkv[base + 2 * ND];
  }
  __syncthreads();
  for (int idx = tid; idx < NS * NS; idx += 256) {
    int i = idx / NS, j = idx % NS;
    float sc = 0.f;
    if (j <= i) {
      float dot = 0.f;
      for (int d = 0; d < NDH; ++d) dot = fmaf(q[i][d], kk[j][d], dot);
      sc = dot * 0.125f + relb[(size_t)(i - j + NS - 1) * NH + h];
    }
    a[i][j] = sc;
  }
  __syncthreads();
  if (tid < NS) {
    const int i = tid;
    float mx = -INFINITY;
    for (int j = 0; j <= i; ++j) mx = fmaxf(mx, a[i][j]);
    float sum = 0.f;
    for (int j = 0; j <= i; ++j) { float e = expf(a[i][j] - mx); a[i][j] = e; sum += e; }
    for (int j = 0; j <= i; ++j) a[i][j] /= sum;
    for (int j = i + 1; j < NS; ++j) a[i][j] = 0.f;
  }
  __syncthreads();
  for (int idx = tid; idx < NS * NDH; idx += 256) {
    int i = idx >> 6, d = idx & 63;
    float o = 0.f;
    for (int j = 0; j < NS; ++j) o = fmaf(a[i][j], vv[j][d], o);
    attout[(size_t)(b * NS + i) * ND + h * NDH + d] = o;
  }
}

// self attention on packed S rows, split qkv planes -> split out planes (x16)
// used for the one-time BOS precompute pass (S = 16).
__global__ __launch_bounds__(256) void k_attn16p(
    const half_t* __restrict__ Qh, const half_t* __restrict__ Ql,
    const float* __restrict__ relb,
    half_t* __restrict__ Oh, half_t* __restrict__ Ol, int S) {
  const int b = blockIdx.x >> 4, h = blockIdx.x & 15;
  __shared__ float q[NS][NDH], kk[NS][NDH], vv[NS][NDH];
  __shared__ float a[NS][NS];
  const int tid = threadIdx.x;
  for (int idx = tid; idx < S * NDH; idx += 256) {
    int s = idx >> 6, d = idx & 63;
    size_t base = (size_t)(b * S + s) * 3072 + h * NDH + d;
    q[s][d]  = (float)Qh[base] + (float)Ql[base];
    kk[s][d] = (float)Qh[base + 1024] + (float)Ql[base + 1024];
    vv[s][d] = (float)Qh[base + 2048] + (float)Ql[base + 2048];
  }
  __syncthreads();
  for (int idx = tid; idx < S * S; idx += 256) {
    int i = idx / S, j = idx % S;
    float sc = 0.f;
    if (j <= i) {
      float dot = 0.f;
      for (int d = 0; d < NDH; ++d) dot = fmaf(q[i][d], kk[j][d], dot);
      sc = dot * 0.125f + relb[(size_t)(i - j + NS - 1) * NH + h];
    }
    a[i][j] = sc;
  }
  __syncthreads();
  if (tid < S) {
    const int i = tid;
    float mx = -INFINITY;
    for (int j = 0; j <= i; ++j) mx = fmaxf(mx, a[i][j]);
    float sum = 0.f;
    for (int j = 0; j <= i; ++j) { float e = expf(a[i][j] - mx); a[i][j] = e; sum += e; }
    for (int j = 0; j <= i; ++j) a[i][j] /= sum;
    for (int j = i + 1; j < S; ++j) a[i][j] = 0.f;
  }
  __syncthreads();
  for (int idx = tid; idx < S * NDH; idx += 256) {
    int i = idx >> 6, d = idx & 63;
    float o = 0.f;
    for (int j = 0; j < S; ++j) o = fmaf(a[i][j], vv[j][d], o);
    const float y = o * 16.0f;
    const half_t hv = (half_t)y;
    const size_t off = (size_t)(b * S + i) * ND + h * NDH + d;
    Oh[off] = hv;
    Ol[off] = (half_t)(y - (float)hv);
  }
}

// copy K/V cols (1024..3071) of BOS QKV planes -> per-layer cache (stride 2048)
__global__ __launch_bounds__(256) void k_copy_kv(
    const half_t* __restrict__ Qh, const half_t* __restrict__ Ql,
    half_t* __restrict__ Ch, half_t* __restrict__ Cl) {
  const int row = blockIdx.x;           // 0..1023 = b*16+s
  const int c0 = threadIdx.x * 8;       // 0..2040
  const size_t src = (size_t)row * 3072 + 1024 + c0;
  const size_t dst = (size_t)row * 2048 + c0;
  *(h8_t*)(Ch + dst) = *(const h8_t*)(Qh + src);
  *(h8_t*)(Cl + dst) = *(const h8_t*)(Ql + src);
}

// content attention: queries = content rows c=0..ncur-1 (global pos 16+c),
// keys/values = cached BOS (16) + fresh content (ncur). Split planes in/out.
__global__ __launch_bounds__(256) void k_attn16c(
    const half_t* __restrict__ Qh, const half_t* __restrict__ Ql,
    const half_t* __restrict__ Ch, const half_t* __restrict__ Cl,
    const float* __restrict__ relb,
    half_t* __restrict__ Oh, half_t* __restrict__ Ol, int ncur) {
  const int b = blockIdx.x >> 4, h = blockIdx.x & 15;
  const int S = NBOS + ncur;            // keys: 17..30
  __shared__ float q[NC][NDH], kk[NS][NDH], vv[NS][NDH];
  __shared__ float a[NC][NS];
  const int tid = threadIdx.x;
  for (int idx = tid; idx < ncur * NDH; idx += 256) {
    int c = idx >> 6, d = idx & 63;
    size_t base = (size_t)(b * ncur + c) * 3072 + h * NDH + d;
    q[c][d] = (float)Qh[base] + (float)Ql[base];
  }
  for (int idx = tid; idx < S * NDH; idx += 256) {
    int j = idx >> 6, d = idx & 63;
    if (j < NBOS) {
      size_t r = (size_t)(b * NBOS + j) * 2048 + h * NDH + d;
      kk[j][d] = (float)Ch[r] + (float)Cl[r];
      vv[j][d] = (float)Ch[r + 1024] + (float)Cl[r + 1024];
    } else {
      size_t base = (size_t)(b * ncur + (j - NBOS)) * 3072 + h * NDH + d;
      kk[j][d] = (float)Qh[base + 1024] + (float)Ql[base + 1024];
      vv[j][d] = (float)Qh[base + 2048] + (float)Ql[base + 2048];
    }
  }
  __syncthreads();
  for (int idx = tid; idx < ncur * S; idx += 256) {
    int c = idx / S, j = idx % S;
    const int s = NBOS + c;
    float sc = 0.f;
    if (j <= s) {
      float dot = 0.f;
      for (int d = 0; d < NDH; ++d) dot = fmaf(q[c][d], kk[j][d], dot);
      sc = dot * 0.125f + relb[(size_t)(s - j + NS - 1) * NH + h];
    }
    a[c][j] = sc;
  }
  __syncthreads();
  if (tid < ncur) {
    const int c = tid, s = NBOS + c;
    float mx = -INFINITY;
    for (int j = 0; j <= s; ++j) mx = fmaxf(mx, a[c][j]);
    float sum = 0.f;
    for (int j = 0; j <= s; ++j) { float e = expf(a[c][j] - mx); a[c][j] = e; sum += e; }
    for (int j = 0; j <= s; ++j) a[c][j] /= sum;
    for (int j = s + 1; j < S; ++j) a[c][j] = 0.f;
  }
  __syncthreads();
  for (int idx = tid; idx < ncur * NDH; idx += 256) {
    int c = idx >> 6, d = idx & 63;
    float o = 0.f;
    for (int j = 0; j < S; ++j) o = fmaf(a[c][j], vv[j][d], o);
    const float y = o * 16.0f;
    const half_t hv = (half_t)y;
    const size_t off = (size_t)(b * ncur + c) * ND + h * NDH + d;
    Oh[off] = hv;
    Ol[off] = (half_t)(y - (float)hv);
  }
}

// ======================= layernorm cores ================================
__device__ __forceinline__ float block_sum(float val, float* sbuf) {
  for (int off = 32; off > 0; off >>= 1) val += __shfl_down(val, off, 64);
  const int wid = threadIdx.x >> 6;
  if ((threadIdx.x & 63) == 0) sbuf[wid] = val;
  __syncthreads();
  if (threadIdx.x == 0) sbuf[0] = sbuf[0] + sbuf[1] + sbuf[2] + sbuf[3];
  __syncthreads();
  float r = sbuf[0];
  __syncthreads();
  return r;
}

__device__ __forceinline__ void ln_core_emit16(
    float4 x4, const float* w, const float* bvec, float* sbuf,
    half_t* Oh, half_t* Ol, size_t rowoff, int d0) {
  float mean = block_sum(x4.x + x4.y + x4.z + x4.w, sbuf) * (1.0f / 1024.0f);
  float dx0 = x4.x - mean, dx1 = x4.y - mean, dx2 = x4.z - mean, dx3 = x4.w - mean;
  float var = block_sum(dx0*dx0 + dx1*dx1 + dx2*dx2 + dx3*dx3, sbuf) * (1.0f / 1024.0f);
  float rs = 1.0f / sqrtf(var + 1e-5f);
  float4 w4 = *(const float4*)(w + d0);
  float4 b4 = *(const float4*)(bvec + d0);
  float y0 = (dx0 * rs * w4.x + b4.x) * 16.0f;
  float y1 = (dx1 * rs * w4.y + b4.y) * 16.0f;
  float y2 = (dx2 * rs * w4.z + b4.z) * 16.0f;
  float y3 = (dx3 * rs * w4.w + b4.w) * 16.0f;
  h4_t vh, vl;
  vh.x = (half_t)y0; vl.x = (half_t)(y0 - (float)vh.x);
  vh.y = (half_t)y1; vl.y = (half_t)(y1 - (float)vh.y);
  vh.z = (half_t)y2; vl.z = (half_t)(y2 - (float)vh.z);
  vh.w = (half_t)y3; vl.w = (half_t)(y3 - (float)vh.w);
  *(h4_t*)(Oh + rowoff + d0) = vh;
  *(h4_t*)(Ol + rowoff + d0) = vl;
}

// fallback fp32 LN
__global__ __launch_bounds__(256) void k_ln(
    const float* __restrict__ in, const float* __restrict__ w,
    const float* __restrict__ bvec, float* __restrict__ out) {
  __shared__ float sbuf[4];
  const size_t row = blockIdx.x;
  const int d0 = threadIdx.x << 2;
  float4 x4 = *(const float4*)(in + row * ND + d0);
  float mean = block_sum(x4.x + x4.y + x4.z + x4.w, sbuf) * (1.0f / 1024.0f);
  float dx0 = x4.x - mean, dx1 = x4.y - mean, dx2 = x4.z - mean, dx3 = x4.w - mean;
  float var = block_sum(dx0*dx0 + dx1*dx1 + dx2*dx2 + dx3*dx3, sbuf) * (1.0f / 1024.0f);
  float rs = 1.0f / sqrtf(var + 1e-5f);
  float4 w4 = *(const float4*)(w + d0);
  float4 b4 = *(const float4*)(bvec + d0);
  float4 o;
  o.x = dx0 * rs * w4.x + b4.x;
  o.y = dx1 * rs * w4.y + b4.y;
  o.z = dx2 * rs * w4.z + b4.z;
  o.w = dx3 * rs * w4.w + b4.w;
  *(float4*)(out + row * ND + d0) = o;
}

// fused: X[row] += sum3(parts[row]); LN -> split planes. Packed rows; Mp =
// padded partial stride (rows). WRITEX=0 doubles as the lnf epilogue.
template<int WRITEX>
__global__ __launch_bounds__(256) void k_red_ln(
    const float* __restrict__ parts, float* __restrict__ X,
    const float* __restrict__ w, const float* __restrict__ bvec,
    half_t* __restrict__ Oh, half_t* __restrict__ Ol, int Mp) {
  __shared__ float sbuf[4];
  const size_t row = blockIdx.x;
  const int d0 = threadIdx.x << 2;
  const size_t off = row * ND + d0;
  const size_t MN = (size_t)Mp * 1024;
  float4 x4 = *(const float4*)(X + off);
  float4 p0 = *(const float4*)(parts + off);
  float4 p1 = *(const float4*)(parts + MN + off);
  float4 p2 = *(const float4*)(parts + 2 * MN + off);
  x4.x += p0.x + p1.x + p2.x; x4.y += p0.y + p1.y + p2.y;
  x4.z += p0.z + p1.z + p2.z; x4.w += p0.w + p1.w + p2.w;
  if (WRITEX) *(float4*)(X + off) = x4;
  ln_core_emit16(x4, w, bvec, sbuf, Oh, Ol, row * ND, d0);
}

// fp32 lnf (fallback)
__global__ __launch_bounds__(256) void k_lnf(
    const float* __restrict__ x, const float* __restrict__ w,
    const float* __restrict__ bvec, float* __restrict__ out) {
  __shared__ float sbuf[4];
  const int blk = blockIdx.x;
  const int b = blk / NC, c = blk % NC;
  const size_t row = (size_t)b * NS + NBOS + c;
  const int d0 = threadIdx.x << 2;
  float4 x4 = *(const float4*)(x + row * ND + d0);
  float mean = block_sum(x4.x + x4.y + x4.z + x4.w, sbuf) * (1.0f / 1024.0f);
  float dx0 = x4.x - mean, dx1 = x4.y - mean, dx2 = x4.z - mean, dx3 = x4.w - mean;
  float var = block_sum(dx0*dx0 + dx1*dx1 + dx2*dx2 + dx3*dx3, sbuf) * (1.0f / 1024.0f);
  float rs = 1.0f / sqrtf(var + 1e-5f);
  float4 w4 = *(const float4*)(w + d0);
  float4 b4 = *(const float4*)(bvec + d0);
  float4 o;
  o.x = dx0 * rs * w4.x + b4.x;
  o.y = dx1 * rs * w4.y + b4.y;
  o.z = dx2 * rs * w4.z + b4.z;
  o.w = dx3 * rs * w4.w + b4.w;
  *(float4*)(out + (size_t)blk * ND + d0) = o;
}

// ======================= build x (+ fused LN1) ==========================
__device__ __forceinline__ float4 build_row(
    const float* bos, const float* pos_emb, const float* tok_emb,
    const int* tok, const float* stval, int b, int s, int d0, int step) {
  float4 o;
  if (s < NBOS) {
    o = *(const float4*)(bos + (size_t)(b * NBOS + s) * ND + d0);
  } else {
    int j = s - NBOS;
    if (j < step) {
      float sv = stval[b * NC + j];
      int t = tok[b * NC + j];
      float4 e = *(const float4*)(tok_emb + (size_t)t * ND + d0);
      o.x = sv * e.x; o.y = sv * e.y; o.z = sv * e.z; o.w = sv * e.w;
    } else {
      o = *(const float4*)(pos_emb + (size_t)j * ND + d0);
    }
  }
  return o;
}

__global__ __launch_bounds__(256) void k_build_x(
    const float* __restrict__ bos, const float* __restrict__ pos_emb,
    const float* __restrict__ tok_emb, const int* __restrict__ tok,
    const float* __restrict__ stval, float* __restrict__ x, int step) {
  const int row = blockIdx.x;
  const int b = row / NS, s = row % NS;
  const int d0 = threadIdx.x << 2;
  float4 o = build_row(bos, pos_emb, tok_emb, tok, stval, b, s, d0, step);
  *(float4*)(x + (size_t)row * ND + d0) = o;
}

// packed build + fused LN1 (S rows per batch; used once for BOS with S=16)
__global__ __launch_bounds__(256) void k_build_ln(
    const float* __restrict__ bos, const float* __restrict__ pos_emb,
    const float* __restrict__ tok_emb, const int* __restrict__ tok,
    const float* __restrict__ stval, const float* __restrict__ w,
    const float* __restrict__ bvec, float* __restrict__ x,
    half_t* __restrict__ Oh, half_t* __restrict__ Ol, int step, int S) {
  __shared__ float sbuf[4];
  const int row = blockIdx.x;
  const int b = row / S, s = row % S;
  const int d0 = threadIdx.x << 2;
  float4 o = build_row(bos, pos_emb, tok_emb, tok, stval, b, s, d0, step);
  *(float4*)(x + (size_t)row * ND + d0) = o;
  ln_core_emit16(o, w, bvec, sbuf, Oh, Ol, (size_t)row * ND, d0);
}

// content-only build + LN1: row = b*ncur + c, logical position s = NBOS+c
__global__ __launch_bounds__(256) void k_build_ln_c(
    const float* __restrict__ pos_emb, const float* __restrict__ tok_emb,
    const int* __restrict__ tok, const float* __restrict__ stval,
    const float* __restrict__ w, const float* __restrict__ bvec,
    float* __restrict__ x, half_t* __restrict__ Oh, half_t* __restrict__ Ol,
    int step, int ncur) {
  __shared__ float sbuf[4];
  const int row = blockIdx.x;
  const int b = row / ncur, c = row % ncur;
  const int d0 = threadIdx.x << 2;
  float4 o;
  if (c < step) {
    float sv = stval[b * NC + c];
    int t = tok[b * NC + c];
    float4 e = *(const float4*)(tok_emb + (size_t)t * ND + d0);
    o.x = sv * e.x; o.y = sv * e.y; o.z = sv * e.z; o.w = sv * e.w;
  } else {
    o = *(const float4*)(pos_emb + (size_t)c * ND + d0);
  }
  *(float4*)(x + (size_t)row * ND + d0) = o;
  ln_core_emit16(o, w, bvec, sbuf, Oh, Ol, (size_t)row * ND, d0);
}

// ======================= SwiGLU (fallback) ==============================
__global__ __launch_bounds__(256) void k_swiglu(const float* __restrict__ u,
                                                float* __restrict__ m) {
  const size_t idx4 = (size_t)blockIdx.x * 256 + threadIdx.x;
  const size_t row = idx4 >> 9;
  const size_t c0 = (idx4 & 511) << 2;
  const float* ur = u + row * (2 * NHID);
  float4 a4 = *(const float4*)(ur + c0);
  float4 b4 = *(const float4*)(ur + NHID + c0);
  float4 o;
  { float s = 1.0f / (1.0f + expf(-a4.x)); o.x = (a4.x * s) * b4.x; }
  { float s = 1.0f / (1.0f + expf(-a4.y)); o.y = (a4.y * s) * b4.y; }
  { float s = 1.0f / (1.0f + expf(-a4.z)); o.z = (a4.z * s) * b4.z; }
  { float s = 1.0f / (1.0f + expf(-a4.w)); o.w = (a4.w * s) * b4.w; }
  *(float4*)(m + row * NHID + c0) = o;
}

// ======================= gumbel + argmax + st ===========================
// GRED=1: logits = sum of 3 partials (stride Mp*1024) + bias. Packed blocks
// blk = b*ncur + c; threefry/tok indices use logical (b, c) with NC stride.
template<int GRED>
__global__ __launch_bounds__(256) void k_gumbel_t(
    const float* __restrict__ logits, const float* __restrict__ vb,
    int* __restrict__ tok, float* __restrict__ stval, float* __restrict__ out,
    int step, int finalstep, int ncur, int Mp) {
  const int blk = blockIdx.x;
  const int b = blk / ncur, c = blk % ncur;
  const int tid = threadIdx.x;
  uint32_t fk0, fk1;
  threefry2x32(0u, 42u, 0u, (uint32_t)step, fk0, fk1);
  const float* zrow = logits + (size_t)blk * NV;
  const size_t MN = (size_t)Mp * 1024;
  float y[4];
  float bv = -INFINITY; int bi = 0;
#pragma unroll
  for (int j = 0; j < 4; ++j) {
    const int v = tid + (j << 8);
    const uint32_t idx = (uint32_t)(b * NC + c) * 1024u + (uint32_t)v;
    uint32_t o0, o1, bits;
#if JAX_PARTITIONABLE
    threefry2x32(fk0, fk1, 0u, idx, o0, o1);
    bits = o0 ^ o1;
#else
    const uint32_t half = (uint32_t)(NB * NC * NV / 2);
    uint32_t jj = (idx < half) ? idx : idx - half;
    threefry2x32(fk0, fk1, jj, jj + half, o0, o1);
    bits = (idx < half) ? o0 : o1;
#endif
    float f = __uint_as_float(0x3F800000u | (bits >> 9)) - 1.0f;
    float uu = (f == 0.0f) ? 1.17549435e-38f : f;
    float g = -logf(-logf(uu));
    float z;
    if (GRED) z = zrow[v] + zrow[MN + v] + zrow[2 * MN + v] + vb[v];
    else      z = zrow[v];
    float yv = z + g;
    y[j] = yv;
    if (yv > bv) { bv = yv; bi = v; }
  }
  __shared__ float swv[4]; __shared__ int swi[4];
  __shared__ float s_ymax; __shared__ int s_arg;
  for (int off = 32; off > 0; off >>= 1) {
    float ov = __shfl_down(bv, off, 64);
    int   oi = __shfl_down(bi, off, 64);
    if (ov > bv || (ov == bv && oi < bi)) { bv = ov; bi = oi; }
  }
  if ((tid & 63) == 0) { swv[tid >> 6] = bv; swi[tid >> 6] = bi; }
  __syncthreads();
  if (tid == 0) {
    float mv = swv[0]; int mi = swi[0];
    for (int w2 = 1; w2 < 4; ++w2)
      if (swv[w2] > mv || (swv[w2] == mv && swi[w2] < mi)) { mv = swv[w2]; mi = swi[w2]; }
    s_ymax = mv; s_arg = mi;
  }
  __syncthreads();
  const float ymax = s_ymax;
  float es = 0.f;
#pragma unroll
  for (int j = 0; j < 4; ++j) es += expf(y[j] - ymax);
  __shared__ float sbuf2[4]; __shared__ float s_es;
  for (int off = 32; off > 0; off >>= 1) es += __shfl_down(es, off, 64);
  if ((tid & 63) == 0) sbuf2[tid >> 6] = es;
  __syncthreads();
  if (tid == 0) s_es = sbuf2[0] + sbuf2[1] + sbuf2[2] + sbuf2[3];
  __syncthreads();
  const float esum = s_es;
  const float sprob = 0.9f * (1.0f / esum) + (0.1f / 1024.0f);
  const float stv = (1.0f - sprob) + sprob;
  if (tid == 0) { tok[b * NC + c] = s_arg; stval[b * NC + c] = stv; }
  if (finalstep) {
    float* orow = out + ((size_t)b * (NC + 2) + 1 + c) * NV;
#pragma unroll
    for (int j = 0; j < 4; ++j) {
      const int v = tid + (j << 8);
      orow[v] = (v == s_arg) ? stv : 0.0f;
    }
  }
}

__global__ __launch_bounds__(256) void k_out_init(float* __restrict__ out) {
  const int b = blockIdx.x;
  const int tid = threadIdx.x;
#pragma unroll
  for (int j = 0; j < 4; ++j) {
    const int v = tid + (j << 8);
    out[((size_t)b * (NC + 2) + 0) * NV + v]      = (v == 0) ? 1.0f : 0.0f;
    out[((size_t)b * (NC + 2) + NC + 1) * NV + v] = (v == 1) ? 1.0f : 0.0f;
  }
}

// ======================= host orchestration =============================
extern "C" void kernel_launch(void* const* d_in, const int* in_sizes, int n_in,
                              void* d_out, int out_size, void* d_ws, size_t ws_size,
                              hipStream_t stream) {
  (void)in_sizes; (void)n_in; (void)out_size;
  const float* prototypes = (const float*)d_in[0];
  const float* query      = (const float*)d_in[1];
  const float* ca_wq      = (const float*)d_in[2];
  const float* ca_wk      = (const float*)d_in[3];
  const float* ca_wv      = (const float*)d_in[4];
  const float* ca_wo      = (const float*)d_in[5];
  const float* ln1_w      = (const float*)d_in[6];
  const float* ln1_b      = (const float*)d_in[7];
  const float* qkv_w      = (const float*)d_in[8];
  const float* attn_out_w = (const float*)d_in[9];
  const float* rel_bias   = (const float*)d_in[10];
  const float* ln2_w      = (const float*)d_in[11];
  const float* ln2_b      = (const float*)d_in[12];
  const float* mlp_w1     = (const float*)d_in[13];
  const float* mlp_w2     = (const float*)d_in[14];
  const float* lnf_w      = (const float*)d_in[15];
  const float* lnf_b      = (const float*)d_in[16];
  const float* vocab_w    = (const float*)d_in[17];
  const float* vocab_b    = (const float*)d_in[18];
  const float* pos_emb    = (const float*)d_in[19];
  const float* tok_emb    = (const float*)d_in[20];
  float* out = (float*)d_out;

  dim3 thr(256);
  dim3 thr512(512);
  const size_t NEED = 234889216ull;

  if (ws_size >= NEED) {
    // ---- fast path: fp16x3 MFMA (ring-4) + BOS K/V cache + content steps ----
    char* p = (char*)d_ws;
    auto alloc = [&](size_t bytes) { char* r = p; p += (bytes + 255) & ~(size_t)255; return r; };
    half_t *WqH[NL], *WqL[NL], *WaH[NL], *WaL[NL], *W1H[NL], *W1L[NL], *W2H[NL], *W2L[NL];
    for (int l = 0; l < NL; ++l) {
      WqH[l] = (half_t*)alloc(3072 * 1024 * 2);
      WqL[l] = (half_t*)alloc(3072 * 1024 * 2);
      WaH[l] = (half_t*)alloc(1024 * 1024 * 2);
      WaL[l] = (half_t*)alloc(1024 * 1024 * 2);
      W1H[l] = (half_t*)alloc(4096 * 1024 * 2);
      W1L[l] = (half_t*)alloc(4096 * 1024 * 2);
      W2H[l] = (half_t*)alloc(1024 * 2048 * 2);
      W2L[l] = (half_t*)alloc(1024 * 2048 * 2);
    }
    half_t* WvH = (half_t*)alloc(1024 * 1024 * 2);
    half_t* WvL = (half_t*)alloc(1024 * 1024 * 2);
    half_t *KVh[NL], *KVl[NL];
    for (int l = 0; l < NL; ++l) {
      KVh[l] = (half_t*)alloc(1024 * 2048 * 2);    // (b*16+s, 2048) hi
      KVl[l] = (half_t*)alloc(1024 * 2048 * 2);    // lo
    }
    half_t* Hh  = (half_t*)alloc(1024 * 1024 * 2); // LN/attn-out/lnf planes
    half_t* Hl  = (half_t*)alloc(1024 * 1024 * 2);
    float*  X   = (float*)alloc(1024 * 1024 * 4);  // residual (BOS pre / content)
    char*  QKVr = alloc(12582912);                 // qkv planes + PARTS + prologue
    half_t* Mh  = (half_t*)alloc(1024 * 2048 * 2); // swiglu planes (hosts BOSb)
    half_t* Ml  = (half_t*)alloc(1024 * 2048 * 2);
    float* STV  = (float*)alloc(4096);
    int*   TOK  = (int*)alloc(4096);
    float* PARTS = (float*)QKVr;
    half_t* QKVh = (half_t*)QKVr;                  // (rows,3072) hi plane
    half_t* QKVl = QKVh + (size_t)1024 * 3072;     // lo plane
    float* BOSb  = (float*)Mh;                     // (NB*16, ND) — dead after build

    // ---- weight split ----
    for (int l = 0; l < NL; ++l) {
      k_splitw<<<dim3(32, 96), thr, 0, stream>>>(qkv_w + (size_t)l * ND * 3 * ND, WqH[l], WqL[l], 1024, 3072);
      k_splitw<<<dim3(32, 32), thr, 0, stream>>>(attn_out_w + (size_t)l * ND * ND, WaH[l], WaL[l], 1024, 1024);
      k_splitw_swz<<<dim3(32, 128), thr, 0, stream>>>(mlp_w1 + (size_t)l * ND * 2 * NHID, W1H[l], W1L[l], 1024, 4096);
      k_splitw<<<dim3(64, 32), thr, 0, stream>>>(mlp_w2 + (size_t)l * NHID * ND, W2H[l], W2L[l], 2048, 1024);
    }
    k_splitw<<<dim3(32, 32), thr, 0, stream>>>(vocab_w, WvH, WvL, 1024, 1024);

    // ---- cross attention prologue (fp32, scratch inside QKVr) ----
    float* QH = (float*)QKVr;
    float* KH = (float*)QKVr + 16384;
    float* VH = (float*)QKVr + 540672;
    float* BOSW = (float*)QKVr + 1064960;
    k_gemm<<<dim3(16, 1),  thr, 0, stream>>>(query,      ca_wq, QH,   nullptr, NBOS,    ND, ND, 0);
    k_gemm<<<dim3(16, 8),  thr, 0, stream>>>(prototypes, ca_wk, KH,   nullptr, NB * NP, ND, ND, 0);
    k_gemm<<<dim3(16, 8),  thr, 0, stream>>>(prototypes, ca_wv, VH,   nullptr, NB * NP, ND, ND, 0);
    k_ca_attn<<<dim3(NB * NH), thr, 0, stream>>>(QH, KH, VH, BOSW);
    k_gemm<<<dim3(16, 16), thr, 0, stream>>>(BOSW, ca_wo, BOSb, nullptr, NB * NBOS, ND, ND, 0);
    k_out_init<<<dim3(NB), thr, 0, stream>>>(out);

    // ---- one-time BOS pass: 1024 rows (b*16+s); cache per-layer K/V ----
    k_build_ln<<<dim3(1024), thr, 0, stream>>>(BOSb, pos_emb, tok_emb, TOK, STV,
                                               ln1_w, ln1_b, X, Hh, Hl, 0, NBOS);
    for (int l = 0; l < NL; ++l) {
      k_g3<2><<<dim3(24, 8, 1), thr512, 0, stream>>>(Hh, Hl, WqH[l], WqL[l], nullptr, QKVh, QKVl,
                                                     1024, 3072, 1024, 1024);
      k_copy_kv<<<dim3(1024), thr, 0, stream>>>(QKVh, QKVl, KVh[l], KVl[l]);
      k_attn16p<<<dim3(NB * NH), thr, 0, stream>>>(QKVh, QKVl, rel_bias + (size_t)l * (2 * NS - 1) * NH,
                                                   Hh, Hl, NBOS);
      k_g3<0><<<dim3(8, 8, 3), thr512, 0, stream>>>(Hh, Hl, WaH[l], WaL[l], PARTS, nullptr, nullptr,
                                                    1024, 1024, 1024, 352);
      k_red_ln<1><<<dim3(1024), thr, 0, stream>>>(PARTS, X, ln2_w + l * ND, ln2_b + l * ND, Hh, Hl, 1024);
      k_g3<1><<<dim3(32, 8, 1), thr512, 0, stream>>>(Hh, Hl, W1H[l], W1L[l], nullptr, Mh, Ml,
                                                     1024, 4096, 1024, 1024);
      k_g3<0><<<dim3(8, 8, 3), thr512, 0, stream>>>(Mh, Ml, W2H[l], W2L[l], PARTS, nullptr, nullptr,
                                                    1024, 1024, 2048, 704);
      if (l < NL - 1)
        k_red_ln<1><<<dim3(1024), thr, 0, stream>>>(PARTS, X, ln1_w + (l + 1) * ND, ln1_b + (l + 1) * ND,
                                                    Hh, Hl, 1024);
    }

    // ---- 14 autoregressive steps: content rows only (c <= i) ----
    for (int i = 0; i < NC; ++i) {
      const int ncur = i + 1;
      const int Mv = NB * ncur;                  // 64..896
      const int MP = (Mv + 127) & ~127;          // x128
      const int gy = MP / 128;

      k_build_ln_c<<<dim3(Mv), thr, 0, stream>>>(pos_emb, tok_emb, TOK, STV,
                                                 ln1_w, ln1_b, X, Hh, Hl, i, ncur);
      for (int l = 0; l < NL; ++l) {
        k_g3<2><<<dim3(24, gy, 1), thr512, 0, stream>>>(Hh, Hl, WqH[l], WqL[l], nullptr, QKVh, QKVl,
                                                        MP, 3072, 1024, 1024);
        k_attn16c<<<dim3(NB * NH), thr, 0, stream>>>(QKVh, QKVl, KVh[l], KVl[l],
                                                     rel_bias + (size_t)l * (2 * NS - 1) * NH,
                                                     Hh, Hl, ncur);
        k_g3<0><<<dim3(8, gy, 3), thr512, 0, stream>>>(Hh, Hl, WaH[l], WaL[l], PARTS, nullptr, nullptr,
                                                       MP, 1024, 1024, 352);
        k_red_ln<1><<<dim3(Mv), thr, 0, stream>>>(PARTS, X, ln2_w + l * ND, ln2_b + l * ND, Hh, Hl, MP);
        k_g3<1><<<dim3(32, gy, 1), thr512, 0, stream>>>(Hh, Hl, W1H[l], W1L[l], nullptr, Mh, Ml,
                                                        MP, 4096, 1024, 1024);
        k_g3<0><<<dim3(8, gy, 3), thr512, 0, stream>>>(Mh, Ml, W2H[l], W2L[l], PARTS, nullptr, nullptr,
                                                       MP, 1024, 2048, 704);
        if (l < NL - 1)
          k_red_ln<1><<<dim3(Mv), thr, 0, stream>>>(PARTS, X, ln1_w + (l + 1) * ND, ln1_b + (l + 1) * ND,
                                                    Hh, Hl, MP);
        else
          k_red_ln<0><<<dim3(Mv), thr, 0, stream>>>(PARTS, X, lnf_w, lnf_b, Hh, Hl, MP);
      }
      k_g3<0><<<dim3(8, gy, 3), thr512, 0, stream>>>(Hh, Hl, WvH, WvL, PARTS, nullptr, nullptr,
                                                     MP, 1024, 1024, 352);
      k_gumbel_t<1><<<dim3(Mv), thr, 0, stream>>>(PARTS, vocab_b, TOK, STV, out, i,
                                                  (i == NC - 1) ? 1 : 0, ncur, MP);
    }
    return;
  }

  // ---------------- fallback: round-1 fp32 path ----------------
  float* ws = (float*)d_ws;
  float* BOSW = ws + 0;
  float* BOSb = ws + 1048576;
  float* QH   = ws + 2097152;
  float* KH   = ws + 2113536;
  float* VH   = ws + 2637824;
  float* X    = ws + 3162112;
  float* Hb   = ws + 5128192;
  float* HL   = Hb;
  float* LG   = Hb + 917504;
  float* QKV  = ws + 7094272;
  float* U    = QKV;
  float* ATT  = ws + 14958592;
  float* Mb   = ATT;
  float* STV  = ws + 18890752;
  int*   TOK  = (int*)(ws + 18891648);

  k_gemm<<<dim3(16, 1),  thr, 0, stream>>>(query,      ca_wq, QH,   nullptr, NBOS,    ND, ND, 0);
  k_gemm<<<dim3(16, 8),  thr, 0, stream>>>(prototypes, ca_wk, KH,   nullptr, NB * NP, ND, ND, 0);
  k_gemm<<<dim3(16, 8),  thr, 0, stream>>>(prototypes, ca_wv, VH,   nullptr, NB * NP, ND, ND, 0);
  k_ca_attn<<<dim3(NB * NH), thr, 0, stream>>>(QH, KH, VH, BOSW);
  k_gemm<<<dim3(16, 16), thr, 0, stream>>>(BOSW, ca_wo, BOSb, nullptr, NB * NBOS, ND, ND, 0);
  k_out_init<<<dim3(NB), thr, 0, stream>>>(out);

  for (int i = 0; i < NC; ++i) {
    k_build_x<<<dim3(NB * NS), thr, 0, stream>>>(BOSb, pos_emb, tok_emb, TOK, STV, X, i);
    for (int l = 0; l < NL; ++l) {
      k_ln<<<dim3(NB * NS), thr, 0, stream>>>(X, ln1_w + l * ND, ln1_b + l * ND, Hb);
      k_gemm<<<dim3(48, 30), thr, 0, stream>>>(Hb, qkv_w + (size_t)l * ND * 3 * ND, QKV,
                                               nullptr, NB * NS, 3 * ND, ND, 0);
      k_attn<<<dim3(NB * NH), thr, 0, stream>>>(QKV, rel_bias + (size_t)l * (2 * NS - 1) * NH, ATT);
      k_gemm<<<dim3(16, 30), thr, 0, stream>>>(ATT, attn_out_w + (size_t)l * ND * ND, X,
                                               nullptr, NB * NS, ND, ND, 1);
      k_ln<<<dim3(NB * NS), thr, 0, stream>>>(X, ln2_w + l * ND, ln2_b + l * ND, Hb);
      k_gemm<<<dim3(64, 30), thr, 0, stream>>>(Hb, mlp_w1 + (size_t)l * ND * 2 * NHID, U,
                                               nullptr, NB * NS, 2 * NHID, ND, 0);
      k_swiglu<<<dim3(3840), thr, 0, stream>>>(U, Mb);
      k_gemm<<<dim3(16, 30), thr, 0, stream>>>(Mb, mlp_w2 + (size_t)l * NHID * ND, X,
                                               nullptr, NB * NS, ND, NHID, 1);
    }
    k_lnf<<<dim3(NB * NC), thr, 0, stream>>>(X, lnf_w, lnf_b, HL);
    k_gemm<<<dim3(16, 14), thr, 0, stream>>>(HL, vocab_w, LG, vocab_b, NB * NC, NV, ND, 2);
    k_gumbel_t<0><<<dim3(NB * NC), thr, 0, stream>>>(LG, nullptr, TOK, STV, out, i,
                                                     (i == NC - 1) ? 1 : 0, NC, 896);
  }
}